// Round 2
// baseline (62356.335 us; speedup 1.0000x reference)
//
#include <hip/hip_runtime.h>
#include <cstdint>

// ---------------------------------------------------------------------------
// VQVAE forward. Direct convolutions, channels-last (NDHWC).
// Thread map: threadIdx.x = cout (coalesced weight loads, broadcast input
// loads), threadIdx.y = voxel-group; VPT=4 output voxels per thread along W.
//
// Workspace is adaptive on ws_size (deterministic):
//   Path A (ws >= 256MiB): all-fp32, exactly 256MiB (VQ scratch overlaid in
//           the dead 'A' buffer; perplexity computed before decoder).
//   Path B (smaller):      res-unit h + 32^3 chain stored bf16 (201.6MB).
// ---------------------------------------------------------------------------

typedef unsigned short bf16_t;

__device__ __forceinline__ float b2f(bf16_t u) { return __uint_as_float((unsigned)u << 16); }
__device__ __forceinline__ float b2f_lo(unsigned v) { return __uint_as_float(v << 16); }
__device__ __forceinline__ float b2f_hi(unsigned v) { return __uint_as_float(v & 0xFFFF0000u); }
__device__ __forceinline__ bf16_t f2b(float f) {
    unsigned x = __float_as_uint(f);
    unsigned r = (x + 0x7FFFu + ((x >> 16) & 1u)) >> 16;
    return (bf16_t)r;
}

__device__ __forceinline__ float ld1(const float* p) { return *p; }
__device__ __forceinline__ float ld1(const bf16_t* p) { return b2f(*p); }
__device__ __forceinline__ void st1(float* p, float v) { *p = v; }
__device__ __forceinline__ void st1(bf16_t* p, float v) { *p = f2b(v); }

// load 8 consecutive channels as fp32
__device__ __forceinline__ void load8(const float* p, float* f) {
    const float4 a = *reinterpret_cast<const float4*>(p);
    const float4 b = *reinterpret_cast<const float4*>(p + 4);
    f[0] = a.x; f[1] = a.y; f[2] = a.z; f[3] = a.w;
    f[4] = b.x; f[5] = b.y; f[6] = b.z; f[7] = b.w;
}
__device__ __forceinline__ void load8(const bf16_t* p, float* f) {
    const uint4 r = *reinterpret_cast<const uint4*>(p);
    f[0] = b2f_lo(r.x); f[1] = b2f_hi(r.x);
    f[2] = b2f_lo(r.y); f[3] = b2f_hi(r.y);
    f[4] = b2f_lo(r.z); f[5] = b2f_hi(r.z);
    f[6] = b2f_lo(r.w); f[7] = b2f_hi(r.w);
}

// EPI: 0=ReLU, 1=swish, 2=PReLU, 3=BN+PReLU+skip-add+ReLU (in-place capable)
template<int CIN, int COUT, int VPT, int EPI, typename TI, typename TO>
__global__ __launch_bounds__(256)
void conv_k3(const TI* __restrict__ in, const float* __restrict__ wt,
             const float* __restrict__ bias, TO* out,
             int B, int D, int H, int W,
             const float* __restrict__ g, const float* __restrict__ be,
             const float* __restrict__ m, const float* __restrict__ v,
             const float* __restrict__ alpha, const TO* skip)
{
    constexpr int GPB = 256 / COUT;
    const int co  = threadIdx.x;
    const int gid = blockIdx.x * GPB + threadIdx.y;
    const int v0  = gid * VPT;
    const int w0  = v0 % W;
    int rem = v0 / W;
    const int h = rem % H; rem /= H;
    const int d = rem % D; rem /= D;
    const int b = rem;

    float acc[VPT];
    {
        const float bv = bias[co];
#pragma unroll
        for (int t = 0; t < VPT; ++t) acc[t] = bv;
    }

#pragma unroll 1
    for (int kd = 0; kd < 3; ++kd) {
        const int iz = d + kd - 1;
        if ((unsigned)iz >= (unsigned)D) continue;
#pragma unroll 1
        for (int kh = 0; kh < 3; ++kh) {
            const int iy = h + kh - 1;
            if ((unsigned)iy >= (unsigned)H) continue;
            const TI* iprow = in + (size_t)(((b * D + iz) * H + iy) * W) * CIN;
#pragma unroll 1
            for (int kw = 0; kw < 3; ++kw) {
                const float* wp = wt + (size_t)((kd * 3 + kh) * 3 + kw) * CIN * COUT + co;
                const TI* ipt[VPT];
                bool ok[VPT];
#pragma unroll
                for (int t = 0; t < VPT; ++t) {
                    const int ix = w0 + t + kw - 1;
                    ok[t]  = (unsigned)ix < (unsigned)W;
                    ipt[t] = iprow + (size_t)ix * CIN;
                }
#pragma unroll 2
                for (int ci = 0; ci < CIN; ci += 8) {
                    float wv[8];
#pragma unroll
                    for (int j = 0; j < 8; ++j) wv[j] = wp[(ci + j) * COUT];
#pragma unroll
                    for (int t = 0; t < VPT; ++t) {
                        if (ok[t]) {
                            float f[8];
                            load8(ipt[t] + ci, f);
#pragma unroll
                            for (int j = 0; j < 8; ++j) acc[t] = fmaf(f[j], wv[j], acc[t]);
                        }
                    }
                }
            }
        }
    }

#pragma unroll
    for (int t = 0; t < VPT; ++t) {
        float y = acc[t];
        if constexpr (EPI == 0) {
            y = fmaxf(y, 0.0f);
        } else if constexpr (EPI == 1) {
            y = y / (1.0f + expf(-y));                       // swish
        } else if constexpr (EPI == 2) {
            const float a = alpha[co];
            y = y > 0.0f ? y : a * y;                        // prelu
        } else {
            const float sc = g[co] * rsqrtf(v[co] + 1e-3f);  // BN eps=1e-3
            float t2 = (y - m[co]) * sc + be[co];
            const float a = alpha[co];
            t2 = t2 > 0.0f ? t2 : a * t2;
            y = fmaxf(ld1(skip + (size_t)(v0 + t) * COUT + co) + t2, 0.0f);
        }
        st1(out + (size_t)(v0 + t) * COUT + co, y);
    }
}

// stride-2 k=4 SAME conv (pad_lo=1): ix = 2*ox + kw - 1. Epilogue: ReLU.
template<int CIN, int COUT, int VPT, typename TI, typename TO>
__global__ __launch_bounds__(256)
void conv_s2k4(const TI* __restrict__ in, const float* __restrict__ wt,
               const float* __restrict__ bias, TO* __restrict__ out,
               int B, int ID, int IH, int IW)
{
    constexpr int GPB = 256 / COUT;
    const int OD = ID >> 1, OH = IH >> 1, OW = IW >> 1;
    const int co  = threadIdx.x;
    const int gid = blockIdx.x * GPB + threadIdx.y;
    const int v0  = gid * VPT;
    const int w0  = v0 % OW;
    int rem = v0 / OW;
    const int h = rem % OH; rem /= OH;
    const int d = rem % OD; rem /= OD;
    const int b = rem;

    float acc[VPT];
    {
        const float bv = bias[co];
#pragma unroll
        for (int t = 0; t < VPT; ++t) acc[t] = bv;
    }

#pragma unroll 1
    for (int kd = 0; kd < 4; ++kd) {
        const int iz = 2 * d + kd - 1;
        if ((unsigned)iz >= (unsigned)ID) continue;
#pragma unroll 1
        for (int kh = 0; kh < 4; ++kh) {
            const int iy = 2 * h + kh - 1;
            if ((unsigned)iy >= (unsigned)IH) continue;
            const TI* iprow = in + (size_t)(((b * ID + iz) * IH + iy) * IW) * CIN;
#pragma unroll 1
            for (int kw = 0; kw < 4; ++kw) {
                const float* wp = wt + (size_t)((kd * 4 + kh) * 4 + kw) * CIN * COUT + co;
                const TI* ipt[VPT];
                bool ok[VPT];
#pragma unroll
                for (int t = 0; t < VPT; ++t) {
                    const int ix = 2 * (w0 + t) + kw - 1;
                    ok[t]  = (unsigned)ix < (unsigned)IW;
                    ipt[t] = iprow + (size_t)ix * CIN;
                }
#pragma unroll 2
                for (int ci = 0; ci < CIN; ci += 8) {
                    float wv[8];
#pragma unroll
                    for (int j = 0; j < 8; ++j) wv[j] = wp[(ci + j) * COUT];
#pragma unroll
                    for (int t = 0; t < VPT; ++t) {
                        if (ok[t]) {
                            float f[8];
                            load8(ipt[t] + ci, f);
#pragma unroll
                            for (int j = 0; j < 8; ++j) acc[t] = fmaf(f[j], wv[j], acc[t]);
                        }
                    }
                }
            }
        }
    }

#pragma unroll
    for (int t = 0; t < VPT; ++t)
        st1(out + (size_t)(v0 + t) * COUT + co, fmaxf(acc[t], 0.0f));
}

// ec0: stride-2 k=4, CIN=1, COUT=64, in fp32, out fp32, ReLU.
__global__ __launch_bounds__(256)
void conv_ec0(const float* __restrict__ in, const float* __restrict__ wt,
              const float* __restrict__ bias, float* __restrict__ out,
              int B, int ID, int IH, int IW)
{
    const int OD = ID >> 1, OH = IH >> 1, OW = IW >> 1;
    const int co  = threadIdx.x;
    const int vox = blockIdx.x * 4 + threadIdx.y;
    const int w = vox % OW; int rem = vox / OW;
    const int h = rem % OH; rem /= OH;
    const int d = rem % OD; rem /= OD;
    const int b = rem;
    float acc = bias[co];
#pragma unroll 1
    for (int kd = 0; kd < 4; ++kd) {
        const int iz = 2 * d + kd - 1;
        if ((unsigned)iz >= (unsigned)ID) continue;
#pragma unroll 1
        for (int kh = 0; kh < 4; ++kh) {
            const int iy = 2 * h + kh - 1;
            if ((unsigned)iy >= (unsigned)IH) continue;
#pragma unroll
            for (int kw = 0; kw < 4; ++kw) {
                const int ix = 2 * w + kw - 1;
                if ((unsigned)ix >= (unsigned)IW) continue;
                const float xv = in[(size_t)((b * ID + iz) * IH + iy) * IW + ix];
                acc = fmaf(xv, wt[((kd * 4 + kh) * 4 + kw) * 64 + co], acc);
            }
        }
    }
    out[(size_t)vox * 64 + co] = fmaxf(acc, 0.0f);
}

// conv_transpose stride 2, k=4, SAME (pad=(2,2), lhs-dilated, no flip):
// per dim 2 taps: k = parity+2j, i = (o>>1) + parity - 1 + j. Epilogue ReLU.
template<int CIN, int COUT, int VPT, typename TI, typename TO>
__global__ __launch_bounds__(256)
void convT_s2k4(const TI* __restrict__ in, const float* __restrict__ wt,
                const float* __restrict__ bias, TO* __restrict__ out,
                int B, int ID, int IH, int IW)
{
    constexpr int GPB = 256 / COUT;
    const int OD = ID * 2, OH = IH * 2, OW = IW * 2;
    const int co  = threadIdx.x;
    const int gid = blockIdx.x * GPB + threadIdx.y;
    const int v0  = gid * VPT;
    const int w0  = v0 % OW;      // even (VPT=4, OW mult of 4)
    int rem = v0 / OW;
    const int oh = rem % OH; rem /= OH;
    const int od = rem % OD; rem /= OD;
    const int b  = rem;
    const int pd = od & 1, dz = od >> 1;
    const int ph = oh & 1, hy = oh >> 1;

    float acc[VPT];
    {
        const float bv = bias[co];
#pragma unroll
        for (int t = 0; t < VPT; ++t) acc[t] = bv;
    }

#pragma unroll 1
    for (int jd = 0; jd < 2; ++jd) {
        const int kd = pd + 2 * jd;
        const int iz = dz + pd - 1 + jd;
        if ((unsigned)iz >= (unsigned)ID) continue;
#pragma unroll 1
        for (int jh = 0; jh < 2; ++jh) {
            const int kh = ph + 2 * jh;
            const int iy = hy + ph - 1 + jh;
            if ((unsigned)iy >= (unsigned)IH) continue;
            const TI* iprow = in + (size_t)(((b * ID + iz) * IH + iy) * IW) * CIN;
#pragma unroll 1
            for (int jw = 0; jw < 2; ++jw) {
                const float* wpE = wt + (size_t)((kd * 4 + kh) * 4 + (2 * jw)) * CIN * COUT + co;
                const float* wpO = wt + (size_t)((kd * 4 + kh) * 4 + (1 + 2 * jw)) * CIN * COUT + co;
                const TI* ipt[VPT];
                bool ok[VPT];
#pragma unroll
                for (int t = 0; t < VPT; ++t) {
                    const int ow = w0 + t;
                    const int ix = (ow >> 1) + (ow & 1) - 1 + jw;
                    ok[t]  = (unsigned)ix < (unsigned)IW;
                    ipt[t] = iprow + (size_t)ix * CIN;
                }
#pragma unroll 2
                for (int ci = 0; ci < CIN; ci += 8) {
                    float wE[8], wO[8];
#pragma unroll
                    for (int j = 0; j < 8; ++j) {
                        wE[j] = wpE[(ci + j) * COUT];
                        wO[j] = wpO[(ci + j) * COUT];
                    }
#pragma unroll
                    for (int t = 0; t < VPT; ++t) {
                        if (ok[t]) {
                            float f[8];
                            load8(ipt[t] + ci, f);
                            const float* wv = (t & 1) ? wO : wE;
#pragma unroll
                            for (int j = 0; j < 8; ++j) acc[t] = fmaf(f[j], wv[j], acc[t]);
                        }
                    }
                }
            }
        }
    }

#pragma unroll
    for (int t = 0; t < VPT; ++t)
        st1(out + (size_t)(v0 + t) * COUT + co, fmaxf(acc[t], 0.0f));
}

// du1: convT stride 2 k=4, CIN=64, COUT=1, fp32 in (A), fp32 out, no act.
__global__ __launch_bounds__(256)
void convT_du1(const float* __restrict__ in, const float* __restrict__ wt,
               const float* __restrict__ bias, float* __restrict__ out,
               int B, int ID, int IH, int IW)
{
    const int OD = ID * 2, OH = IH * 2, OW = IW * 2;
    const int vox = blockIdx.x * 256 + threadIdx.x;
    const int ow = vox % OW; int rem = vox / OW;
    const int oh = rem % OH; rem /= OH;
    const int od = rem % OD; rem /= OD;
    const int b  = rem;
    const int pd = od & 1, dz = od >> 1;
    const int ph = oh & 1, hy = oh >> 1;
    const int pw = ow & 1, wx = ow >> 1;
    float acc = bias[0];
#pragma unroll 1
    for (int jd = 0; jd < 2; ++jd) {
        const int kd = pd + 2 * jd, iz = dz + pd - 1 + jd;
        if ((unsigned)iz >= (unsigned)ID) continue;
#pragma unroll 1
        for (int jh = 0; jh < 2; ++jh) {
            const int kh = ph + 2 * jh, iy = hy + ph - 1 + jh;
            if ((unsigned)iy >= (unsigned)IH) continue;
#pragma unroll 1
            for (int jw = 0; jw < 2; ++jw) {
                const int kw = pw + 2 * jw, ix = wx + pw - 1 + jw;
                if ((unsigned)ix >= (unsigned)IW) continue;
                const float* ip = in + (size_t)(((b * ID + iz) * IH + iy) * IW + ix) * 64;
                const float* wp = wt + (size_t)((kd * 4 + kh) * 4 + kw) * 64;
#pragma unroll 4
                for (int ci = 0; ci < 64; ci += 4) {
                    const float4 iv = *reinterpret_cast<const float4*>(ip + ci);
                    acc = fmaf(iv.x, wp[ci + 0], acc);
                    acc = fmaf(iv.y, wp[ci + 1], acc);
                    acc = fmaf(iv.z, wp[ci + 2], acc);
                    acc = fmaf(iv.w, wp[ci + 3], acc);
                }
            }
        }
    }
    out[vox] = acc;
}

// ---------------- VQ ----------------
__global__ void zero512(float* __restrict__ p) { p[threadIdx.x] = 0.0f; }

__global__ void vq_cnorm(const float* __restrict__ cb, float* __restrict__ cnorm)
{
    const int k = blockIdx.x * 64 + threadIdx.x;
    float s = 0.0f;
    for (int ci = 0; ci < 64; ++ci) { const float c = cb[k * 64 + ci]; s = fmaf(c, c, s); }
    cnorm[k] = s;
}

__global__ __launch_bounds__(256)
void vq_assign(const float* __restrict__ z, const float* __restrict__ cb,
               const float* __restrict__ cnorm, int* __restrict__ idx,
               float* __restrict__ hist, int N)
{
    const int n = blockIdx.x * 256 + threadIdx.x;
    const float4* zp = reinterpret_cast<const float4*>(z + (size_t)n * 64);
    float4 zv[16];
    float z2 = 0.0f;
#pragma unroll
    for (int i = 0; i < 16; ++i) {
        zv[i] = zp[i];
        z2 += zv[i].x * zv[i].x + zv[i].y * zv[i].y + zv[i].z * zv[i].z + zv[i].w * zv[i].w;
    }
    float best = 3.4e38f;
    int bi = 0;
#pragma unroll 1
    for (int k = 0; k < 512; ++k) {
        const float4* cp = reinterpret_cast<const float4*>(cb + (size_t)k * 64);
        float dot = 0.0f;
#pragma unroll
        for (int i = 0; i < 16; ++i) {
            const float4 c = cp[i];
            dot += zv[i].x * c.x + zv[i].y * c.y + zv[i].z * c.z + zv[i].w * c.w;
        }
        const float dist = z2 + cnorm[k] - 2.0f * dot;   // exact reference formula
        if (dist < best) { best = dist; bi = k; }        // first-min argmin
    }
    idx[n] = bi;
    atomicAdd(&hist[bi], 1.0f);
}

// gather zq in-place over fp32 z
__global__ __launch_bounds__(256)
void vq_gather_f32(const float* __restrict__ cb, const int* __restrict__ idx,
                   float* __restrict__ zq)
{
    const int gid = blockIdx.x * 256 + threadIdx.x;
    const int n = gid >> 4, c4 = gid & 15;
    const int k = idx[n];
    reinterpret_cast<float4*>(zq)[(size_t)n * 16 + c4] =
        reinterpret_cast<const float4*>(cb)[k * 16 + c4];
}

// gather zq into bf16 buffer (path B)
__global__ __launch_bounds__(256)
void vq_gather_bf16(const float* __restrict__ cb, const int* __restrict__ idx,
                    bf16_t* __restrict__ zq)
{
    const int gid = blockIdx.x * 256 + threadIdx.x;
    const int n = gid >> 4, c4 = gid & 15;
    const int k = idx[n];
    const float4 c = reinterpret_cast<const float4*>(cb)[k * 16 + c4];
    ushort4 o;
    o.x = f2b(c.x); o.y = f2b(c.y); o.z = f2b(c.z); o.w = f2b(c.w);
    reinterpret_cast<ushort4*>(zq)[gid] = o;
}

__global__ __launch_bounds__(512)
void perplexity_k(const float* __restrict__ hist, float* __restrict__ out, float invN)
{
    __shared__ float red[512];
    const int t = threadIdx.x;
    const float p = hist[t] * invN;
    red[t] = p * logf(p + 1e-12f);
    __syncthreads();
    for (int s = 256; s > 0; s >>= 1) {
        if (t < s) red[t] += red[t + s];
        __syncthreads();
    }
    if (t == 0) out[0] = expf(-red[0]);
}

// ---------------------------------------------------------------------------
extern "C" void kernel_launch(void* const* d_in, const int* in_sizes, int n_in,
                              void* d_out, int out_size, void* d_ws, size_t ws_size,
                              hipStream_t stream)
{
    const float* x       = (const float*)d_in[0];
    const float* ec0_w   = (const float*)d_in[1];
    const float* ec0_b   = (const float*)d_in[2];
    const float* er0_c1w = (const float*)d_in[3];
    const float* er0_c1b = (const float*)d_in[4];
    const float* er0_c2w = (const float*)d_in[5];
    const float* er0_c2b = (const float*)d_in[6];
    const float* er0_g   = (const float*)d_in[7];
    const float* er0_be  = (const float*)d_in[8];
    const float* er0_m   = (const float*)d_in[9];
    const float* er0_v   = (const float*)d_in[10];
    const float* er0_a   = (const float*)d_in[11];
    const float* ec1_w   = (const float*)d_in[12];
    const float* ec1_b   = (const float*)d_in[13];
    const float* er1_c1w = (const float*)d_in[14];
    const float* er1_c1b = (const float*)d_in[15];
    const float* er1_c2w = (const float*)d_in[16];
    const float* er1_c2b = (const float*)d_in[17];
    const float* er1_g   = (const float*)d_in[18];
    const float* er1_be  = (const float*)d_in[19];
    const float* er1_m   = (const float*)d_in[20];
    const float* er1_v   = (const float*)d_in[21];
    const float* er1_a   = (const float*)d_in[22];
    const float* eo_w    = (const float*)d_in[23];
    const float* eo_b    = (const float*)d_in[24];
    const float* eo_a    = (const float*)d_in[25];
    const float* cb      = (const float*)d_in[26];
    const float* dc0_w   = (const float*)d_in[27];
    const float* dc0_b   = (const float*)d_in[28];
    const float* dc0_a   = (const float*)d_in[29];
    const float* dr0_c1w = (const float*)d_in[30];
    const float* dr0_c1b = (const float*)d_in[31];
    const float* dr0_c2w = (const float*)d_in[32];
    const float* dr0_c2b = (const float*)d_in[33];
    const float* dr0_g   = (const float*)d_in[34];
    const float* dr0_be  = (const float*)d_in[35];
    const float* dr0_m   = (const float*)d_in[36];
    const float* dr0_v   = (const float*)d_in[37];
    const float* dr0_a   = (const float*)d_in[38];
    const float* du0_w   = (const float*)d_in[39];
    const float* du0_b   = (const float*)d_in[40];
    const float* dr1_c1w = (const float*)d_in[41];
    const float* dr1_c1b = (const float*)d_in[42];
    const float* dr1_c2w = (const float*)d_in[43];
    const float* dr1_c2b = (const float*)d_in[44];
    const float* dr1_g   = (const float*)d_in[45];
    const float* dr1_be  = (const float*)d_in[46];
    const float* dr1_m   = (const float*)d_in[47];
    const float* dr1_v   = (const float*)d_in[48];
    const float* dr1_a   = (const float*)d_in[49];
    const float* du1_w   = (const float*)d_in[50];
    const float* du1_b   = (const float*)d_in[51];

    float* out = (float*)d_out;
    float* ws  = (float*)d_ws;

    const dim3 b64(64, 4), b128(128, 2);
    const float* fnul = nullptr;

    if (ws_size >= (size_t)268435456) {
        // ---------- Path A: all-fp32, exactly 256 MiB ----------
        float* A   = ws;                 // [2,64,64,64,64] = 134,217,728 B
        float* R2  = ws + 33554432;      // region2, 134,217,728 B
        float* E1  = R2;                 // [2,32,32,32,128]
        float* Hb  = R2 + 8388608;       // [2,32,32,32,128]
        float* Z   = R2 + 16777216;      // [2,32,32,32,64]
        float* D0  = R2 + 20971520;      // [2,32,32,32,128]
        float* H64 = R2;                 // full region2: er0/dr1 h
        // VQ scratch inside dead A (A dead between ec1 and du0;
        // perplexity runs before decoder revives A):
        int*   IDX = (int*)A;            // 65,536 ints
        float* CN  = A + 65536;          // 512
        float* HS  = A + 66048;          // 512

        // Encoder
        conv_ec0<<<131072, b64, 0, stream>>>(x, ec0_w, ec0_b, A, 2, 128, 128, 128);
        conv_k3<64, 64, 4, 1, float, float><<<32768, b64, 0, stream>>>(A, er0_c1w, er0_c1b, H64,
            2, 64, 64, 64, fnul, fnul, fnul, fnul, fnul, (const float*)nullptr);
        conv_k3<64, 64, 4, 3, float, float><<<32768, b64, 0, stream>>>(H64, er0_c2w, er0_c2b, A,
            2, 64, 64, 64, er0_g, er0_be, er0_m, er0_v, er0_a, A);
        conv_s2k4<64, 128, 4, float, float><<<8192, b128, 0, stream>>>(A, ec1_w, ec1_b, E1, 2, 64, 64, 64);
        conv_k3<128, 128, 4, 1, float, float><<<8192, b128, 0, stream>>>(E1, er1_c1w, er1_c1b, Hb,
            2, 32, 32, 32, fnul, fnul, fnul, fnul, fnul, (const float*)nullptr);
        conv_k3<128, 128, 4, 3, float, float><<<8192, b128, 0, stream>>>(Hb, er1_c2w, er1_c2b, E1,
            2, 32, 32, 32, er1_g, er1_be, er1_m, er1_v, er1_a, E1);
        conv_k3<128, 64, 4, 2, float, float><<<4096, b64, 0, stream>>>(E1, eo_w, eo_b, Z,
            2, 32, 32, 32, fnul, fnul, fnul, fnul, eo_a, (const float*)nullptr);

        // VQ (perplexity BEFORE decoder overwrites A-resident scratch)
        vq_cnorm<<<8, 64, 0, stream>>>(cb, CN);
        zero512<<<1, 512, 0, stream>>>(HS);
        vq_assign<<<256, 256, 0, stream>>>(Z, cb, CN, IDX, HS, 65536);
        perplexity_k<<<1, 512, 0, stream>>>(HS, out + 4194304, 1.0f / 65536.0f);
        vq_gather_f32<<<4096, 256, 0, stream>>>(cb, IDX, Z);

        // Decoder
        conv_k3<64, 128, 4, 2, float, float><<<8192, b128, 0, stream>>>(Z, dc0_w, dc0_b, D0,
            2, 32, 32, 32, fnul, fnul, fnul, fnul, dc0_a, (const float*)nullptr);
        conv_k3<128, 128, 4, 1, float, float><<<8192, b128, 0, stream>>>(D0, dr0_c1w, dr0_c1b, Hb,
            2, 32, 32, 32, fnul, fnul, fnul, fnul, fnul, (const float*)nullptr);
        conv_k3<128, 128, 4, 3, float, float><<<8192, b128, 0, stream>>>(Hb, dr0_c2w, dr0_c2b, D0,
            2, 32, 32, 32, dr0_g, dr0_be, dr0_m, dr0_v, dr0_a, D0);
        convT_s2k4<128, 64, 4, float, float><<<32768, b64, 0, stream>>>(D0, du0_w, du0_b, A, 2, 32, 32, 32);
        conv_k3<64, 64, 4, 1, float, float><<<32768, b64, 0, stream>>>(A, dr1_c1w, dr1_c1b, H64,
            2, 64, 64, 64, fnul, fnul, fnul, fnul, fnul, (const float*)nullptr);
        conv_k3<64, 64, 4, 3, float, float><<<32768, b64, 0, stream>>>(H64, dr1_c2w, dr1_c2b, A,
            2, 64, 64, 64, dr1_g, dr1_be, dr1_m, dr1_v, dr1_a, A);
        convT_du1<<<16384, 256, 0, stream>>>(A, du1_w, du1_b, out, 2, 64, 64, 64);
    } else {
        // ---------- Path B: compact (201.6 MB), h + 32^3 chain in bf16 ----------
        float*  A    = ws;                                   // fp32, 134,217,728 B
        char*   R2   = (char*)(ws + 33554432);               // 67,108,864 B
        bf16_t* H64b = (bf16_t*)R2;                          // full region (er0/dr1 h)
        bf16_t* E1b  = (bf16_t*)R2;                          // 16,777,216 B
        bf16_t* Hbb  = (bf16_t*)(R2 + 16777216);
        bf16_t* D0b  = (bf16_t*)(R2 + 33554432);
        float*  Zf   = (float*)(R2 + 50331648);              // fp32, 16,777,216 B
        bf16_t* ZQ   = E1b;                                  // reuse E1 slot
        int*    IDX  = (int*)(R2 + 67108864);
        float*  CN   = (float*)((char*)IDX + 262144);
        float*  HS   = CN + 512;

        conv_ec0<<<131072, b64, 0, stream>>>(x, ec0_w, ec0_b, A, 2, 128, 128, 128);
        conv_k3<64, 64, 4, 1, float, bf16_t><<<32768, b64, 0, stream>>>(A, er0_c1w, er0_c1b, H64b,
            2, 64, 64, 64, fnul, fnul, fnul, fnul, fnul, (const bf16_t*)nullptr);
        conv_k3<64, 64, 4, 3, bf16_t, float><<<32768, b64, 0, stream>>>(H64b, er0_c2w, er0_c2b, A,
            2, 64, 64, 64, er0_g, er0_be, er0_m, er0_v, er0_a, A);
        conv_s2k4<64, 128, 4, float, bf16_t><<<8192, b128, 0, stream>>>(A, ec1_w, ec1_b, E1b, 2, 64, 64, 64);
        conv_k3<128, 128, 4, 1, bf16_t, bf16_t><<<8192, b128, 0, stream>>>(E1b, er1_c1w, er1_c1b, Hbb,
            2, 32, 32, 32, fnul, fnul, fnul, fnul, fnul, (const bf16_t*)nullptr);
        conv_k3<128, 128, 4, 3, bf16_t, bf16_t><<<8192, b128, 0, stream>>>(Hbb, er1_c2w, er1_c2b, E1b,
            2, 32, 32, 32, er1_g, er1_be, er1_m, er1_v, er1_a, E1b);
        conv_k3<128, 64, 4, 2, bf16_t, float><<<4096, b64, 0, stream>>>(E1b, eo_w, eo_b, Zf,
            2, 32, 32, 32, fnul, fnul, fnul, fnul, eo_a, (const float*)nullptr);

        vq_cnorm<<<8, 64, 0, stream>>>(cb, CN);
        zero512<<<1, 512, 0, stream>>>(HS);
        vq_assign<<<256, 256, 0, stream>>>(Zf, cb, CN, IDX, HS, 65536);
        perplexity_k<<<1, 512, 0, stream>>>(HS, out + 4194304, 1.0f / 65536.0f);
        vq_gather_bf16<<<4096, 256, 0, stream>>>(cb, IDX, ZQ);

        conv_k3<64, 128, 4, 2, bf16_t, bf16_t><<<8192, b128, 0, stream>>>(ZQ, dc0_w, dc0_b, D0b,
            2, 32, 32, 32, fnul, fnul, fnul, fnul, dc0_a, (const bf16_t*)nullptr);
        conv_k3<128, 128, 4, 1, bf16_t, bf16_t><<<8192, b128, 0, stream>>>(D0b, dr0_c1w, dr0_c1b, Hbb,
            2, 32, 32, 32, fnul, fnul, fnul, fnul, fnul, (const bf16_t*)nullptr);
        conv_k3<128, 128, 4, 3, bf16_t, bf16_t><<<8192, b128, 0, stream>>>(Hbb, dr0_c2w, dr0_c2b, D0b,
            2, 32, 32, 32, dr0_g, dr0_be, dr0_m, dr0_v, dr0_a, D0b);
        convT_s2k4<128, 64, 4, bf16_t, float><<<32768, b64, 0, stream>>>(D0b, du0_w, du0_b, A, 2, 32, 32, 32);
        conv_k3<64, 64, 4, 1, float, bf16_t><<<32768, b64, 0, stream>>>(A, dr1_c1w, dr1_c1b, H64b,
            2, 64, 64, 64, fnul, fnul, fnul, fnul, fnul, (const bf16_t*)nullptr);
        conv_k3<64, 64, 4, 3, bf16_t, float><<<32768, b64, 0, stream>>>(H64b, dr1_c2w, dr1_c2b, A,
            2, 64, 64, 64, dr1_g, dr1_be, dr1_m, dr1_v, dr1_a, A);
        convT_du1<<<16384, 256, 0, stream>>>(A, du1_w, du1_b, out, 2, 64, 64, 64);
    }
}

// Round 5
// 16001.805 us; speedup vs baseline: 3.8968x; 3.8968x over previous
//
#include <hip/hip_runtime.h>
#include <cstdint>

// ---------------------------------------------------------------------------
// VQVAE forward — MFMA implicit-GEMM convolutions, channels-last.
//
// Encoder: fp32 activations in memory; in-register EXACT 3-way bf16 split
//   (v = h+m+l bit-exact via truncation) + 6-MFMA products (h*h, h*m, m*h,
//   h*l, m*m, l*h) => fp32-class accuracy => VQ argmin matches fp32 refs.
// Decoder: split-2 bf16 (hi/lo) storage, 3-pass MFMA (~2^-17 rel/layer).
//
// MFMA v_mfma_f32_32x32x16_bf16; A/B k-mapping: lane l supplies k =
// (l>>5)*8 + j (consistent on A and B => any k-permutation cancels).
// C layout: col = lane&31, row = (reg&3) + 8*(reg>>2) + 4*(lane>>5)  [m101]
//
// ws (256 MiB): A = [0,134MB) fp32 64^3 buf; H = [134MB,268MB) fp32 64^3 buf
// (encoder); decoder reuses: 32^3 bf16 slots in A, du0/dr1 64^3 bf16 in H+A.
// Weight arenas live in d_out (dead until du1): encoder split-3 first,
// then overwritten by decoder split-2 after VQ.
// ---------------------------------------------------------------------------

typedef unsigned short bf16_t;
typedef __attribute__((ext_vector_type(8)))  short s8b;     // 8 x bf16 frag
typedef __attribute__((ext_vector_type(16))) float f32x16;  // 32x32 acc

__device__ __forceinline__ float b2f(bf16_t u) { return __uint_as_float((unsigned)u << 16); }
__device__ __forceinline__ bf16_t f2b(float f) {
    unsigned x = __float_as_uint(f);
    return (bf16_t)((x + 0x7FFFu + ((x >> 16) & 1u)) >> 16);
}

// exact 3-way split of 8 fp32 (two float4) into bf16 h/m/l frags
__device__ __forceinline__ void split3v(const float4 a, const float4 b,
                                        s8b& h, s8b& m, s8b& l)
{
    float v[8] = {a.x, a.y, a.z, a.w, b.x, b.y, b.z, b.w};
#pragma unroll
    for (int j = 0; j < 8; ++j) {
        const unsigned uv = __float_as_uint(v[j]);
        const float fh = __uint_as_float(uv & 0xFFFF0000u);
        const float r1 = v[j] - fh;
        const unsigned u1 = __float_as_uint(r1);
        const float fm = __uint_as_float(u1 & 0xFFFF0000u);
        const float r2 = r1 - fm;
        h[j] = (short)(uv >> 16);
        m[j] = (short)(u1 >> 16);
        l[j] = (short)(__float_as_uint(r2) >> 16);
    }
}

// ------------------------- weight prep ------------------------------------
// src [tap][ci][co] fp32 -> dst [tap][co][ci] bf16, 3-way exact split
__global__ __launch_bounds__(256)
void wprep3(const float* __restrict__ w, bf16_t* __restrict__ h,
            bf16_t* __restrict__ m, bf16_t* __restrict__ l,
            int ci, int co, int n)
{
    const int i = blockIdx.x * 256 + threadIdx.x;
    if (i >= n) return;
    const int co_ = i % co;
    const int ci_ = (i / co) % ci;
    const int tap = i / (co * ci);
    const int dst = (tap * co + co_) * ci + ci_;
    const float v = w[i];
    const unsigned uv = __float_as_uint(v);
    const float fh = __uint_as_float(uv & 0xFFFF0000u);
    const float r1 = v - fh;
    const unsigned u1 = __float_as_uint(r1);
    const float fm = __uint_as_float(u1 & 0xFFFF0000u);
    const float r2 = r1 - fm;
    h[dst] = (bf16_t)(uv >> 16);
    m[dst] = (bf16_t)(u1 >> 16);
    l[dst] = (bf16_t)(__float_as_uint(r2) >> 16);
}

// 2-way split (rounded) for decoder
__global__ __launch_bounds__(256)
void wprep_split(const float* __restrict__ w, bf16_t* __restrict__ hi,
                 bf16_t* __restrict__ lo, int ci, int co, int n)
{
    const int i = blockIdx.x * 256 + threadIdx.x;
    if (i >= n) return;
    const int co_ = i % co;
    const int ci_ = (i / co) % ci;
    const int tap = i / (co * ci);
    const float v = w[i];
    const int dst = (tap * co + co_) * ci + ci_;
    const bf16_t h = f2b(v);
    hi[dst] = h;
    lo[dst] = f2b(v - b2f(h));
}

// ---------------- encoder 3x3x3 conv: fp32 in/out, split-3 6-MFMA -----------
// EPI: 0=ReLU 1=swish 2=PReLU 3=BN+PReLU+skip+ReLU
template<int CIN, int COUT, int WM, int WN, int SD, int EPI>
__global__ __launch_bounds__(256)
void conv3s3(const float* __restrict__ xf,
             const bf16_t* __restrict__ wh, const bf16_t* __restrict__ wm,
             const bf16_t* __restrict__ wl,
             const float* __restrict__ bias,
             const float* __restrict__ g, const float* __restrict__ be,
             const float* __restrict__ mn, const float* __restrict__ vr,
             const float* __restrict__ al,
             const float* skf, float* __restrict__ of)
{
    const int lane = threadIdx.x & 63;
    const int wid  = threadIdx.x >> 6;
    const int wn   = wid % WN, wm2 = wid / WN;
    const int half = lane >> 5, ln = lane & 31;
    const int w    = wm2 * 32 + ln;
    const int bid  = blockIdx.x;
    const int h    = bid % SD;
    const int d    = (bid / SD) % SD;
    const int b    = bid / (SD * SD);
    const int cout = wn * 32 + ln;
    const int boff = cout * CIN + half * 8;

    f32x16 acc;
#pragma unroll
    for (int i = 0; i < 16; ++i) acc[i] = 0.0f;

#pragma unroll 1
    for (int kd = 0; kd < 3; ++kd) {
        const int iz = d + kd - 1;
        if ((unsigned)iz >= (unsigned)SD) continue;
#pragma unroll 1
        for (int kh = 0; kh < 3; ++kh) {
            const int iy = h + kh - 1;
            if ((unsigned)iy >= (unsigned)SD) continue;
            const size_t rowb = ((size_t)((b * SD + iz) * SD + iy)) * SD;
#pragma unroll
            for (int kw = 0; kw < 3; ++kw) {
                const int iw = w + kw - 1;
                const bool edge = (unsigned)iw >= (unsigned)SD;
                const int wcl = edge ? w : iw;
                const size_t aoe = (rowb + wcl) * CIN + half * 8;
                const size_t wbase = (size_t)((kd * 3 + kh) * 3 + kw) * CIN * COUT + boff;
#pragma unroll
                for (int ks = 0; ks < CIN / 16; ++ks) {
                    float4 a0 = *reinterpret_cast<const float4*>(xf + aoe + ks * 16);
                    float4 a1 = *reinterpret_cast<const float4*>(xf + aoe + ks * 16 + 4);
                    if (edge) { a0 = make_float4(0,0,0,0); a1 = make_float4(0,0,0,0); }
                    s8b ah, am, al2;
                    split3v(a0, a1, ah, am, al2);
                    const s8b bh = *reinterpret_cast<const s8b*>(wh + wbase + ks * 16);
                    const s8b bm = *reinterpret_cast<const s8b*>(wm + wbase + ks * 16);
                    const s8b bl = *reinterpret_cast<const s8b*>(wl + wbase + ks * 16);
                    acc = __builtin_amdgcn_mfma_f32_32x32x16_bf16(ah, bh, acc, 0, 0, 0);
                    acc = __builtin_amdgcn_mfma_f32_32x32x16_bf16(ah, bm, acc, 0, 0, 0);
                    acc = __builtin_amdgcn_mfma_f32_32x32x16_bf16(am, bh, acc, 0, 0, 0);
                    acc = __builtin_amdgcn_mfma_f32_32x32x16_bf16(ah, bl, acc, 0, 0, 0);
                    acc = __builtin_amdgcn_mfma_f32_32x32x16_bf16(am, bm, acc, 0, 0, 0);
                    acc = __builtin_amdgcn_mfma_f32_32x32x16_bf16(al2, bh, acc, 0, 0, 0);
                }
            }
        }
    }

    const float bv = bias[cout];
    float sc = 0.f, mm = 0.f, bb2 = 0.f, aa = 0.f;
    if constexpr (EPI == 3) {
        sc = g[cout] * (1.0f / sqrtf(vr[cout] + 1e-3f));
        mm = mn[cout]; bb2 = be[cout]; aa = al[cout];
    }
    if constexpr (EPI == 2) aa = al[cout];
    const size_t outrow = ((size_t)((b * SD + d) * SD + h)) * SD;
#pragma unroll
    for (int r = 0; r < 16; ++r) {
        const int rl = (r & 3) + 8 * (r >> 2) + 4 * half + wm2 * 32;
        const size_t oe = (outrow + rl) * COUT + cout;
        float y = acc[r] + bv;
        if constexpr (EPI == 0) y = fmaxf(y, 0.f);
        else if constexpr (EPI == 1) y = y / (1.f + expf(-y));
        else if constexpr (EPI == 2) y = y > 0.f ? y : aa * y;
        else {
            float t2 = (y - mm) * sc + bb2;
            t2 = t2 > 0.f ? t2 : aa * t2;
            y = fmaxf(skf[oe] + t2, 0.f);
        }
        of[oe] = y;
    }
}

// ---------------- ec1: stride-2 k=4, fp32 in/out, split-3 -------------------
__global__ __launch_bounds__(256)
void convs2m3(const float* __restrict__ xf,
              const bf16_t* __restrict__ wh, const bf16_t* __restrict__ wm,
              const bf16_t* __restrict__ wl,
              const float* __restrict__ bias, float* __restrict__ of)
{
    const int lane = threadIdx.x & 63;
    const int wn   = threadIdx.x >> 6;
    const int half = lane >> 5, ln = lane & 31;
    const int bid  = blockIdx.x;
    const int h    = bid % 32;
    const int d    = (bid / 32) % 32;
    const int b    = bid / 1024;
    const int cout = wn * 32 + ln;
    const int boff = cout * 64 + half * 8;

    f32x16 acc;
#pragma unroll
    for (int i = 0; i < 16; ++i) acc[i] = 0.0f;

#pragma unroll 1
    for (int kd = 0; kd < 4; ++kd) {
        const int iz = 2 * d + kd - 1;
        if ((unsigned)iz >= 64u) continue;
#pragma unroll 1
        for (int kh = 0; kh < 4; ++kh) {
            const int iy = 2 * h + kh - 1;
            if ((unsigned)iy >= 64u) continue;
            const size_t rowb = ((size_t)((b * 64 + iz) * 64 + iy)) * 64;
#pragma unroll
            for (int kw = 0; kw < 4; ++kw) {
                const int iw = 2 * ln + kw - 1;
                const bool edge = (unsigned)iw >= 64u;
                const int wcl = edge ? 2 * ln : iw;
                const size_t aoe = (rowb + wcl) * 64 + half * 8;
                const size_t wbase = (size_t)((kd * 4 + kh) * 4 + kw) * 64 * 128 + boff;
#pragma unroll
                for (int ks = 0; ks < 4; ++ks) {
                    float4 a0 = *reinterpret_cast<const float4*>(xf + aoe + ks * 16);
                    float4 a1 = *reinterpret_cast<const float4*>(xf + aoe + ks * 16 + 4);
                    if (edge) { a0 = make_float4(0,0,0,0); a1 = make_float4(0,0,0,0); }
                    s8b ah, am, al2;
                    split3v(a0, a1, ah, am, al2);
                    const s8b bh = *reinterpret_cast<const s8b*>(wh + wbase + ks * 16);
                    const s8b bm = *reinterpret_cast<const s8b*>(wm + wbase + ks * 16);
                    const s8b bl = *reinterpret_cast<const s8b*>(wl + wbase + ks * 16);
                    acc = __builtin_amdgcn_mfma_f32_32x32x16_bf16(ah, bh, acc, 0, 0, 0);
                    acc = __builtin_amdgcn_mfma_f32_32x32x16_bf16(ah, bm, acc, 0, 0, 0);
                    acc = __builtin_amdgcn_mfma_f32_32x32x16_bf16(am, bh, acc, 0, 0, 0);
                    acc = __builtin_amdgcn_mfma_f32_32x32x16_bf16(ah, bl, acc, 0, 0, 0);
                    acc = __builtin_amdgcn_mfma_f32_32x32x16_bf16(am, bm, acc, 0, 0, 0);
                    acc = __builtin_amdgcn_mfma_f32_32x32x16_bf16(al2, bh, acc, 0, 0, 0);
                }
            }
        }
    }

    const float bv = bias[cout];
    const size_t outrow = ((size_t)((b * 32 + d) * 32 + h)) * 32;
#pragma unroll
    for (int r = 0; r < 16; ++r) {
        const int rl = (r & 3) + 8 * (r >> 2) + 4 * half;
        const size_t oe = (outrow + rl) * 128 + cout;
        of[oe] = fmaxf(acc[r] + bv, 0.f);
    }
}

// ---------------- decoder 3x3x3 conv: split-2 bf16 (round-4 proven) ---------
template<int CIN, int COUT, int WM, int WN, int SD, int EPI, bool SIN, int OM>
__global__ __launch_bounds__(256)
void conv3m(const bf16_t* __restrict__ xh, const bf16_t* __restrict__ xl,
            const bf16_t* __restrict__ wh, const bf16_t* __restrict__ wl,
            const float* __restrict__ bias,
            const float* __restrict__ g, const float* __restrict__ be,
            const float* __restrict__ mn, const float* __restrict__ vr,
            const float* __restrict__ al,
            const bf16_t* skh, const bf16_t* skl,
            bf16_t* oh, bf16_t* ol)
{
    const int lane = threadIdx.x & 63;
    const int wid  = threadIdx.x >> 6;
    const int wn   = wid % WN, wm = wid / WN;
    const int half = lane >> 5, ln = lane & 31;
    const int w    = wm * 32 + ln;
    const int bid  = blockIdx.x;
    const int h    = bid % SD;
    const int d    = (bid / SD) % SD;
    const int b    = bid / (SD * SD);
    const int cout = wn * 32 + ln;
    const int boff = cout * CIN + half * 8;

    f32x16 acc;
#pragma unroll
    for (int i = 0; i < 16; ++i) acc[i] = 0.0f;

#pragma unroll 1
    for (int kd = 0; kd < 3; ++kd) {
        const int iz = d + kd - 1;
        if ((unsigned)iz >= (unsigned)SD) continue;
#pragma unroll 1
        for (int kh = 0; kh < 3; ++kh) {
            const int iy = h + kh - 1;
            if ((unsigned)iy >= (unsigned)SD) continue;
            const size_t rowb = ((size_t)((b * SD + iz) * SD + iy)) * SD;
#pragma unroll
            for (int kw = 0; kw < 3; ++kw) {
                const int iw = w + kw - 1;
                const bool edge = (unsigned)iw >= (unsigned)SD;
                const int wcl = edge ? w : iw;
                const size_t aoe = (rowb + wcl) * CIN + half * 8;
                const size_t wbase = (size_t)((kd * 3 + kh) * 3 + kw) * CIN * COUT + boff;
                const s8b zz = {};
#pragma unroll
                for (int ks = 0; ks < CIN / 16; ++ks) {
                    s8b a = *reinterpret_cast<const s8b*>(xh + aoe + ks * 16);
                    if (edge) a = zz;
                    s8b bb = *reinterpret_cast<const s8b*>(wh + wbase + ks * 16);
                    acc = __builtin_amdgcn_mfma_f32_32x32x16_bf16(a, bb, acc, 0, 0, 0);
                    if constexpr (SIN) {
                        s8b a2 = *reinterpret_cast<const s8b*>(xl + aoe + ks * 16);
                        if (edge) a2 = zz;
                        acc = __builtin_amdgcn_mfma_f32_32x32x16_bf16(a2, bb, acc, 0, 0, 0);
                        s8b b2 = *reinterpret_cast<const s8b*>(wl + wbase + ks * 16);
                        acc = __builtin_amdgcn_mfma_f32_32x32x16_bf16(a, b2, acc, 0, 0, 0);
                    }
                }
            }
        }
    }

    const float bv = bias[cout];
    float sc = 0.f, mm = 0.f, bb2 = 0.f, aa = 0.f;
    if constexpr (EPI == 3) {
        sc = g[cout] * (1.0f / sqrtf(vr[cout] + 1e-3f));
        mm = mn[cout]; bb2 = be[cout]; aa = al[cout];
    }
    if constexpr (EPI == 2) aa = al[cout];
    const size_t outrow = ((size_t)((b * SD + d) * SD + h)) * SD;
#pragma unroll
    for (int r = 0; r < 16; ++r) {
        const int rl = (r & 3) + 8 * (r >> 2) + 4 * half + wm * 32;
        const size_t oe = (outrow + rl) * COUT + cout;
        float y = acc[r] + bv;
        if constexpr (EPI == 0) y = fmaxf(y, 0.f);
        else if constexpr (EPI == 1) y = y / (1.f + expf(-y));
        else if constexpr (EPI == 2) y = y > 0.f ? y : aa * y;
        else {
            float t2 = (y - mm) * sc + bb2;
            t2 = t2 > 0.f ? t2 : aa * t2;
            float sv = b2f(skh[oe]);
            if constexpr (SIN) sv += b2f(skl[oe]);
            y = fmaxf(sv + t2, 0.f);
        }
        const bf16_t hh = f2b(y);
        oh[oe] = hh;
        if constexpr (OM == 1) ol[oe] = f2b(y - b2f(hh));
    }
}

// ---------------- convT stride-2 k=4 (du0, split-2) -------------------------
__global__ __launch_bounds__(256)
void convTm(const bf16_t* __restrict__ xh, const bf16_t* __restrict__ xl,
            const bf16_t* __restrict__ wh, const bf16_t* __restrict__ wl,
            const float* __restrict__ bias,
            bf16_t* __restrict__ oh, bf16_t* __restrict__ ol)
{
    const int lane = threadIdx.x & 63;
    const int wid  = threadIdx.x >> 6;
    const int wn   = wid & 1, p = wid >> 1;
    const int half = lane >> 5, ln = lane & 31;
    const int bid  = blockIdx.x;
    const int ohh  = bid % 64;
    const int od   = (bid / 64) % 64;
    const int b    = bid / 4096;
    const int pd = od & 1, dz = od >> 1;
    const int ph = ohh & 1, hy = ohh >> 1;
    const int cout = wn * 32 + ln;
    const int boff = cout * 128 + half * 8;

    f32x16 acc;
#pragma unroll
    for (int i = 0; i < 16; ++i) acc[i] = 0.0f;

#pragma unroll 1
    for (int jd = 0; jd < 2; ++jd) {
        const int kd = pd + 2 * jd;
        const int iz = dz + pd - 1 + jd;
        if ((unsigned)iz >= 32u) continue;
#pragma unroll 1
        for (int jh = 0; jh < 2; ++jh) {
            const int kh = ph + 2 * jh;
            const int iy = hy + ph - 1 + jh;
            if ((unsigned)iy >= 32u) continue;
            const size_t rowb = ((size_t)((b * 32 + iz) * 32 + iy)) * 32;
#pragma unroll
            for (int jw = 0; jw < 2; ++jw) {
                const int kw = p + 2 * jw;
                const int ix = ln + p - 1 + jw;
                const bool edge = (unsigned)ix >= 32u;
                const int xcl = edge ? ln : ix;
                const size_t aoe = (rowb + xcl) * 128 + half * 8;
                const size_t wbase = (size_t)((kd * 4 + kh) * 4 + kw) * 128 * 64 + boff;
                const s8b zz = {};
#pragma unroll
                for (int ks = 0; ks < 8; ++ks) {
                    s8b a = *reinterpret_cast<const s8b*>(xh + aoe + ks * 16);
                    if (edge) a = zz;
                    s8b bb = *reinterpret_cast<const s8b*>(wh + wbase + ks * 16);
                    acc = __builtin_amdgcn_mfma_f32_32x32x16_bf16(a, bb, acc, 0, 0, 0);
                    s8b a2 = *reinterpret_cast<const s8b*>(xl + aoe + ks * 16);
                    if (edge) a2 = zz;
                    acc = __builtin_amdgcn_mfma_f32_32x32x16_bf16(a2, bb, acc, 0, 0, 0);
                    s8b b2 = *reinterpret_cast<const s8b*>(wl + wbase + ks * 16);
                    acc = __builtin_amdgcn_mfma_f32_32x32x16_bf16(a, b2, acc, 0, 0, 0);
                }
            }
        }
    }

    const float bv = bias[cout];
#pragma unroll
    for (int r = 0; r < 16; ++r) {
        const int rl = (r & 3) + 8 * (r >> 2) + 4 * half;
        const int ow = 2 * rl + p;
        const size_t oe = (((size_t)((b * 64 + od) * 64 + ohh)) * 64 + ow) * 64 + cout;
        const float y = fmaxf(acc[r] + bv, 0.f);
        const bf16_t hh = f2b(y);
        oh[oe] = hh;
        ol[oe] = f2b(y - b2f(hh));
    }
}

// ---------------- ec0: s2 k=4, CIN=1, fp32 direct, fp32 out -----------------
__global__ __launch_bounds__(256)
void conv_ec0f(const float* __restrict__ in, const float* __restrict__ wt,
               const float* __restrict__ bias, float* __restrict__ out)
{
    const int co  = threadIdx.x;
    const int vox = blockIdx.x * 4 + threadIdx.y;
    const int w = vox % 64; int rem = vox / 64;
    const int h = rem % 64; rem /= 64;
    const int d = rem % 64; rem /= 64;
    const int b = rem;
    float acc = bias[co];
#pragma unroll 1
    for (int kd = 0; kd < 4; ++kd) {
        const int iz = 2 * d + kd - 1;
        if ((unsigned)iz >= 128u) continue;
#pragma unroll 1
        for (int kh = 0; kh < 4; ++kh) {
            const int iy = 2 * h + kh - 1;
            if ((unsigned)iy >= 128u) continue;
#pragma unroll
            for (int kw = 0; kw < 4; ++kw) {
                const int ix = 2 * w + kw - 1;
                if ((unsigned)ix >= 128u) continue;
                const float xv = in[(size_t)((b * 128 + iz) * 128 + iy) * 128 + ix];
                acc = fmaf(xv, wt[((kd * 4 + kh) * 4 + kw) * 64 + co], acc);
            }
        }
    }
    out[(size_t)vox * 64 + co] = fmaxf(acc, 0.f);
}

// ---------------- du1: convT s2 k=4, CIN=64, COUT=1, split-2 in -------------
__global__ __launch_bounds__(256)
void convT_du1b(const bf16_t* __restrict__ inh, const bf16_t* __restrict__ inl,
                const float* __restrict__ wt, const float* __restrict__ bias,
                float* __restrict__ out)
{
    const int vox = blockIdx.x * 256 + threadIdx.x;
    const int ow = vox % 128; int rem = vox / 128;
    const int ohh = rem % 128; rem /= 128;
    const int od = rem % 128; rem /= 128;
    const int b  = rem;
    const int pd = od & 1, dz = od >> 1;
    const int ph = ohh & 1, hy = ohh >> 1;
    const int pw = ow & 1, wx = ow >> 1;
    float acc = bias[0];
#pragma unroll 1
    for (int jd = 0; jd < 2; ++jd) {
        const int kd = pd + 2 * jd, iz = dz + pd - 1 + jd;
        if ((unsigned)iz >= 64u) continue;
#pragma unroll 1
        for (int jh = 0; jh < 2; ++jh) {
            const int kh = ph + 2 * jh, iy = hy + ph - 1 + jh;
            if ((unsigned)iy >= 64u) continue;
#pragma unroll 1
            for (int jw = 0; jw < 2; ++jw) {
                const int kw = pw + 2 * jw, ix = wx + pw - 1 + jw;
                if ((unsigned)ix >= 64u) continue;
                const size_t base = (size_t)(((b * 64 + iz) * 64 + iy) * 64 + ix) * 64;
                const float* wp = wt + (size_t)((kd * 4 + kh) * 4 + kw) * 64;
#pragma unroll
                for (int c8 = 0; c8 < 8; ++c8) {
                    const s8b vh = *reinterpret_cast<const s8b*>(inh + base + c8 * 8);
                    const s8b vl = *reinterpret_cast<const s8b*>(inl + base + c8 * 8);
#pragma unroll
                    for (int j = 0; j < 8; ++j)
                        acc = fmaf(b2f((bf16_t)vh[j]) + b2f((bf16_t)vl[j]), wp[c8 * 8 + j], acc);
                }
            }
        }
    }
    out[vox] = acc;
}

// --------------------------------- VQ ---------------------------------------
__global__ void zero512(float* __restrict__ p) { p[threadIdx.x] = 0.0f; }

__global__ void vq_cnorm(const float* __restrict__ cb, float* __restrict__ cnorm)
{
    const int k = blockIdx.x * 64 + threadIdx.x;
    float s = 0.0f;
    for (int ci = 0; ci < 64; ++ci) { const float c = cb[k * 64 + ci]; s = fmaf(c, c, s); }
    cnorm[k] = s;
}

__global__ __launch_bounds__(256)
void vq_assign(const float* __restrict__ z, const float* __restrict__ cb,
               const float* __restrict__ cnorm, int* __restrict__ idx,
               float* __restrict__ hist, int N)
{
    const int n = blockIdx.x * 256 + threadIdx.x;
    const float4* zp = reinterpret_cast<const float4*>(z + (size_t)n * 64);
    float4 zv[16];
    float z2 = 0.0f;
#pragma unroll
    for (int i = 0; i < 16; ++i) {
        zv[i] = zp[i];
        z2 += zv[i].x * zv[i].x + zv[i].y * zv[i].y + zv[i].z * zv[i].z + zv[i].w * zv[i].w;
    }
    float best = 3.4e38f;
    int bi = 0;
#pragma unroll 1
    for (int k = 0; k < 512; ++k) {
        const float4* cp = reinterpret_cast<const float4*>(cb + (size_t)k * 64);
        float dot = 0.0f;
#pragma unroll
        for (int i = 0; i < 16; ++i) {
            const float4 c = cp[i];
            dot += zv[i].x * c.x + zv[i].y * c.y + zv[i].z * c.z + zv[i].w * c.w;
        }
        const float dist = z2 + cnorm[k] - 2.0f * dot;
        if (dist < best) { best = dist; bi = k; }
    }
    idx[n] = bi;
    atomicAdd(&hist[bi], 1.0f);
}

__global__ __launch_bounds__(256)
void vq_gather_split(const float* __restrict__ cb, const int* __restrict__ idx,
                     bf16_t* __restrict__ zh, bf16_t* __restrict__ zl)
{
    const int gid = blockIdx.x * 256 + threadIdx.x;
    const int n = gid >> 4, c4 = gid & 15;
    const int k = idx[n];
    const float4 c = reinterpret_cast<const float4*>(cb)[k * 16 + c4];
    ushort4 h, l;
    h.x = f2b(c.x); l.x = f2b(c.x - b2f(h.x));
    h.y = f2b(c.y); l.y = f2b(c.y - b2f(h.y));
    h.z = f2b(c.z); l.z = f2b(c.z - b2f(h.z));
    h.w = f2b(c.w); l.w = f2b(c.w - b2f(h.w));
    reinterpret_cast<ushort4*>(zh)[gid] = h;
    reinterpret_cast<ushort4*>(zl)[gid] = l;
}

__global__ __launch_bounds__(512)
void perplexity_k(const float* __restrict__ hist, float* __restrict__ out, float invN)
{
    __shared__ float red[512];
    const int t = threadIdx.x;
    const float p = hist[t] * invN;
    red[t] = p * logf(p + 1e-12f);
    __syncthreads();
    for (int s = 256; s > 0; s >>= 1) {
        if (t < s) red[t] += red[t + s];
        __syncthreads();
    }
    if (t == 0) out[0] = expf(-red[0]);
}

// ---------------------------------------------------------------------------
extern "C" void kernel_launch(void* const* d_in, const int* in_sizes, int n_in,
                              void* d_out, int out_size, void* d_ws, size_t ws_size,
                              hipStream_t stream)
{
    const float* x       = (const float*)d_in[0];
    const float* ec0_w   = (const float*)d_in[1];
    const float* ec0_b   = (const float*)d_in[2];
    const float* er0_c1w = (const float*)d_in[3];
    const float* er0_c1b = (const float*)d_in[4];
    const float* er0_c2w = (const float*)d_in[5];
    const float* er0_c2b = (const float*)d_in[6];
    const float* er0_g   = (const float*)d_in[7];
    const float* er0_be  = (const float*)d_in[8];
    const float* er0_m   = (const float*)d_in[9];
    const float* er0_v   = (const float*)d_in[10];
    const float* er0_a   = (const float*)d_in[11];
    const float* ec1_w   = (const float*)d_in[12];
    const float* ec1_b   = (const float*)d_in[13];
    const float* er1_c1w = (const float*)d_in[14];
    const float* er1_c1b = (const float*)d_in[15];
    const float* er1_c2w = (const float*)d_in[16];
    const float* er1_c2b = (const float*)d_in[17];
    const float* er1_g   = (const float*)d_in[18];
    const float* er1_be  = (const float*)d_in[19];
    const float* er1_m   = (const float*)d_in[20];
    const float* er1_v   = (const float*)d_in[21];
    const float* er1_a   = (const float*)d_in[22];
    const float* eo_w    = (const float*)d_in[23];
    const float* eo_b    = (const float*)d_in[24];
    const float* eo_a    = (const float*)d_in[25];
    const float* cb      = (const float*)d_in[26];
    const float* dc0_w   = (const float*)d_in[27];
    const float* dc0_b   = (const float*)d_in[28];
    const float* dc0_a   = (const float*)d_in[29];
    const float* dr0_c1w = (const float*)d_in[30];
    const float* dr0_c1b = (const float*)d_in[31];
    const float* dr0_c2w = (const float*)d_in[32];
    const float* dr0_c2b = (const float*)d_in[33];
    const float* dr0_g   = (const float*)d_in[34];
    const float* dr0_be  = (const float*)d_in[35];
    const float* dr0_m   = (const float*)d_in[36];
    const float* dr0_v   = (const float*)d_in[37];
    const float* dr0_a   = (const float*)d_in[38];
    const float* du0_w   = (const float*)d_in[39];
    const float* du0_b   = (const float*)d_in[40];
    const float* dr1_c1w = (const float*)d_in[41];
    const float* dr1_c1b = (const float*)d_in[42];
    const float* dr1_c2w = (const float*)d_in[43];
    const float* dr1_c2b = (const float*)d_in[44];
    const float* dr1_g   = (const float*)d_in[45];
    const float* dr1_be  = (const float*)d_in[46];
    const float* dr1_m   = (const float*)d_in[47];
    const float* dr1_v   = (const float*)d_in[48];
    const float* dr1_a   = (const float*)d_in[49];
    const float* du1_w   = (const float*)d_in[50];
    const float* du1_b   = (const float*)d_in[51];

    float* out = (float*)d_out;

    // ---- ws: A=[0,134MB) , H=[134MB,268MB) ----
    char* W = (char*)d_ws;
    float*  Af  = (float*)(W);                          // encoder 64^3 fp32
    float*  Hf  = (float*)(W + 134217728);              // er0 h fp32
    float*  E1f = (float*)(W + 134217728);              // [2,32^3,128] fp32
    float*  R1f = (float*)(W + 134217728 + 33554432);   // er1 h fp32
    float*  Zf  = (float*)(W);                          // z fp32 (A dead)
    int*    IDX = (int*)  (W + 16777216);
    float*  CN  = (float*)(W + 17039360);
    float*  HS  = (float*)(W + 17041408);
    bf16_t* ZQh = (bf16_t*)(W + 33554432);
    bf16_t* ZQl = (bf16_t*)(W + 41943040);
    // decoder 32^3 (A region):
    bf16_t* D0h = (bf16_t*)(W + 50331648);
    bf16_t* D0l = (bf16_t*)(W + 67108864);
    bf16_t* Gh  = (bf16_t*)(W + 83886080);
    bf16_t* Gl  = (bf16_t*)(W + 100663296);
    // decoder 64^3:
    bf16_t* U0h = (bf16_t*)(W + 134217728);             // H region
    bf16_t* U0l = (bf16_t*)(W + 201326592);
    bf16_t* G1h = (bf16_t*)(W);                         // A region
    bf16_t* G1l = (bf16_t*)(W + 67108864);

    // ---- weight arenas in d_out ----
    char* WB = (char*)d_out;
    // encoder split-3:
    bf16_t* e0c1h = (bf16_t*)(WB + 0);
    bf16_t* e0c1m = (bf16_t*)(WB + 221184);
    bf16_t* e0c1l = (bf16_t*)(WB + 442368);
    bf16_t* e0c2h = (bf16_t*)(WB + 663552);
    bf16_t* e0c2m = (bf16_t*)(WB + 884736);
    bf16_t* e0c2l = (bf16_t*)(WB + 1105920);
    bf16_t* ec1h  = (bf16_t*)(WB + 1327104);
    bf16_t* ec1m  = (bf16_t*)(WB + 2375680);
    bf16_t* ec1l  = (bf16_t*)(WB + 3424256);
    bf16_t* e1c1h = (bf16_t*)(WB + 4472832);
    bf16_t* e1c1m = (bf16_t*)(WB + 5357568);
    bf16_t* e1c1l = (bf16_t*)(WB + 6242304);
    bf16_t* e1c2h = (bf16_t*)(WB + 7127040);
    bf16_t* e1c2m = (bf16_t*)(WB + 8011776);
    bf16_t* e1c2l = (bf16_t*)(WB + 8896512);
    bf16_t* eoh   = (bf16_t*)(WB + 9781248);
    bf16_t* eom   = (bf16_t*)(WB + 10223616);
    bf16_t* eol   = (bf16_t*)(WB + 10665984);
    // decoder split-2 (written AFTER encoder finishes, same arena):
    bf16_t* dc0h  = (bf16_t*)(WB + 0);
    bf16_t* dc0l  = (bf16_t*)(WB + 442368);
    bf16_t* d0c1h = (bf16_t*)(WB + 884736);
    bf16_t* d0c1l = (bf16_t*)(WB + 1769472);
    bf16_t* d0c2h = (bf16_t*)(WB + 2654208);
    bf16_t* d0c2l = (bf16_t*)(WB + 3538944);
    bf16_t* du0h  = (bf16_t*)(WB + 4423680);
    bf16_t* du0l  = (bf16_t*)(WB + 5472256);
    bf16_t* d1c1h = (bf16_t*)(WB + 6520832);
    bf16_t* d1c1l = (bf16_t*)(WB + 6742016);
    bf16_t* d1c2h = (bf16_t*)(WB + 6963200);
    bf16_t* d1c2l = (bf16_t*)(WB + 7184384);

    const float* fn = nullptr;
    const bf16_t* bn_ = nullptr;
    bf16_t* bo = nullptr;

    // ---- encoder weight prep (split-3) ----
    wprep3<<<432, 256, 0, stream>>>(er0_c1w, e0c1h, e0c1m, e0c1l, 64, 64, 110592);
    wprep3<<<432, 256, 0, stream>>>(er0_c2w, e0c2h, e0c2m, e0c2l, 64, 64, 110592);
    wprep3<<<2048, 256, 0, stream>>>(ec1_w, ec1h, ec1m, ec1l, 64, 128, 524288);
    wprep3<<<1728, 256, 0, stream>>>(er1_c1w, e1c1h, e1c1m, e1c1l, 128, 128, 442368);
    wprep3<<<1728, 256, 0, stream>>>(er1_c2w, e1c2h, e1c2m, e1c2l, 128, 128, 442368);
    wprep3<<<864, 256, 0, stream>>>(eo_w, eoh, eom, eol, 128, 64, 221184);

    // ---- encoder (fp32-class) ----
    conv_ec0f<<<131072, dim3(64, 4), 0, stream>>>(x, ec0_w, ec0_b, Af);

    conv3s3<64, 64, 2, 2, 64, 1><<<8192, 256, 0, stream>>>(
        Af, e0c1h, e0c1m, e0c1l, er0_c1b, fn, fn, fn, fn, fn, fn, Hf);
    conv3s3<64, 64, 2, 2, 64, 3><<<8192, 256, 0, stream>>>(
        Hf, e0c2h, e0c2m, e0c2l, er0_c2b, er0_g, er0_be, er0_m, er0_v, er0_a, Af, Af);

    convs2m3<<<2048, 256, 0, stream>>>(Af, ec1h, ec1m, ec1l, ec1_b, E1f);

    conv3s3<128, 128, 1, 4, 32, 1><<<2048, 256, 0, stream>>>(
        E1f, e1c1h, e1c1m, e1c1l, er1_c1b, fn, fn, fn, fn, fn, fn, R1f);
    conv3s3<128, 128, 1, 4, 32, 3><<<2048, 256, 0, stream>>>(
        R1f, e1c2h, e1c2m, e1c2l, er1_c2b, er1_g, er1_be, er1_m, er1_v, er1_a, E1f, E1f);

    conv3s3<128, 64, 1, 2, 32, 2><<<2048, 128, 0, stream>>>(
        E1f, eoh, eom, eol, eo_b, fn, fn, fn, fn, eo_a, fn, Zf);

    // ---- VQ (exact fp32) ----
    vq_cnorm<<<8, 64, 0, stream>>>(cb, CN);
    zero512<<<1, 512, 0, stream>>>(HS);
    vq_assign<<<256, 256, 0, stream>>>(Zf, cb, CN, IDX, HS, 65536);
    perplexity_k<<<1, 512, 0, stream>>>(HS, out + 4194304, 1.0f / 65536.0f);
    vq_gather_split<<<4096, 256, 0, stream>>>(cb, IDX, ZQh, ZQl);

    // ---- decoder weight prep (split-2, overwrites encoder arena) ----
    wprep_split<<<864, 256, 0, stream>>>(dc0_w, dc0h, dc0l, 64, 128, 221184);
    wprep_split<<<1728, 256, 0, stream>>>(dr0_c1w, d0c1h, d0c1l, 128, 128, 442368);
    wprep_split<<<1728, 256, 0, stream>>>(dr0_c2w, d0c2h, d0c2l, 128, 128, 442368);
    wprep_split<<<2048, 256, 0, stream>>>(du0_w, du0h, du0l, 128, 64, 524288);
    wprep_split<<<432, 256, 0, stream>>>(dr1_c1w, d1c1h, d1c1l, 64, 64, 110592);
    wprep_split<<<432, 256, 0, stream>>>(dr1_c2w, d1c2h, d1c2l, 64, 64, 110592);

    // ---- decoder (split-2 bf16) ----
    conv3m<64, 128, 1, 4, 32, 2, true, 1><<<2048, 256, 0, stream>>>(
        ZQh, ZQl, dc0h, dc0l, dc0_b, fn, fn, fn, fn, dc0_a, bn_, bn_, D0h, D0l);
    conv3m<128, 128, 1, 4, 32, 1, true, 1><<<2048, 256, 0, stream>>>(
        D0h, D0l, d0c1h, d0c1l, dr0_c1b, fn, fn, fn, fn, fn, bn_, bn_, Gh, Gl);
    conv3m<128, 128, 1, 4, 32, 3, true, 1><<<2048, 256, 0, stream>>>(
        Gh, Gl, d0c2h, d0c2l, dr0_c2b, dr0_g, dr0_be, dr0_m, dr0_v, dr0_a,
        D0h, D0l, D0h, D0l);

    convTm<<<8192, 256, 0, stream>>>(D0h, D0l, du0h, du0l, du0_b, U0h, U0l);

    conv3m<64, 64, 2, 2, 64, 1, true, 1><<<8192, 256, 0, stream>>>(
        U0h, U0l, d1c1h, d1c1l, dr1_c1b, fn, fn, fn, fn, fn, bn_, bn_, G1h, G1l);
    conv3m<64, 64, 2, 2, 64, 3, true, 1><<<8192, 256, 0, stream>>>(
        G1h, G1l, d1c2h, d1c2l, dr1_c2b, dr1_g, dr1_be, dr1_m, dr1_v, dr1_a,
        U0h, U0l, U0h, U0l);

    convT_du1b<<<16384, 256, 0, stream>>>(U0h, U0l, du1_w, du1_b, out);
}

// Round 6
// 13466.269 us; speedup vs baseline: 4.6306x; 1.1883x over previous
//
#include <hip/hip_runtime.h>
#include <cstdint>

// ---------------------------------------------------------------------------
// VQVAE forward — MFMA implicit-GEMM convolutions, channels-last.
//
// Encoder: fp32 activations in memory; in-register EXACT 3-way bf16 split
//   (v = h+m+l bit-exact) + 6-MFMA products => fp32-class => VQ argmin safe.
// Decoder: split-2 bf16 (hi/lo) storage, 3-pass MFMA (~2^-17 rel/layer).
//
// Round-6 structure: wave tile = 32 voxels x 64 couts (N2=2), 4 independent
// accumulator chains per wave (accA/accB x n2) to break MFMA dep-latency
// serialization; blocks = 2 waves (128 thr) covering one row x full COUT.
//
// C layout: col = lane&31, row = (reg&3) + 8*(reg>>2) + 4*(lane>>5)  [m101]
// ws layout and weight arenas identical to round 5 (proven).
// ---------------------------------------------------------------------------

typedef unsigned short bf16_t;
typedef __attribute__((ext_vector_type(8)))  short s8b;     // 8 x bf16 frag
typedef __attribute__((ext_vector_type(16))) float f32x16;  // 32x32 acc

__device__ __forceinline__ float b2f(bf16_t u) { return __uint_as_float((unsigned)u << 16); }
__device__ __forceinline__ bf16_t f2b(float f) {
    unsigned x = __float_as_uint(f);
    return (bf16_t)((x + 0x7FFFu + ((x >> 16) & 1u)) >> 16);
}

// exact 3-way split of 8 fp32 (two float4) into bf16 h/m/l frags
__device__ __forceinline__ void split3v(const float4 a, const float4 b,
                                        s8b& h, s8b& m, s8b& l)
{
    float v[8] = {a.x, a.y, a.z, a.w, b.x, b.y, b.z, b.w};
#pragma unroll
    for (int j = 0; j < 8; ++j) {
        const unsigned uv = __float_as_uint(v[j]);
        const float fh = __uint_as_float(uv & 0xFFFF0000u);
        const float r1 = v[j] - fh;
        const unsigned u1 = __float_as_uint(r1);
        const float fm = __uint_as_float(u1 & 0xFFFF0000u);
        const float r2 = r1 - fm;
        h[j] = (short)(uv >> 16);
        m[j] = (short)(u1 >> 16);
        l[j] = (short)(__float_as_uint(r2) >> 16);
    }
}

// ------------------------- weight prep ------------------------------------
__global__ __launch_bounds__(256)
void wprep3(const float* __restrict__ w, bf16_t* __restrict__ h,
            bf16_t* __restrict__ m, bf16_t* __restrict__ l,
            int ci, int co, int n)
{
    const int i = blockIdx.x * 256 + threadIdx.x;
    if (i >= n) return;
    const int co_ = i % co;
    const int ci_ = (i / co) % ci;
    const int tap = i / (co * ci);
    const int dst = (tap * co + co_) * ci + ci_;
    const float v = w[i];
    const unsigned uv = __float_as_uint(v);
    const float fh = __uint_as_float(uv & 0xFFFF0000u);
    const float r1 = v - fh;
    const unsigned u1 = __float_as_uint(r1);
    const float fm = __uint_as_float(u1 & 0xFFFF0000u);
    const float r2 = r1 - fm;
    h[dst] = (bf16_t)(uv >> 16);
    m[dst] = (bf16_t)(u1 >> 16);
    l[dst] = (bf16_t)(__float_as_uint(r2) >> 16);
}

__global__ __launch_bounds__(256)
void wprep_split(const float* __restrict__ w, bf16_t* __restrict__ hi,
                 bf16_t* __restrict__ lo, int ci, int co, int n)
{
    const int i = blockIdx.x * 256 + threadIdx.x;
    if (i >= n) return;
    const int co_ = i % co;
    const int ci_ = (i / co) % ci;
    const int tap = i / (co * ci);
    const float v = w[i];
    const int dst = (tap * co + co_) * ci + ci_;
    const bf16_t h = f2b(v);
    hi[dst] = h;
    lo[dst] = f2b(v - b2f(h));
}

// ---------------- encoder 3x3x3 conv: fp32 in/out, split-3, tiled -----------
// Wave tile: 32 voxels x 64 couts (n2=0,1). Block: (SD/32) M-waves x NW N-waves.
// EPI: 0=ReLU 1=swish 2=PReLU 3=BN+PReLU+skip+ReLU
template<int CIN, int COUT, int SD, int NW, int EPI>
__global__ __launch_bounds__((SD / 32) * NW * 64)
void conv3e(const float* __restrict__ xf,
            const bf16_t* __restrict__ wh, const bf16_t* __restrict__ wm,
            const bf16_t* __restrict__ wl,
            const float* __restrict__ bias,
            const float* __restrict__ g, const float* __restrict__ be,
            const float* __restrict__ mn, const float* __restrict__ vr,
            const float* __restrict__ al,
            const float* skf, float* __restrict__ of)
{
    const int lane = threadIdx.x & 63;
    const int wid  = threadIdx.x >> 6;
    const int wn   = wid % NW, wm2 = wid / NW;
    const int half = lane >> 5, ln = lane & 31;
    const int w    = wm2 * 32 + ln;
    const int bid  = blockIdx.x;
    const int h    = bid % SD;
    const int d    = (bid / SD) % SD;
    const int b    = bid / (SD * SD);
    const size_t boff = (size_t)(wn * 64 + ln) * CIN + half * 8;

    f32x16 accA[2], accB[2];
#pragma unroll
    for (int i = 0; i < 16; ++i) {
        accA[0][i] = 0.f; accA[1][i] = 0.f;
        accB[0][i] = 0.f; accB[1][i] = 0.f;
    }

#pragma unroll 1
    for (int kd = 0; kd < 3; ++kd) {
        const int iz = d + kd - 1;
        if ((unsigned)iz >= (unsigned)SD) continue;
#pragma unroll 1
        for (int kh = 0; kh < 3; ++kh) {
            const int iy = h + kh - 1;
            if ((unsigned)iy >= (unsigned)SD) continue;
            const size_t rowb = ((size_t)((b * SD + iz) * SD + iy)) * SD;
#pragma unroll
            for (int kw = 0; kw < 3; ++kw) {
                const int iw = w + kw - 1;
                const bool edge = (unsigned)iw >= (unsigned)SD;
                const int wcl = edge ? w : iw;
                const size_t aoe = (rowb + wcl) * CIN + half * 8;
                const size_t wbase = (size_t)((kd * 3 + kh) * 3 + kw) * CIN * COUT + boff;
#pragma unroll
                for (int ks = 0; ks < CIN / 16; ++ks) {
                    float4 a0 = *reinterpret_cast<const float4*>(xf + aoe + ks * 16);
                    float4 a1 = *reinterpret_cast<const float4*>(xf + aoe + ks * 16 + 4);
                    if (edge) { a0 = make_float4(0,0,0,0); a1 = make_float4(0,0,0,0); }
                    s8b ah, am, al3;
                    split3v(a0, a1, ah, am, al3);
#pragma unroll
                    for (int n2 = 0; n2 < 2; ++n2) {
                        const size_t wb = wbase + (size_t)n2 * 32 * CIN + ks * 16;
                        const s8b bh = *reinterpret_cast<const s8b*>(wh + wb);
                        const s8b bm = *reinterpret_cast<const s8b*>(wm + wb);
                        const s8b bl = *reinterpret_cast<const s8b*>(wl + wb);
                        accA[n2] = __builtin_amdgcn_mfma_f32_32x32x16_bf16(ah, bh, accA[n2], 0, 0, 0);
                        accB[n2] = __builtin_amdgcn_mfma_f32_32x32x16_bf16(ah, bm, accB[n2], 0, 0, 0);
                        accA[n2] = __builtin_amdgcn_mfma_f32_32x32x16_bf16(am, bh, accA[n2], 0, 0, 0);
                        accB[n2] = __builtin_amdgcn_mfma_f32_32x32x16_bf16(am, bm, accB[n2], 0, 0, 0);
                        accA[n2] = __builtin_amdgcn_mfma_f32_32x32x16_bf16(al3, bh, accA[n2], 0, 0, 0);
                        accB[n2] = __builtin_amdgcn_mfma_f32_32x32x16_bf16(ah, bl, accB[n2], 0, 0, 0);
                    }
                }
            }
        }
    }

    const size_t outrow = ((size_t)((b * SD + d) * SD + h)) * SD;
#pragma unroll
    for (int n2 = 0; n2 < 2; ++n2) {
        const int cout = wn * 64 + n2 * 32 + ln;
        const float bv = bias[cout];
        float sc = 0.f, mm = 0.f, bb2 = 0.f, aa = 0.f;
        if constexpr (EPI == 3) {
            sc = g[cout] * (1.0f / sqrtf(vr[cout] + 1e-3f));
            mm = mn[cout]; bb2 = be[cout]; aa = al[cout];
        }
        if constexpr (EPI == 2) aa = al[cout];
#pragma unroll
        for (int r = 0; r < 16; ++r) {
            const int rl = (r & 3) + 8 * (r >> 2) + 4 * half;
            const size_t oe = (outrow + wm2 * 32 + rl) * COUT + cout;
            float y = accA[n2][r] + accB[n2][r] + bv;
            if constexpr (EPI == 0) y = fmaxf(y, 0.f);
            else if constexpr (EPI == 1) y = y / (1.f + expf(-y));
            else if constexpr (EPI == 2) y = y > 0.f ? y : aa * y;
            else {
                float t2 = (y - mm) * sc + bb2;
                t2 = t2 > 0.f ? t2 : aa * t2;
                y = fmaxf(skf[oe] + t2, 0.f);
            }
            of[oe] = y;
        }
    }
}

// ---------------- ec1: stride-2 k=4, fp32 in/out, split-3, tiled ------------
__global__ __launch_bounds__(128)
void convs2e(const float* __restrict__ xf,
             const bf16_t* __restrict__ wh, const bf16_t* __restrict__ wm,
             const bf16_t* __restrict__ wl,
             const float* __restrict__ bias, float* __restrict__ of)
{
    const int lane = threadIdx.x & 63;
    const int wn   = threadIdx.x >> 6;         // 2 waves x 64 couts
    const int half = lane >> 5, ln = lane & 31;
    const int bid  = blockIdx.x;
    const int h    = bid % 32;
    const int d    = (bid / 32) % 32;
    const int b    = bid / 1024;
    const size_t boff = (size_t)(wn * 64 + ln) * 64 + half * 8;

    f32x16 accA[2], accB[2];
#pragma unroll
    for (int i = 0; i < 16; ++i) {
        accA[0][i] = 0.f; accA[1][i] = 0.f;
        accB[0][i] = 0.f; accB[1][i] = 0.f;
    }

#pragma unroll 1
    for (int kd = 0; kd < 4; ++kd) {
        const int iz = 2 * d + kd - 1;
        if ((unsigned)iz >= 64u) continue;
#pragma unroll 1
        for (int kh = 0; kh < 4; ++kh) {
            const int iy = 2 * h + kh - 1;
            if ((unsigned)iy >= 64u) continue;
            const size_t rowb = ((size_t)((b * 64 + iz) * 64 + iy)) * 64;
#pragma unroll
            for (int kw = 0; kw < 4; ++kw) {
                const int iw = 2 * ln + kw - 1;
                const bool edge = (unsigned)iw >= 64u;
                const int wcl = edge ? 2 * ln : iw;
                const size_t aoe = (rowb + wcl) * 64 + half * 8;
                const size_t wbase = (size_t)((kd * 4 + kh) * 4 + kw) * 64 * 128 + boff;
#pragma unroll
                for (int ks = 0; ks < 4; ++ks) {
                    float4 a0 = *reinterpret_cast<const float4*>(xf + aoe + ks * 16);
                    float4 a1 = *reinterpret_cast<const float4*>(xf + aoe + ks * 16 + 4);
                    if (edge) { a0 = make_float4(0,0,0,0); a1 = make_float4(0,0,0,0); }
                    s8b ah, am, al3;
                    split3v(a0, a1, ah, am, al3);
#pragma unroll
                    for (int n2 = 0; n2 < 2; ++n2) {
                        const size_t wb = wbase + (size_t)n2 * 32 * 64 + ks * 16;
                        const s8b bh = *reinterpret_cast<const s8b*>(wh + wb);
                        const s8b bm = *reinterpret_cast<const s8b*>(wm + wb);
                        const s8b bl = *reinterpret_cast<const s8b*>(wl + wb);
                        accA[n2] = __builtin_amdgcn_mfma_f32_32x32x16_bf16(ah, bh, accA[n2], 0, 0, 0);
                        accB[n2] = __builtin_amdgcn_mfma_f32_32x32x16_bf16(ah, bm, accB[n2], 0, 0, 0);
                        accA[n2] = __builtin_amdgcn_mfma_f32_32x32x16_bf16(am, bh, accA[n2], 0, 0, 0);
                        accB[n2] = __builtin_amdgcn_mfma_f32_32x32x16_bf16(am, bm, accB[n2], 0, 0, 0);
                        accA[n2] = __builtin_amdgcn_mfma_f32_32x32x16_bf16(al3, bh, accA[n2], 0, 0, 0);
                        accB[n2] = __builtin_amdgcn_mfma_f32_32x32x16_bf16(ah, bl, accB[n2], 0, 0, 0);
                    }
                }
            }
        }
    }

    const size_t outrow = ((size_t)((b * 32 + d) * 32 + h)) * 32;
#pragma unroll
    for (int n2 = 0; n2 < 2; ++n2) {
        const int cout = wn * 64 + n2 * 32 + ln;
        const float bv = bias[cout];
#pragma unroll
        for (int r = 0; r < 16; ++r) {
            const int rl = (r & 3) + 8 * (r >> 2) + 4 * half;
            const size_t oe = (outrow + rl) * 128 + cout;
            of[oe] = fmaxf(accA[n2][r] + accB[n2][r] + bv, 0.f);
        }
    }
}

// ---------------- decoder 3x3x3 conv: split-2 bf16, tiled -------------------
template<int CIN, int COUT, int SD, int NW, int EPI>
__global__ __launch_bounds__((SD / 32) * NW * 64)
void conv3d(const bf16_t* __restrict__ xh, const bf16_t* __restrict__ xl,
            const bf16_t* __restrict__ wh, const bf16_t* __restrict__ wl,
            const float* __restrict__ bias,
            const float* __restrict__ g, const float* __restrict__ be,
            const float* __restrict__ mn, const float* __restrict__ vr,
            const float* __restrict__ al,
            const bf16_t* skh, const bf16_t* skl,
            bf16_t* oh, bf16_t* ol)
{
    const int lane = threadIdx.x & 63;
    const int wid  = threadIdx.x >> 6;
    const int wn   = wid % NW, wm2 = wid / NW;
    const int half = lane >> 5, ln = lane & 31;
    const int w    = wm2 * 32 + ln;
    const int bid  = blockIdx.x;
    const int h    = bid % SD;
    const int d    = (bid / SD) % SD;
    const int b    = bid / (SD * SD);
    const size_t boff = (size_t)(wn * 64 + ln) * CIN + half * 8;

    f32x16 accA[2], accB[2];
#pragma unroll
    for (int i = 0; i < 16; ++i) {
        accA[0][i] = 0.f; accA[1][i] = 0.f;
        accB[0][i] = 0.f; accB[1][i] = 0.f;
    }

#pragma unroll 1
    for (int kd = 0; kd < 3; ++kd) {
        const int iz = d + kd - 1;
        if ((unsigned)iz >= (unsigned)SD) continue;
#pragma unroll 1
        for (int kh = 0; kh < 3; ++kh) {
            const int iy = h + kh - 1;
            if ((unsigned)iy >= (unsigned)SD) continue;
            const size_t rowb = ((size_t)((b * SD + iz) * SD + iy)) * SD;
#pragma unroll
            for (int kw = 0; kw < 3; ++kw) {
                const int iw = w + kw - 1;
                const bool edge = (unsigned)iw >= (unsigned)SD;
                const int wcl = edge ? w : iw;
                const size_t aoe = (rowb + wcl) * CIN + half * 8;
                const size_t wbase = (size_t)((kd * 3 + kh) * 3 + kw) * CIN * COUT + boff;
                const s8b zz = {};
#pragma unroll
                for (int ks = 0; ks < CIN / 16; ++ks) {
                    s8b ah = *reinterpret_cast<const s8b*>(xh + aoe + ks * 16);
                    s8b al2 = *reinterpret_cast<const s8b*>(xl + aoe + ks * 16);
                    if (edge) { ah = zz; al2 = zz; }
#pragma unroll
                    for (int n2 = 0; n2 < 2; ++n2) {
                        const size_t wb = wbase + (size_t)n2 * 32 * CIN + ks * 16;
                        const s8b bh = *reinterpret_cast<const s8b*>(wh + wb);
                        const s8b bl = *reinterpret_cast<const s8b*>(wl + wb);
                        accA[n2] = __builtin_amdgcn_mfma_f32_32x32x16_bf16(ah, bh, accA[n2], 0, 0, 0);
                        accB[n2] = __builtin_amdgcn_mfma_f32_32x32x16_bf16(al2, bh, accB[n2], 0, 0, 0);
                        accB[n2] = __builtin_amdgcn_mfma_f32_32x32x16_bf16(ah, bl, accB[n2], 0, 0, 0);
                    }
                }
            }
        }
    }

    const size_t outrow = ((size_t)((b * SD + d) * SD + h)) * SD;
#pragma unroll
    for (int n2 = 0; n2 < 2; ++n2) {
        const int cout = wn * 64 + n2 * 32 + ln;
        const float bv = bias[cout];
        float sc = 0.f, mm = 0.f, bb2 = 0.f, aa = 0.f;
        if constexpr (EPI == 3) {
            sc = g[cout] * (1.0f / sqrtf(vr[cout] + 1e-3f));
            mm = mn[cout]; bb2 = be[cout]; aa = al[cout];
        }
        if constexpr (EPI == 2) aa = al[cout];
#pragma unroll
        for (int r = 0; r < 16; ++r) {
            const int rl = (r & 3) + 8 * (r >> 2) + 4 * half;
            const size_t oe = (outrow + wm2 * 32 + rl) * COUT + cout;
            float y = accA[n2][r] + accB[n2][r] + bv;
            if constexpr (EPI == 0) y = fmaxf(y, 0.f);
            else if constexpr (EPI == 1) y = y / (1.f + expf(-y));
            else if constexpr (EPI == 2) y = y > 0.f ? y : aa * y;
            else {
                float t2 = (y - mm) * sc + bb2;
                t2 = t2 > 0.f ? t2 : aa * t2;
                float sv = b2f(skh[oe]) + b2f(skl[oe]);
                y = fmaxf(sv + t2, 0.f);
            }
            const bf16_t hh = f2b(y);
            oh[oe] = hh;
            ol[oe] = f2b(y - b2f(hh));
        }
    }
}

// ---------------- convT stride-2 k=4 (du0, split-2) -------------------------
__global__ __launch_bounds__(256)
void convTm(const bf16_t* __restrict__ xh, const bf16_t* __restrict__ xl,
            const bf16_t* __restrict__ wh, const bf16_t* __restrict__ wl,
            const float* __restrict__ bias,
            bf16_t* __restrict__ oh, bf16_t* __restrict__ ol)
{
    const int lane = threadIdx.x & 63;
    const int wid  = threadIdx.x >> 6;
    const int wn   = wid & 1, p = wid >> 1;
    const int half = lane >> 5, ln = lane & 31;
    const int bid  = blockIdx.x;
    const int ohh  = bid % 64;
    const int od   = (bid / 64) % 64;
    const int b    = bid / 4096;
    const int pd = od & 1, dz = od >> 1;
    const int ph = ohh & 1, hy = ohh >> 1;
    const int cout = wn * 32 + ln;
    const int boff = cout * 128 + half * 8;

    f32x16 accA, accB;
#pragma unroll
    for (int i = 0; i < 16; ++i) { accA[i] = 0.0f; accB[i] = 0.0f; }

#pragma unroll 1
    for (int jd = 0; jd < 2; ++jd) {
        const int kd = pd + 2 * jd;
        const int iz = dz + pd - 1 + jd;
        if ((unsigned)iz >= 32u) continue;
#pragma unroll 1
        for (int jh = 0; jh < 2; ++jh) {
            const int kh = ph + 2 * jh;
            const int iy = hy + ph - 1 + jh;
            if ((unsigned)iy >= 32u) continue;
            const size_t rowb = ((size_t)((b * 32 + iz) * 32 + iy)) * 32;
#pragma unroll
            for (int jw = 0; jw < 2; ++jw) {
                const int kw = p + 2 * jw;
                const int ix = ln + p - 1 + jw;
                const bool edge = (unsigned)ix >= 32u;
                const int xcl = edge ? ln : ix;
                const size_t aoe = (rowb + xcl) * 128 + half * 8;
                const size_t wbase = (size_t)((kd * 4 + kh) * 4 + kw) * 128 * 64 + boff;
                const s8b zz = {};
#pragma unroll
                for (int ks = 0; ks < 8; ++ks) {
                    s8b a = *reinterpret_cast<const s8b*>(xh + aoe + ks * 16);
                    s8b a2 = *reinterpret_cast<const s8b*>(xl + aoe + ks * 16);
                    if (edge) { a = zz; a2 = zz; }
                    const s8b bb = *reinterpret_cast<const s8b*>(wh + wbase + ks * 16);
                    const s8b b2 = *reinterpret_cast<const s8b*>(wl + wbase + ks * 16);
                    accA = __builtin_amdgcn_mfma_f32_32x32x16_bf16(a, bb, accA, 0, 0, 0);
                    accB = __builtin_amdgcn_mfma_f32_32x32x16_bf16(a2, bb, accB, 0, 0, 0);
                    accB = __builtin_amdgcn_mfma_f32_32x32x16_bf16(a, b2, accB, 0, 0, 0);
                }
            }
        }
    }

    const float bv = bias[cout];
#pragma unroll
    for (int r = 0; r < 16; ++r) {
        const int rl = (r & 3) + 8 * (r >> 2) + 4 * half;
        const int ow = 2 * rl + p;
        const size_t oe = (((size_t)((b * 64 + od) * 64 + ohh)) * 64 + ow) * 64 + cout;
        const float y = fmaxf(accA[r] + accB[r] + bv, 0.f);
        const bf16_t hh = f2b(y);
        oh[oe] = hh;
        ol[oe] = f2b(y - b2f(hh));
    }
}

// ---------------- ec0: s2 k=4, CIN=1, fp32 direct, fp32 out -----------------
__global__ __launch_bounds__(256)
void conv_ec0f(const float* __restrict__ in, const float* __restrict__ wt,
               const float* __restrict__ bias, float* __restrict__ out)
{
    const int co  = threadIdx.x;
    const int vox = blockIdx.x * 4 + threadIdx.y;
    const int w = vox % 64; int rem = vox / 64;
    const int h = rem % 64; rem /= 64;
    const int d = rem % 64; rem /= 64;
    const int b = rem;
    float acc = bias[co];
#pragma unroll 1
    for (int kd = 0; kd < 4; ++kd) {
        const int iz = 2 * d + kd - 1;
        if ((unsigned)iz >= 128u) continue;
#pragma unroll 1
        for (int kh = 0; kh < 4; ++kh) {
            const int iy = 2 * h + kh - 1;
            if ((unsigned)iy >= 128u) continue;
#pragma unroll
            for (int kw = 0; kw < 4; ++kw) {
                const int ix = 2 * w + kw - 1;
                if ((unsigned)ix >= 128u) continue;
                const float xv = in[(size_t)((b * 128 + iz) * 128 + iy) * 128 + ix];
                acc = fmaf(xv, wt[((kd * 4 + kh) * 4 + kw) * 64 + co], acc);
            }
        }
    }
    out[(size_t)vox * 64 + co] = fmaxf(acc, 0.f);
}

// ---------------- du1: convT s2 k=4, CIN=64, COUT=1, split-2 in -------------
__global__ __launch_bounds__(256)
void convT_du1b(const bf16_t* __restrict__ inh, const bf16_t* __restrict__ inl,
                const float* __restrict__ wt, const float* __restrict__ bias,
                float* __restrict__ out)
{
    const int vox = blockIdx.x * 256 + threadIdx.x;
    const int ow = vox % 128; int rem = vox / 128;
    const int ohh = rem % 128; rem /= 128;
    const int od = rem % 128; rem /= 128;
    const int b  = rem;
    const int pd = od & 1, dz = od >> 1;
    const int ph = ohh & 1, hy = ohh >> 1;
    const int pw = ow & 1, wx = ow >> 1;
    float acc = bias[0];
#pragma unroll 1
    for (int jd = 0; jd < 2; ++jd) {
        const int kd = pd + 2 * jd, iz = dz + pd - 1 + jd;
        if ((unsigned)iz >= 64u) continue;
#pragma unroll 1
        for (int jh = 0; jh < 2; ++jh) {
            const int kh = ph + 2 * jh, iy = hy + ph - 1 + jh;
            if ((unsigned)iy >= 64u) continue;
#pragma unroll 1
            for (int jw = 0; jw < 2; ++jw) {
                const int kw = pw + 2 * jw, ix = wx + pw - 1 + jw;
                if ((unsigned)ix >= 64u) continue;
                const size_t base = (size_t)(((b * 64 + iz) * 64 + iy) * 64 + ix) * 64;
                const float* wp = wt + (size_t)((kd * 4 + kh) * 4 + kw) * 64;
#pragma unroll
                for (int c8 = 0; c8 < 8; ++c8) {
                    const s8b vh = *reinterpret_cast<const s8b*>(inh + base + c8 * 8);
                    const s8b vl = *reinterpret_cast<const s8b*>(inl + base + c8 * 8);
#pragma unroll
                    for (int j = 0; j < 8; ++j)
                        acc = fmaf(b2f((bf16_t)vh[j]) + b2f((bf16_t)vl[j]), wp[c8 * 8 + j], acc);
                }
            }
        }
    }
    out[vox] = acc;
}

// --------------------------------- VQ ---------------------------------------
__global__ void zero512(float* __restrict__ p) { p[threadIdx.x] = 0.0f; }

__global__ void vq_cnorm(const float* __restrict__ cb, float* __restrict__ cnorm)
{
    const int k = blockIdx.x * 64 + threadIdx.x;
    float s = 0.0f;
    for (int ci = 0; ci < 64; ++ci) { const float c = cb[k * 64 + ci]; s = fmaf(c, c, s); }
    cnorm[k] = s;
}

__global__ __launch_bounds__(256)
void vq_assign(const float* __restrict__ z, const float* __restrict__ cb,
               const float* __restrict__ cnorm, int* __restrict__ idx,
               float* __restrict__ hist, int N)
{
    const int n = blockIdx.x * 256 + threadIdx.x;
    const float4* zp = reinterpret_cast<const float4*>(z + (size_t)n * 64);
    float4 zv[16];
    float z2 = 0.0f;
#pragma unroll
    for (int i = 0; i < 16; ++i) {
        zv[i] = zp[i];
        z2 += zv[i].x * zv[i].x + zv[i].y * zv[i].y + zv[i].z * zv[i].z + zv[i].w * zv[i].w;
    }
    float best = 3.4e38f;
    int bi = 0;
#pragma unroll 1
    for (int k = 0; k < 512; ++k) {
        const float4* cp = reinterpret_cast<const float4*>(cb + (size_t)k * 64);
        float dot = 0.0f;
#pragma unroll
        for (int i = 0; i < 16; ++i) {
            const float4 c = cp[i];
            dot += zv[i].x * c.x + zv[i].y * c.y + zv[i].z * c.z + zv[i].w * c.w;
        }
        const float dist = z2 + cnorm[k] - 2.0f * dot;
        if (dist < best) { best = dist; bi = k; }
    }
    idx[n] = bi;
    atomicAdd(&hist[bi], 1.0f);
}

__global__ __launch_bounds__(256)
void vq_gather_split(const float* __restrict__ cb, const int* __restrict__ idx,
                     bf16_t* __restrict__ zh, bf16_t* __restrict__ zl)
{
    const int gid = blockIdx.x * 256 + threadIdx.x;
    const int n = gid >> 4, c4 = gid & 15;
    const int k = idx[n];
    const float4 c = reinterpret_cast<const float4*>(cb)[k * 16 + c4];
    ushort4 h, l;
    h.x = f2b(c.x); l.x = f2b(c.x - b2f(h.x));
    h.y = f2b(c.y); l.y = f2b(c.y - b2f(h.y));
    h.z = f2b(c.z); l.z = f2b(c.z - b2f(h.z));
    h.w = f2b(c.w); l.w = f2b(c.w - b2f(h.w));
    reinterpret_cast<ushort4*>(zh)[gid] = h;
    reinterpret_cast<ushort4*>(zl)[gid] = l;
}

__global__ __launch_bounds__(512)
void perplexity_k(const float* __restrict__ hist, float* __restrict__ out, float invN)
{
    __shared__ float red[512];
    const int t = threadIdx.x;
    const float p = hist[t] * invN;
    red[t] = p * logf(p + 1e-12f);
    __syncthreads();
    for (int s = 256; s > 0; s >>= 1) {
        if (t < s) red[t] += red[t + s];
        __syncthreads();
    }
    if (t == 0) out[0] = expf(-red[0]);
}

// ---------------------------------------------------------------------------
extern "C" void kernel_launch(void* const* d_in, const int* in_sizes, int n_in,
                              void* d_out, int out_size, void* d_ws, size_t ws_size,
                              hipStream_t stream)
{
    const float* x       = (const float*)d_in[0];
    const float* ec0_w   = (const float*)d_in[1];
    const float* ec0_b   = (const float*)d_in[2];
    const float* er0_c1w = (const float*)d_in[3];
    const float* er0_c1b = (const float*)d_in[4];
    const float* er0_c2w = (const float*)d_in[5];
    const float* er0_c2b = (const float*)d_in[6];
    const float* er0_g   = (const float*)d_in[7];
    const float* er0_be  = (const float*)d_in[8];
    const float* er0_m   = (const float*)d_in[9];
    const float* er0_v   = (const float*)d_in[10];
    const float* er0_a   = (const float*)d_in[11];
    const float* ec1_w   = (const float*)d_in[12];
    const float* ec1_b   = (const float*)d_in[13];
    const float* er1_c1w = (const float*)d_in[14];
    const float* er1_c1b = (const float*)d_in[15];
    const float* er1_c2w = (const float*)d_in[16];
    const float* er1_c2b = (const float*)d_in[17];
    const float* er1_g   = (const float*)d_in[18];
    const float* er1_be  = (const float*)d_in[19];
    const float* er1_m   = (const float*)d_in[20];
    const float* er1_v   = (const float*)d_in[21];
    const float* er1_a   = (const float*)d_in[22];
    const float* eo_w    = (const float*)d_in[23];
    const float* eo_b    = (const float*)d_in[24];
    const float* eo_a    = (const float*)d_in[25];
    const float* cb      = (const float*)d_in[26];
    const float* dc0_w   = (const float*)d_in[27];
    const float* dc0_b   = (const float*)d_in[28];
    const float* dc0_a   = (const float*)d_in[29];
    const float* dr0_c1w = (const float*)d_in[30];
    const float* dr0_c1b = (const float*)d_in[31];
    const float* dr0_c2w = (const float*)d_in[32];
    const float* dr0_c2b = (const float*)d_in[33];
    const float* dr0_g   = (const float*)d_in[34];
    const float* dr0_be  = (const float*)d_in[35];
    const float* dr0_m   = (const float*)d_in[36];
    const float* dr0_v   = (const float*)d_in[37];
    const float* dr0_a   = (const float*)d_in[38];
    const float* du0_w   = (const float*)d_in[39];
    const float* du0_b   = (const float*)d_in[40];
    const float* dr1_c1w = (const float*)d_in[41];
    const float* dr1_c1b = (const float*)d_in[42];
    const float* dr1_c2w = (const float*)d_in[43];
    const float* dr1_c2b = (const float*)d_in[44];
    const float* dr1_g   = (const float*)d_in[45];
    const float* dr1_be  = (const float*)d_in[46];
    const float* dr1_m   = (const float*)d_in[47];
    const float* dr1_v   = (const float*)d_in[48];
    const float* dr1_a   = (const float*)d_in[49];
    const float* du1_w   = (const float*)d_in[50];
    const float* du1_b   = (const float*)d_in[51];

    float* out = (float*)d_out;

    // ---- ws: A=[0,134MB) , H=[134MB,268MB) ----
    char* W = (char*)d_ws;
    float*  Af  = (float*)(W);                          // encoder 64^3 fp32
    float*  Hf  = (float*)(W + 134217728);              // er0 h fp32
    float*  E1f = (float*)(W + 134217728);              // [2,32^3,128] fp32
    float*  R1f = (float*)(W + 134217728 + 33554432);   // er1 h fp32
    float*  Zf  = (float*)(W);                          // z fp32 (A dead)
    int*    IDX = (int*)  (W + 16777216);
    float*  CN  = (float*)(W + 17039360);
    float*  HS  = (float*)(W + 17041408);
    bf16_t* ZQh = (bf16_t*)(W + 33554432);
    bf16_t* ZQl = (bf16_t*)(W + 41943040);
    // decoder 32^3 (A region):
    bf16_t* D0h = (bf16_t*)(W + 50331648);
    bf16_t* D0l = (bf16_t*)(W + 67108864);
    bf16_t* Gh  = (bf16_t*)(W + 83886080);
    bf16_t* Gl  = (bf16_t*)(W + 100663296);
    // decoder 64^3:
    bf16_t* U0h = (bf16_t*)(W + 134217728);             // H region
    bf16_t* U0l = (bf16_t*)(W + 201326592);
    bf16_t* G1h = (bf16_t*)(W);                         // A region
    bf16_t* G1l = (bf16_t*)(W + 67108864);

    // ---- weight arenas in d_out ----
    char* WB = (char*)d_out;
    // encoder split-3:
    bf16_t* e0c1h = (bf16_t*)(WB + 0);
    bf16_t* e0c1m = (bf16_t*)(WB + 221184);
    bf16_t* e0c1l = (bf16_t*)(WB + 442368);
    bf16_t* e0c2h = (bf16_t*)(WB + 663552);
    bf16_t* e0c2m = (bf16_t*)(WB + 884736);
    bf16_t* e0c2l = (bf16_t*)(WB + 1105920);
    bf16_t* ec1h  = (bf16_t*)(WB + 1327104);
    bf16_t* ec1m  = (bf16_t*)(WB + 2375680);
    bf16_t* ec1l  = (bf16_t*)(WB + 3424256);
    bf16_t* e1c1h = (bf16_t*)(WB + 4472832);
    bf16_t* e1c1m = (bf16_t*)(WB + 5357568);
    bf16_t* e1c1l = (bf16_t*)(WB + 6242304);
    bf16_t* e1c2h = (bf16_t*)(WB + 7127040);
    bf16_t* e1c2m = (bf16_t*)(WB + 8011776);
    bf16_t* e1c2l = (bf16_t*)(WB + 8896512);
    bf16_t* eoh   = (bf16_t*)(WB + 9781248);
    bf16_t* eom   = (bf16_t*)(WB + 10223616);
    bf16_t* eol   = (bf16_t*)(WB + 10665984);
    // decoder split-2 (written AFTER encoder finishes, same arena):
    bf16_t* dc0h  = (bf16_t*)(WB + 0);
    bf16_t* dc0l  = (bf16_t*)(WB + 442368);
    bf16_t* d0c1h = (bf16_t*)(WB + 884736);
    bf16_t* d0c1l = (bf16_t*)(WB + 1769472);
    bf16_t* d0c2h = (bf16_t*)(WB + 2654208);
    bf16_t* d0c2l = (bf16_t*)(WB + 3538944);
    bf16_t* du0h  = (bf16_t*)(WB + 4423680);
    bf16_t* du0l  = (bf16_t*)(WB + 5472256);
    bf16_t* d1c1h = (bf16_t*)(WB + 6520832);
    bf16_t* d1c1l = (bf16_t*)(WB + 6742016);
    bf16_t* d1c2h = (bf16_t*)(WB + 6963200);
    bf16_t* d1c2l = (bf16_t*)(WB + 7184384);

    const float* fn = nullptr;
    const bf16_t* bn_ = nullptr;

    // ---- encoder weight prep (split-3) ----
    wprep3<<<432, 256, 0, stream>>>(er0_c1w, e0c1h, e0c1m, e0c1l, 64, 64, 110592);
    wprep3<<<432, 256, 0, stream>>>(er0_c2w, e0c2h, e0c2m, e0c2l, 64, 64, 110592);
    wprep3<<<2048, 256, 0, stream>>>(ec1_w, ec1h, ec1m, ec1l, 64, 128, 524288);
    wprep3<<<1728, 256, 0, stream>>>(er1_c1w, e1c1h, e1c1m, e1c1l, 128, 128, 442368);
    wprep3<<<1728, 256, 0, stream>>>(er1_c2w, e1c2h, e1c2m, e1c2l, 128, 128, 442368);
    wprep3<<<864, 256, 0, stream>>>(eo_w, eoh, eom, eol, 128, 64, 221184);

    // ---- encoder (fp32-class) ----
    conv_ec0f<<<131072, dim3(64, 4), 0, stream>>>(x, ec0_w, ec0_b, Af);

    conv3e<64, 64, 64, 1, 1><<<8192, 128, 0, stream>>>(
        Af, e0c1h, e0c1m, e0c1l, er0_c1b, fn, fn, fn, fn, fn, fn, Hf);
    conv3e<64, 64, 64, 1, 3><<<8192, 128, 0, stream>>>(
        Hf, e0c2h, e0c2m, e0c2l, er0_c2b, er0_g, er0_be, er0_m, er0_v, er0_a, Af, Af);

    convs2e<<<2048, 128, 0, stream>>>(Af, ec1h, ec1m, ec1l, ec1_b, E1f);

    conv3e<128, 128, 32, 2, 1><<<2048, 128, 0, stream>>>(
        E1f, e1c1h, e1c1m, e1c1l, er1_c1b, fn, fn, fn, fn, fn, fn, R1f);
    conv3e<128, 128, 32, 2, 3><<<2048, 128, 0, stream>>>(
        R1f, e1c2h, e1c2m, e1c2l, er1_c2b, er1_g, er1_be, er1_m, er1_v, er1_a, E1f, E1f);

    conv3e<128, 64, 32, 1, 2><<<2048, 64, 0, stream>>>(
        E1f, eoh, eom, eol, eo_b, fn, fn, fn, fn, eo_a, fn, Zf);

    // ---- VQ (exact fp32) ----
    vq_cnorm<<<8, 64, 0, stream>>>(cb, CN);
    zero512<<<1, 512, 0, stream>>>(HS);
    vq_assign<<<256, 256, 0, stream>>>(Zf, cb, CN, IDX, HS, 65536);
    perplexity_k<<<1, 512, 0, stream>>>(HS, out + 4194304, 1.0f / 65536.0f);
    vq_gather_split<<<4096, 256, 0, stream>>>(cb, IDX, ZQh, ZQl);

    // ---- decoder weight prep (split-2, overwrites encoder arena) ----
    wprep_split<<<864, 256, 0, stream>>>(dc0_w, dc0h, dc0l, 64, 128, 221184);
    wprep_split<<<1728, 256, 0, stream>>>(dr0_c1w, d0c1h, d0c1l, 128, 128, 442368);
    wprep_split<<<1728, 256, 0, stream>>>(dr0_c2w, d0c2h, d0c2l, 128, 128, 442368);
    wprep_split<<<2048, 256, 0, stream>>>(du0_w, du0h, du0l, 128, 64, 524288);
    wprep_split<<<432, 256, 0, stream>>>(dr1_c1w, d1c1h, d1c1l, 64, 64, 110592);
    wprep_split<<<432, 256, 0, stream>>>(dr1_c2w, d1c2h, d1c2l, 64, 64, 110592);

    // ---- decoder (split-2 bf16) ----
    conv3d<64, 128, 32, 2, 2><<<2048, 128, 0, stream>>>(
        ZQh, ZQl, dc0h, dc0l, dc0_b, fn, fn, fn, fn, dc0_a, bn_, bn_, D0h, D0l);
    conv3d<128, 128, 32, 2, 1><<<2048, 128, 0, stream>>>(
        D0h, D0l, d0c1h, d0c1l, dr0_c1b, fn, fn, fn, fn, fn, bn_, bn_, Gh, Gl);
    conv3d<128, 128, 32, 2, 3><<<2048, 128, 0, stream>>>(
        Gh, Gl, d0c2h, d0c2l, dr0_c2b, dr0_g, dr0_be, dr0_m, dr0_v, dr0_a,
        D0h, D0l, D0h, D0l);

    convTm<<<8192, 256, 0, stream>>>(D0h, D0l, du0h, du0l, du0_b, U0h, U0l);

    conv3d<64, 64, 64, 1, 1><<<8192, 128, 0, stream>>>(
        U0h, U0l, d1c1h, d1c1l, dr1_c1b, fn, fn, fn, fn, fn, bn_, bn_, G1h, G1l);
    conv3d<64, 64, 64, 1, 3><<<8192, 128, 0, stream>>>(
        G1h, G1l, d1c2h, d1c2l, dr1_c2b, dr1_g, dr1_be, dr1_m, dr1_v, dr1_a,
        U0h, U0l, U0h, U0l);

    convT_du1b<<<16384, 256, 0, stream>>>(U0h, U0l, du1_w, du1_b, out);
}

// Round 7
// 11152.457 us; speedup vs baseline: 5.5913x; 1.2075x over previous
//
#include <hip/hip_runtime.h>
#include <cstdint>

// ---------------------------------------------------------------------------
// VQVAE forward — MFMA implicit-GEMM convolutions, channels-last.
//
// Encoder: fp32 activations in memory; EXACT 3-way bf16 split (v = h+m+l)
//   done at LDS-stage time; 6-MFMA products => fp32-class => VQ argmin safe.
// Decoder: split-2 bf16 (hi/lo) storage, 3-pass MFMA.
//
// Round-7: LDS row staging. Each block covers one (d,h) output row; loops
// over valid (kd,kh) input rows, double-buffered in LDS (1 barrier/iter).
// Global loads are fully coalesced (float4/ushort4); MFMA A-fragments read
// from LDS with XOR swizzle  byte ^= (vox&7)<<4  (G4 bank-conflict fix).
//
// C layout: col = lane&31, row = (reg&3) + 8*(reg>>2) + 4*(lane>>5)
// ws layout and weight arenas identical to rounds 5/6 (proven).
// ---------------------------------------------------------------------------

typedef unsigned short bf16_t;
typedef __attribute__((ext_vector_type(8)))  short s8b;     // 8 x bf16 frag
typedef __attribute__((ext_vector_type(16))) float f32x16;  // 32x32 acc

__device__ __forceinline__ float b2f(bf16_t u) { return __uint_as_float((unsigned)u << 16); }
__device__ __forceinline__ bf16_t f2b(float f) {
    unsigned x = __float_as_uint(f);
    return (bf16_t)((x + 0x7FFFu + ((x >> 16) & 1u)) >> 16);
}

__device__ __forceinline__ void split3s(float v, unsigned short& h,
                                        unsigned short& m, unsigned short& l)
{
    const unsigned uv = __float_as_uint(v);
    const float fh = __uint_as_float(uv & 0xFFFF0000u);
    const float r1 = v - fh;
    const unsigned u1 = __float_as_uint(r1);
    const float fm = __uint_as_float(u1 & 0xFFFF0000u);
    const float r2 = r1 - fm;
    h = (unsigned short)(uv >> 16);
    m = (unsigned short)(u1 >> 16);
    l = (unsigned short)(__float_as_uint(r2) >> 16);
}

// ------------------------- weight prep ------------------------------------
__global__ __launch_bounds__(256)
void wprep3(const float* __restrict__ w, bf16_t* __restrict__ h,
            bf16_t* __restrict__ m, bf16_t* __restrict__ l,
            int ci, int co, int n)
{
    const int i = blockIdx.x * 256 + threadIdx.x;
    if (i >= n) return;
    const int co_ = i % co;
    const int ci_ = (i / co) % ci;
    const int tap = i / (co * ci);
    const int dst = (tap * co + co_) * ci + ci_;
    unsigned short hh, mm, ll2;
    split3s(w[i], hh, mm, ll2);
    h[dst] = hh; m[dst] = mm; l[dst] = ll2;
}

__global__ __launch_bounds__(256)
void wprep_split(const float* __restrict__ w, bf16_t* __restrict__ hi,
                 bf16_t* __restrict__ lo, int ci, int co, int n)
{
    const int i = blockIdx.x * 256 + threadIdx.x;
    if (i >= n) return;
    const int co_ = i % co;
    const int ci_ = (i / co) % ci;
    const int tap = i / (co * ci);
    const float v = w[i];
    const int dst = (tap * co + co_) * ci + ci_;
    const bf16_t h = f2b(v);
    hi[dst] = h;
    lo[dst] = f2b(v - b2f(h));
}

// ---------------- encoder 3x3x3 conv: fp32 in, LDS-staged split-3 -----------
// EPI: 0=ReLU 1=swish 2=PReLU 3=BN+PReLU+skip+ReLU
template<int CIN, int COUT, int SD, int NW, int EPI>
__global__ __launch_bounds__((SD / 32) * NW * 64)
void conv3e(const float* __restrict__ xf,
            const bf16_t* __restrict__ wh, const bf16_t* __restrict__ wm,
            const bf16_t* __restrict__ wl,
            const float* __restrict__ bias,
            const float* __restrict__ g, const float* __restrict__ be,
            const float* __restrict__ mn, const float* __restrict__ vr,
            const float* __restrict__ al,
            const float* skf, float* __restrict__ of)
{
    constexpr int NT = (SD / 32) * NW * 64;
    constexpr int LP = (SD * CIN) / (4 * NT);
    __shared__ bf16_t lh[2][SD * CIN], lm[2][SD * CIN], ll[2][SD * CIN];

    const int tid  = threadIdx.x;
    const int lane = tid & 63;
    const int wid  = tid >> 6;
    const int wn   = wid % NW, wm2 = wid / NW;
    const int half = lane >> 5, ln = lane & 31;
    const int w    = wm2 * 32 + ln;
    const int bid  = blockIdx.x;
    const int h    = bid % SD;
    const int d    = (bid / SD) % SD;
    const int b    = bid / (SD * SD);
    const size_t boff = (size_t)(wn * 64 + ln) * CIN + half * 8;

    int pz[9], py[9], pt[9], np = 0;
    for (int kd = 0; kd < 3; ++kd) {
        const int iz = d + kd - 1;
        if ((unsigned)iz >= (unsigned)SD) continue;
        for (int kh = 0; kh < 3; ++kh) {
            const int iy = h + kh - 1;
            if ((unsigned)iy >= (unsigned)SD) continue;
            pz[np] = iz; py[np] = iy; pt[np] = (kd * 3 + kh) * 3; ++np;
        }
    }

    f32x16 accA[2], accB[2];
#pragma unroll
    for (int i = 0; i < 16; ++i) {
        accA[0][i] = 0.f; accA[1][i] = 0.f;
        accB[0][i] = 0.f; accB[1][i] = 0.f;
    }

    auto stageE = [&](int slot, int iz, int iy) {
        const float* src = xf + ((size_t)((b * SD + iz) * SD + iy)) * SD * CIN;
#pragma unroll
        for (int j = 0; j < LP; ++j) {
            const int idx = (tid + j * NT) * 4;
            const int vox = idx / CIN, ch = idx % CIN;
            const float4 v = *reinterpret_cast<const float4*>(src + idx);
            ushort4 h4, m4, l4;
            split3s(v.x, h4.x, m4.x, l4.x);
            split3s(v.y, h4.y, m4.y, l4.y);
            split3s(v.z, h4.z, m4.z, l4.z);
            split3s(v.w, h4.w, m4.w, l4.w);
            const int bo = ((vox * CIN + ch) * 2) ^ ((vox & 7) << 4);
            *reinterpret_cast<ushort4*>((char*)&lh[slot][0] + bo) = h4;
            *reinterpret_cast<ushort4*>((char*)&lm[slot][0] + bo) = m4;
            *reinterpret_cast<ushort4*>((char*)&ll[slot][0] + bo) = l4;
        }
    };

    stageE(0, pz[0], py[0]);
    __syncthreads();
    int cur = 0;
#pragma unroll 1
    for (int i = 0; i < np; ++i) {
        if (i + 1 < np) stageE(cur ^ 1, pz[i + 1], py[i + 1]);
        const size_t tapb = (size_t)pt[i] * CIN * COUT;
#pragma unroll
        for (int kw = 0; kw < 3; ++kw) {
            const int iw = w + kw - 1;
            const bool edge = (unsigned)iw >= (unsigned)SD;
            const int wcl = edge ? w : iw;
            const size_t wbase = tapb + (size_t)kw * CIN * COUT + boff;
            const s8b zz = {};
#pragma unroll
            for (int ks = 0; ks < CIN / 16; ++ks) {
                const int bo = ((wcl * CIN + half * 8 + ks * 16) * 2) ^ ((wcl & 7) << 4);
                s8b ah  = *reinterpret_cast<const s8b*>((const char*)&lh[cur][0] + bo);
                s8b am  = *reinterpret_cast<const s8b*>((const char*)&lm[cur][0] + bo);
                s8b al3 = *reinterpret_cast<const s8b*>((const char*)&ll[cur][0] + bo);
                if (edge) { ah = zz; am = zz; al3 = zz; }
#pragma unroll
                for (int n2 = 0; n2 < 2; ++n2) {
                    const size_t wb = wbase + (size_t)n2 * 32 * CIN + ks * 16;
                    const s8b bh = *reinterpret_cast<const s8b*>(wh + wb);
                    const s8b bm = *reinterpret_cast<const s8b*>(wm + wb);
                    const s8b bl = *reinterpret_cast<const s8b*>(wl + wb);
                    accA[n2] = __builtin_amdgcn_mfma_f32_32x32x16_bf16(ah, bh, accA[n2], 0, 0, 0);
                    accB[n2] = __builtin_amdgcn_mfma_f32_32x32x16_bf16(ah, bm, accB[n2], 0, 0, 0);
                    accA[n2] = __builtin_amdgcn_mfma_f32_32x32x16_bf16(am, bh, accA[n2], 0, 0, 0);
                    accB[n2] = __builtin_amdgcn_mfma_f32_32x32x16_bf16(am, bm, accB[n2], 0, 0, 0);
                    accA[n2] = __builtin_amdgcn_mfma_f32_32x32x16_bf16(al3, bh, accA[n2], 0, 0, 0);
                    accB[n2] = __builtin_amdgcn_mfma_f32_32x32x16_bf16(ah, bl, accB[n2], 0, 0, 0);
                }
            }
        }
        __syncthreads();
        cur ^= 1;
    }

    const size_t outrow = ((size_t)((b * SD + d) * SD + h)) * SD;
#pragma unroll
    for (int n2 = 0; n2 < 2; ++n2) {
        const int cout = wn * 64 + n2 * 32 + ln;
        const float bv = bias[cout];
        float sc = 0.f, mm = 0.f, bb2 = 0.f, aa = 0.f;
        if constexpr (EPI == 3) {
            sc = g[cout] * (1.0f / sqrtf(vr[cout] + 1e-3f));
            mm = mn[cout]; bb2 = be[cout]; aa = al[cout];
        }
        if constexpr (EPI == 2) aa = al[cout];
#pragma unroll
        for (int r = 0; r < 16; ++r) {
            const int rl = (r & 3) + 8 * (r >> 2) + 4 * half;
            const size_t oe = (outrow + wm2 * 32 + rl) * COUT + cout;
            float y = accA[n2][r] + accB[n2][r] + bv;
            if constexpr (EPI == 0) y = fmaxf(y, 0.f);
            else if constexpr (EPI == 1) y = y / (1.f + expf(-y));
            else if constexpr (EPI == 2) y = y > 0.f ? y : aa * y;
            else {
                float t2 = (y - mm) * sc + bb2;
                t2 = t2 > 0.f ? t2 : aa * t2;
                y = fmaxf(skf[oe] + t2, 0.f);
            }
            of[oe] = y;
        }
    }
}

// ---------------- ec1: stride-2 k=4, fp32 in, LDS-staged split-3 ------------
__global__ __launch_bounds__(128)
void convs2e(const float* __restrict__ xf,
             const bf16_t* __restrict__ wh, const bf16_t* __restrict__ wm,
             const bf16_t* __restrict__ wl,
             const float* __restrict__ bias, float* __restrict__ of)
{
    constexpr int NT = 128, LP = (64 * 64) / (4 * NT);
    __shared__ bf16_t lh[2][64 * 64], lm[2][64 * 64], ll[2][64 * 64];

    const int tid  = threadIdx.x;
    const int lane = tid & 63;
    const int wn   = tid >> 6;
    const int half = lane >> 5, ln = lane & 31;
    const int bid  = blockIdx.x;
    const int h    = bid % 32;
    const int d    = (bid / 32) % 32;
    const int b    = bid / 1024;
    const size_t boff = (size_t)(wn * 64 + ln) * 64 + half * 8;

    int pz[16], py[16], pt[16], np = 0;
    for (int kd = 0; kd < 4; ++kd) {
        const int iz = 2 * d + kd - 1;
        if ((unsigned)iz >= 64u) continue;
        for (int kh = 0; kh < 4; ++kh) {
            const int iy = 2 * h + kh - 1;
            if ((unsigned)iy >= 64u) continue;
            pz[np] = iz; py[np] = iy; pt[np] = (kd * 4 + kh) * 4; ++np;
        }
    }

    f32x16 accA[2], accB[2];
#pragma unroll
    for (int i = 0; i < 16; ++i) {
        accA[0][i] = 0.f; accA[1][i] = 0.f;
        accB[0][i] = 0.f; accB[1][i] = 0.f;
    }

    auto stageE = [&](int slot, int iz, int iy) {
        const float* src = xf + ((size_t)((b * 64 + iz) * 64 + iy)) * 64 * 64;
#pragma unroll
        for (int j = 0; j < LP; ++j) {
            const int idx = (tid + j * NT) * 4;
            const int vox = idx / 64, ch = idx % 64;
            const float4 v = *reinterpret_cast<const float4*>(src + idx);
            ushort4 h4, m4, l4;
            split3s(v.x, h4.x, m4.x, l4.x);
            split3s(v.y, h4.y, m4.y, l4.y);
            split3s(v.z, h4.z, m4.z, l4.z);
            split3s(v.w, h4.w, m4.w, l4.w);
            const int bo = ((vox * 64 + ch) * 2) ^ ((vox & 7) << 4);
            *reinterpret_cast<ushort4*>((char*)&lh[slot][0] + bo) = h4;
            *reinterpret_cast<ushort4*>((char*)&lm[slot][0] + bo) = m4;
            *reinterpret_cast<ushort4*>((char*)&ll[slot][0] + bo) = l4;
        }
    };

    stageE(0, pz[0], py[0]);
    __syncthreads();
    int cur = 0;
#pragma unroll 1
    for (int i = 0; i < np; ++i) {
        if (i + 1 < np) stageE(cur ^ 1, pz[i + 1], py[i + 1]);
        const size_t tapb = (size_t)pt[i] * 64 * 128;
#pragma unroll
        for (int kw = 0; kw < 4; ++kw) {
            const int iw = 2 * ln + kw - 1;
            const bool edge = (unsigned)iw >= 64u;
            const int wcl = edge ? 2 * ln : iw;
            const size_t wbase = tapb + (size_t)kw * 64 * 128 + boff;
            const s8b zz = {};
#pragma unroll
            for (int ks = 0; ks < 4; ++ks) {
                const int bo = ((wcl * 64 + half * 8 + ks * 16) * 2) ^ ((wcl & 7) << 4);
                s8b ah  = *reinterpret_cast<const s8b*>((const char*)&lh[cur][0] + bo);
                s8b am  = *reinterpret_cast<const s8b*>((const char*)&lm[cur][0] + bo);
                s8b al3 = *reinterpret_cast<const s8b*>((const char*)&ll[cur][0] + bo);
                if (edge) { ah = zz; am = zz; al3 = zz; }
#pragma unroll
                for (int n2 = 0; n2 < 2; ++n2) {
                    const size_t wb = wbase + (size_t)n2 * 32 * 64 + ks * 16;
                    const s8b bh = *reinterpret_cast<const s8b*>(wh + wb);
                    const s8b bm = *reinterpret_cast<const s8b*>(wm + wb);
                    const s8b bl = *reinterpret_cast<const s8b*>(wl + wb);
                    accA[n2] = __builtin_amdgcn_mfma_f32_32x32x16_bf16(ah, bh, accA[n2], 0, 0, 0);
                    accB[n2] = __builtin_amdgcn_mfma_f32_32x32x16_bf16(ah, bm, accB[n2], 0, 0, 0);
                    accA[n2] = __builtin_amdgcn_mfma_f32_32x32x16_bf16(am, bh, accA[n2], 0, 0, 0);
                    accB[n2] = __builtin_amdgcn_mfma_f32_32x32x16_bf16(am, bm, accB[n2], 0, 0, 0);
                    accA[n2] = __builtin_amdgcn_mfma_f32_32x32x16_bf16(al3, bh, accA[n2], 0, 0, 0);
                    accB[n2] = __builtin_amdgcn_mfma_f32_32x32x16_bf16(ah, bl, accB[n2], 0, 0, 0);
                }
            }
        }
        __syncthreads();
        cur ^= 1;
    }

    const size_t outrow = ((size_t)((b * 32 + d) * 32 + h)) * 32;
#pragma unroll
    for (int n2 = 0; n2 < 2; ++n2) {
        const int cout = wn * 64 + n2 * 32 + ln;
        const float bv = bias[cout];
#pragma unroll
        for (int r = 0; r < 16; ++r) {
            const int rl = (r & 3) + 8 * (r >> 2) + 4 * half;
            const size_t oe = (outrow + rl) * 128 + cout;
            of[oe] = fmaxf(accA[n2][r] + accB[n2][r] + bv, 0.f);
        }
    }
}

// ---------------- decoder 3x3x3 conv: split-2 bf16, LDS-staged --------------
template<int CIN, int COUT, int SD, int NW, int EPI>
__global__ __launch_bounds__((SD / 32) * NW * 64)
void conv3d(const bf16_t* __restrict__ xh, const bf16_t* __restrict__ xl,
            const bf16_t* __restrict__ wh, const bf16_t* __restrict__ wl,
            const float* __restrict__ bias,
            const float* __restrict__ g, const float* __restrict__ be,
            const float* __restrict__ mn, const float* __restrict__ vr,
            const float* __restrict__ al,
            const bf16_t* skh, const bf16_t* skl,
            bf16_t* oh, bf16_t* ol)
{
    constexpr int NT = (SD / 32) * NW * 64;
    constexpr int LP = (SD * CIN) / (4 * NT);
    __shared__ bf16_t lh[2][SD * CIN], ll[2][SD * CIN];

    const int tid  = threadIdx.x;
    const int lane = tid & 63;
    const int wid  = tid >> 6;
    const int wn   = wid % NW, wm2 = wid / NW;
    const int half = lane >> 5, ln = lane & 31;
    const int w    = wm2 * 32 + ln;
    const int bid  = blockIdx.x;
    const int h    = bid % SD;
    const int d    = (bid / SD) % SD;
    const int b    = bid / (SD * SD);
    const size_t boff = (size_t)(wn * 64 + ln) * CIN + half * 8;

    int pz[9], py[9], pt[9], np = 0;
    for (int kd = 0; kd < 3; ++kd) {
        const int iz = d + kd - 1;
        if ((unsigned)iz >= (unsigned)SD) continue;
        for (int kh = 0; kh < 3; ++kh) {
            const int iy = h + kh - 1;
            if ((unsigned)iy >= (unsigned)SD) continue;
            pz[np] = iz; py[np] = iy; pt[np] = (kd * 3 + kh) * 3; ++np;
        }
    }

    f32x16 accA[2], accB[2];
#pragma unroll
    for (int i = 0; i < 16; ++i) {
        accA[0][i] = 0.f; accA[1][i] = 0.f;
        accB[0][i] = 0.f; accB[1][i] = 0.f;
    }

    auto stageD = [&](int slot, int iz, int iy) {
        const size_t rb = ((size_t)((b * SD + iz) * SD + iy)) * SD * CIN;
#pragma unroll
        for (int j = 0; j < LP; ++j) {
            const int idx = (tid + j * NT) * 4;
            const int vox = idx / CIN, ch = idx % CIN;
            const ushort4 vh = *reinterpret_cast<const ushort4*>(xh + rb + idx);
            const ushort4 vl = *reinterpret_cast<const ushort4*>(xl + rb + idx);
            const int bo = ((vox * CIN + ch) * 2) ^ ((vox & 7) << 4);
            *reinterpret_cast<ushort4*>((char*)&lh[slot][0] + bo) = vh;
            *reinterpret_cast<ushort4*>((char*)&ll[slot][0] + bo) = vl;
        }
    };

    stageD(0, pz[0], py[0]);
    __syncthreads();
    int cur = 0;
#pragma unroll 1
    for (int i = 0; i < np; ++i) {
        if (i + 1 < np) stageD(cur ^ 1, pz[i + 1], py[i + 1]);
        const size_t tapb = (size_t)pt[i] * CIN * COUT;
#pragma unroll
        for (int kw = 0; kw < 3; ++kw) {
            const int iw = w + kw - 1;
            const bool edge = (unsigned)iw >= (unsigned)SD;
            const int wcl = edge ? w : iw;
            const size_t wbase = tapb + (size_t)kw * CIN * COUT + boff;
            const s8b zz = {};
#pragma unroll
            for (int ks = 0; ks < CIN / 16; ++ks) {
                const int bo = ((wcl * CIN + half * 8 + ks * 16) * 2) ^ ((wcl & 7) << 4);
                s8b ah  = *reinterpret_cast<const s8b*>((const char*)&lh[cur][0] + bo);
                s8b al2 = *reinterpret_cast<const s8b*>((const char*)&ll[cur][0] + bo);
                if (edge) { ah = zz; al2 = zz; }
#pragma unroll
                for (int n2 = 0; n2 < 2; ++n2) {
                    const size_t wb = wbase + (size_t)n2 * 32 * CIN + ks * 16;
                    const s8b bh = *reinterpret_cast<const s8b*>(wh + wb);
                    const s8b bl = *reinterpret_cast<const s8b*>(wl + wb);
                    accA[n2] = __builtin_amdgcn_mfma_f32_32x32x16_bf16(ah, bh, accA[n2], 0, 0, 0);
                    accB[n2] = __builtin_amdgcn_mfma_f32_32x32x16_bf16(al2, bh, accB[n2], 0, 0, 0);
                    accB[n2] = __builtin_amdgcn_mfma_f32_32x32x16_bf16(ah, bl, accB[n2], 0, 0, 0);
                }
            }
        }
        __syncthreads();
        cur ^= 1;
    }

    const size_t outrow = ((size_t)((b * SD + d) * SD + h)) * SD;
#pragma unroll
    for (int n2 = 0; n2 < 2; ++n2) {
        const int cout = wn * 64 + n2 * 32 + ln;
        const float bv = bias[cout];
        float sc = 0.f, mm = 0.f, bb2 = 0.f, aa = 0.f;
        if constexpr (EPI == 3) {
            sc = g[cout] * (1.0f / sqrtf(vr[cout] + 1e-3f));
            mm = mn[cout]; bb2 = be[cout]; aa = al[cout];
        }
        if constexpr (EPI == 2) aa = al[cout];
#pragma unroll
        for (int r = 0; r < 16; ++r) {
            const int rl = (r & 3) + 8 * (r >> 2) + 4 * half;
            const size_t oe = (outrow + wm2 * 32 + rl) * COUT + cout;
            float y = accA[n2][r] + accB[n2][r] + bv;
            if constexpr (EPI == 0) y = fmaxf(y, 0.f);
            else if constexpr (EPI == 1) y = y / (1.f + expf(-y));
            else if constexpr (EPI == 2) y = y > 0.f ? y : aa * y;
            else {
                float t2 = (y - mm) * sc + bb2;
                t2 = t2 > 0.f ? t2 : aa * t2;
                float sv = b2f(skh[oe]) + b2f(skl[oe]);
                y = fmaxf(sv + t2, 0.f);
            }
            const bf16_t hh = f2b(y);
            oh[oe] = hh;
            ol[oe] = f2b(y - b2f(hh));
        }
    }
}

// ---------------- convT stride-2 k=4 (du0, split-2, LDS-staged) -------------
__global__ __launch_bounds__(256)
void convTm(const bf16_t* __restrict__ xh, const bf16_t* __restrict__ xl,
            const bf16_t* __restrict__ wh, const bf16_t* __restrict__ wl,
            const float* __restrict__ bias,
            bf16_t* __restrict__ oh, bf16_t* __restrict__ ol)
{
    constexpr int NT = 256, LP = (32 * 128) / (4 * NT);
    __shared__ bf16_t lh[2][32 * 128], ll[2][32 * 128];

    const int tid  = threadIdx.x;
    const int lane = tid & 63;
    const int wid  = tid >> 6;
    const int wn   = wid & 1, p = wid >> 1;
    const int half = lane >> 5, ln = lane & 31;
    const int bid  = blockIdx.x;
    const int ohh  = bid % 64;
    const int od   = (bid / 64) % 64;
    const int b    = bid / 4096;
    const int pd = od & 1, dz = od >> 1;
    const int ph = ohh & 1, hy = ohh >> 1;
    const int cout = wn * 32 + ln;
    const int boff = cout * 128 + half * 8;

    int pz[4], py[4], pt[4], np = 0;
    for (int jd = 0; jd < 2; ++jd) {
        const int kd = pd + 2 * jd;
        const int iz = dz + pd - 1 + jd;
        if ((unsigned)iz >= 32u) continue;
        for (int jh = 0; jh < 2; ++jh) {
            const int kh = ph + 2 * jh;
            const int iy = hy + ph - 1 + jh;
            if ((unsigned)iy >= 32u) continue;
            pz[np] = iz; py[np] = iy; pt[np] = (kd * 4 + kh) * 4; ++np;
        }
    }

    f32x16 accA, accB;
#pragma unroll
    for (int i = 0; i < 16; ++i) { accA[i] = 0.0f; accB[i] = 0.0f; }

    auto stageD = [&](int slot, int iz, int iy) {
        const size_t rb = ((size_t)((b * 32 + iz) * 32 + iy)) * 32 * 128;
#pragma unroll
        for (int j = 0; j < LP; ++j) {
            const int idx = (tid + j * NT) * 4;
            const int vox = idx / 128, ch = idx % 128;
            const ushort4 vh = *reinterpret_cast<const ushort4*>(xh + rb + idx);
            const ushort4 vl = *reinterpret_cast<const ushort4*>(xl + rb + idx);
            const int bo = ((vox * 128 + ch) * 2) ^ ((vox & 7) << 4);
            *reinterpret_cast<ushort4*>((char*)&lh[slot][0] + bo) = vh;
            *reinterpret_cast<ushort4*>((char*)&ll[slot][0] + bo) = vl;
        }
    };

    stageD(0, pz[0], py[0]);
    __syncthreads();
    int cur = 0;
#pragma unroll 1
    for (int i = 0; i < np; ++i) {
        if (i + 1 < np) stageD(cur ^ 1, pz[i + 1], py[i + 1]);
#pragma unroll
        for (int jw = 0; jw < 2; ++jw) {
            const int kw = p + 2 * jw;
            const int ix = ln + p - 1 + jw;
            const bool edge = (unsigned)ix >= 32u;
            const int xcl = edge ? ln : ix;
            const size_t wbase = (size_t)(pt[i] + kw) * 128 * 64 + boff;
            const s8b zz = {};
#pragma unroll
            for (int ks = 0; ks < 8; ++ks) {
                const int bo = ((xcl * 128 + half * 8 + ks * 16) * 2) ^ ((xcl & 7) << 4);
                s8b a  = *reinterpret_cast<const s8b*>((const char*)&lh[cur][0] + bo);
                s8b a2 = *reinterpret_cast<const s8b*>((const char*)&ll[cur][0] + bo);
                if (edge) { a = zz; a2 = zz; }
                const s8b bb = *reinterpret_cast<const s8b*>(wh + wbase + ks * 16);
                const s8b b2 = *reinterpret_cast<const s8b*>(wl + wbase + ks * 16);
                accA = __builtin_amdgcn_mfma_f32_32x32x16_bf16(a, bb, accA, 0, 0, 0);
                accB = __builtin_amdgcn_mfma_f32_32x32x16_bf16(a2, bb, accB, 0, 0, 0);
                accB = __builtin_amdgcn_mfma_f32_32x32x16_bf16(a, b2, accB, 0, 0, 0);
            }
        }
        __syncthreads();
        cur ^= 1;
    }

    const float bv = bias[cout];
#pragma unroll
    for (int r = 0; r < 16; ++r) {
        const int rl = (r & 3) + 8 * (r >> 2) + 4 * half;
        const int ow = 2 * rl + p;
        const size_t oe = (((size_t)((b * 64 + od) * 64 + ohh)) * 64 + ow) * 64 + cout;
        const float y = fmaxf(accA[r] + accB[r] + bv, 0.f);
        const bf16_t hh = f2b(y);
        oh[oe] = hh;
        ol[oe] = f2b(y - b2f(hh));
    }
}

// ---------------- ec0: s2 k=4, CIN=1, fp32 direct, fp32 out -----------------
__global__ __launch_bounds__(256)
void conv_ec0f(const float* __restrict__ in, const float* __restrict__ wt,
               const float* __restrict__ bias, float* __restrict__ out)
{
    const int co  = threadIdx.x;
    const int vox = blockIdx.x * 4 + threadIdx.y;
    const int w = vox % 64; int rem = vox / 64;
    const int h = rem % 64; rem /= 64;
    const int d = rem % 64; rem /= 64;
    const int b = rem;
    float acc = bias[co];
#pragma unroll 1
    for (int kd = 0; kd < 4; ++kd) {
        const int iz = 2 * d + kd - 1;
        if ((unsigned)iz >= 128u) continue;
#pragma unroll 1
        for (int kh = 0; kh < 4; ++kh) {
            const int iy = 2 * h + kh - 1;
            if ((unsigned)iy >= 128u) continue;
#pragma unroll
            for (int kw = 0; kw < 4; ++kw) {
                const int ix = 2 * w + kw - 1;
                if ((unsigned)ix >= 128u) continue;
                const float xv = in[(size_t)((b * 128 + iz) * 128 + iy) * 128 + ix];
                acc = fmaf(xv, wt[((kd * 4 + kh) * 4 + kw) * 64 + co], acc);
            }
        }
    }
    out[(size_t)vox * 64 + co] = fmaxf(acc, 0.f);
}

// ---------------- du1: convT s2 k=4, CIN=64, COUT=1, split-2 in -------------
__global__ __launch_bounds__(256)
void convT_du1b(const bf16_t* __restrict__ inh, const bf16_t* __restrict__ inl,
                const float* __restrict__ wt, const float* __restrict__ bias,
                float* __restrict__ out)
{
    const int vox = blockIdx.x * 256 + threadIdx.x;
    const int ow = vox % 128; int rem = vox / 128;
    const int ohh = rem % 128; rem /= 128;
    const int od = rem % 128; rem /= 128;
    const int b  = rem;
    const int pd = od & 1, dz = od >> 1;
    const int ph = ohh & 1, hy = ohh >> 1;
    const int pw = ow & 1, wx = ow >> 1;
    float acc = bias[0];
#pragma unroll 1
    for (int jd = 0; jd < 2; ++jd) {
        const int kd = pd + 2 * jd, iz = dz + pd - 1 + jd;
        if ((unsigned)iz >= 64u) continue;
#pragma unroll 1
        for (int jh = 0; jh < 2; ++jh) {
            const int kh = ph + 2 * jh, iy = hy + ph - 1 + jh;
            if ((unsigned)iy >= 64u) continue;
#pragma unroll 1
            for (int jw = 0; jw < 2; ++jw) {
                const int kw = pw + 2 * jw, ix = wx + pw - 1 + jw;
                if ((unsigned)ix >= 64u) continue;
                const size_t base = (size_t)(((b * 64 + iz) * 64 + iy) * 64 + ix) * 64;
                const float* wp = wt + (size_t)((kd * 4 + kh) * 4 + kw) * 64;
#pragma unroll
                for (int c8 = 0; c8 < 8; ++c8) {
                    const s8b vh = *reinterpret_cast<const s8b*>(inh + base + c8 * 8);
                    const s8b vl = *reinterpret_cast<const s8b*>(inl + base + c8 * 8);
#pragma unroll
                    for (int j = 0; j < 8; ++j)
                        acc = fmaf(b2f((bf16_t)vh[j]) + b2f((bf16_t)vl[j]), wp[c8 * 8 + j], acc);
                }
            }
        }
    }
    out[vox] = acc;
}

// --------------------------------- VQ ---------------------------------------
__global__ void zero512(float* __restrict__ p) { p[threadIdx.x] = 0.0f; }

__global__ void vq_cnorm(const float* __restrict__ cb, float* __restrict__ cnorm)
{
    const int k = blockIdx.x * 64 + threadIdx.x;
    float s = 0.0f;
    for (int ci = 0; ci < 64; ++ci) { const float c = cb[k * 64 + ci]; s = fmaf(c, c, s); }
    cnorm[k] = s;
}

__global__ __launch_bounds__(256)
void vq_assign(const float* __restrict__ z, const float* __restrict__ cb,
               const float* __restrict__ cnorm, int* __restrict__ idx,
               float* __restrict__ hist, int N)
{
    const int n = blockIdx.x * 256 + threadIdx.x;
    const float4* zp = reinterpret_cast<const float4*>(z + (size_t)n * 64);
    float4 zv[16];
    float z2 = 0.0f;
#pragma unroll
    for (int i = 0; i < 16; ++i) {
        zv[i] = zp[i];
        z2 += zv[i].x * zv[i].x + zv[i].y * zv[i].y + zv[i].z * zv[i].z + zv[i].w * zv[i].w;
    }
    float best = 3.4e38f;
    int bi = 0;
#pragma unroll 1
    for (int k = 0; k < 512; ++k) {
        const float4* cp = reinterpret_cast<const float4*>(cb + (size_t)k * 64);
        float dot = 0.0f;
#pragma unroll
        for (int i = 0; i < 16; ++i) {
            const float4 c = cp[i];
            dot += zv[i].x * c.x + zv[i].y * c.y + zv[i].z * c.z + zv[i].w * c.w;
        }
        const float dist = z2 + cnorm[k] - 2.0f * dot;
        if (dist < best) { best = dist; bi = k; }
    }
    idx[n] = bi;
    atomicAdd(&hist[bi], 1.0f);
}

__global__ __launch_bounds__(256)
void vq_gather_split(const float* __restrict__ cb, const int* __restrict__ idx,
                     bf16_t* __restrict__ zh, bf16_t* __restrict__ zl)
{
    const int gid = blockIdx.x * 256 + threadIdx.x;
    const int n = gid >> 4, c4 = gid & 15;
    const int k = idx[n];
    const float4 c = reinterpret_cast<const float4*>(cb)[k * 16 + c4];
    ushort4 h, l;
    h.x = f2b(c.x); l.x = f2b(c.x - b2f(h.x));
    h.y = f2b(c.y); l.y = f2b(c.y - b2f(h.y));
    h.z = f2b(c.z); l.z = f2b(c.z - b2f(h.z));
    h.w = f2b(c.w); l.w = f2b(c.w - b2f(h.w));
    reinterpret_cast<ushort4*>(zh)[gid] = h;
    reinterpret_cast<ushort4*>(zl)[gid] = l;
}

__global__ __launch_bounds__(512)
void perplexity_k(const float* __restrict__ hist, float* __restrict__ out, float invN)
{
    __shared__ float red[512];
    const int t = threadIdx.x;
    const float p = hist[t] * invN;
    red[t] = p * logf(p + 1e-12f);
    __syncthreads();
    for (int s = 256; s > 0; s >>= 1) {
        if (t < s) red[t] += red[t + s];
        __syncthreads();
    }
    if (t == 0) out[0] = expf(-red[0]);
}

// ---------------------------------------------------------------------------
extern "C" void kernel_launch(void* const* d_in, const int* in_sizes, int n_in,
                              void* d_out, int out_size, void* d_ws, size_t ws_size,
                              hipStream_t stream)
{
    const float* x       = (const float*)d_in[0];
    const float* ec0_w   = (const float*)d_in[1];
    const float* ec0_b   = (const float*)d_in[2];
    const float* er0_c1w = (const float*)d_in[3];
    const float* er0_c1b = (const float*)d_in[4];
    const float* er0_c2w = (const float*)d_in[5];
    const float* er0_c2b = (const float*)d_in[6];
    const float* er0_g   = (const float*)d_in[7];
    const float* er0_be  = (const float*)d_in[8];
    const float* er0_m   = (const float*)d_in[9];
    const float* er0_v   = (const float*)d_in[10];
    const float* er0_a   = (const float*)d_in[11];
    const float* ec1_w   = (const float*)d_in[12];
    const float* ec1_b   = (const float*)d_in[13];
    const float* er1_c1w = (const float*)d_in[14];
    const float* er1_c1b = (const float*)d_in[15];
    const float* er1_c2w = (const float*)d_in[16];
    const float* er1_c2b = (const float*)d_in[17];
    const float* er1_g   = (const float*)d_in[18];
    const float* er1_be  = (const float*)d_in[19];
    const float* er1_m   = (const float*)d_in[20];
    const float* er1_v   = (const float*)d_in[21];
    const float* er1_a   = (const float*)d_in[22];
    const float* eo_w    = (const float*)d_in[23];
    const float* eo_b    = (const float*)d_in[24];
    const float* eo_a    = (const float*)d_in[25];
    const float* cb      = (const float*)d_in[26];
    const float* dc0_w   = (const float*)d_in[27];
    const float* dc0_b   = (const float*)d_in[28];
    const float* dc0_a   = (const float*)d_in[29];
    const float* dr0_c1w = (const float*)d_in[30];
    const float* dr0_c1b = (const float*)d_in[31];
    const float* dr0_c2w = (const float*)d_in[32];
    const float* dr0_c2b = (const float*)d_in[33];
    const float* dr0_g   = (const float*)d_in[34];
    const float* dr0_be  = (const float*)d_in[35];
    const float* dr0_m   = (const float*)d_in[36];
    const float* dr0_v   = (const float*)d_in[37];
    const float* dr0_a   = (const float*)d_in[38];
    const float* du0_w   = (const float*)d_in[39];
    const float* du0_b   = (const float*)d_in[40];
    const float* dr1_c1w = (const float*)d_in[41];
    const float* dr1_c1b = (const float*)d_in[42];
    const float* dr1_c2w = (const float*)d_in[43];
    const float* dr1_c2b = (const float*)d_in[44];
    const float* dr1_g   = (const float*)d_in[45];
    const float* dr1_be  = (const float*)d_in[46];
    const float* dr1_m   = (const float*)d_in[47];
    const float* dr1_v   = (const float*)d_in[48];
    const float* dr1_a   = (const float*)d_in[49];
    const float* du1_w   = (const float*)d_in[50];
    const float* du1_b   = (const float*)d_in[51];

    float* out = (float*)d_out;

    // ---- ws: A=[0,134MB) , H=[134MB,268MB) ----
    char* W = (char*)d_ws;
    float*  Af  = (float*)(W);
    float*  Hf  = (float*)(W + 134217728);
    float*  E1f = (float*)(W + 134217728);
    float*  R1f = (float*)(W + 134217728 + 33554432);
    float*  Zf  = (float*)(W);
    int*    IDX = (int*)  (W + 16777216);
    float*  CN  = (float*)(W + 17039360);
    float*  HS  = (float*)(W + 17041408);
    bf16_t* ZQh = (bf16_t*)(W + 33554432);
    bf16_t* ZQl = (bf16_t*)(W + 41943040);
    bf16_t* D0h = (bf16_t*)(W + 50331648);
    bf16_t* D0l = (bf16_t*)(W + 67108864);
    bf16_t* Gh  = (bf16_t*)(W + 83886080);
    bf16_t* Gl  = (bf16_t*)(W + 100663296);
    bf16_t* U0h = (bf16_t*)(W + 134217728);
    bf16_t* U0l = (bf16_t*)(W + 201326592);
    bf16_t* G1h = (bf16_t*)(W);
    bf16_t* G1l = (bf16_t*)(W + 67108864);

    // ---- weight arenas in d_out ----
    char* WB = (char*)d_out;
    bf16_t* e0c1h = (bf16_t*)(WB + 0);
    bf16_t* e0c1m = (bf16_t*)(WB + 221184);
    bf16_t* e0c1l = (bf16_t*)(WB + 442368);
    bf16_t* e0c2h = (bf16_t*)(WB + 663552);
    bf16_t* e0c2m = (bf16_t*)(WB + 884736);
    bf16_t* e0c2l = (bf16_t*)(WB + 1105920);
    bf16_t* ec1h  = (bf16_t*)(WB + 1327104);
    bf16_t* ec1m  = (bf16_t*)(WB + 2375680);
    bf16_t* ec1l  = (bf16_t*)(WB + 3424256);
    bf16_t* e1c1h = (bf16_t*)(WB + 4472832);
    bf16_t* e1c1m = (bf16_t*)(WB + 5357568);
    bf16_t* e1c1l = (bf16_t*)(WB + 6242304);
    bf16_t* e1c2h = (bf16_t*)(WB + 7127040);
    bf16_t* e1c2m = (bf16_t*)(WB + 8011776);
    bf16_t* e1c2l = (bf16_t*)(WB + 8896512);
    bf16_t* eoh   = (bf16_t*)(WB + 9781248);
    bf16_t* eom   = (bf16_t*)(WB + 10223616);
    bf16_t* eol   = (bf16_t*)(WB + 10665984);
    bf16_t* dc0h  = (bf16_t*)(WB + 0);
    bf16_t* dc0l  = (bf16_t*)(WB + 442368);
    bf16_t* d0c1h = (bf16_t*)(WB + 884736);
    bf16_t* d0c1l = (bf16_t*)(WB + 1769472);
    bf16_t* d0c2h = (bf16_t*)(WB + 2654208);
    bf16_t* d0c2l = (bf16_t*)(WB + 3538944);
    bf16_t* du0h  = (bf16_t*)(WB + 4423680);
    bf16_t* du0l  = (bf16_t*)(WB + 5472256);
    bf16_t* d1c1h = (bf16_t*)(WB + 6520832);
    bf16_t* d1c1l = (bf16_t*)(WB + 6742016);
    bf16_t* d1c2h = (bf16_t*)(WB + 6963200);
    bf16_t* d1c2l = (bf16_t*)(WB + 7184384);

    const float* fn = nullptr;
    const bf16_t* bn_ = nullptr;

    // ---- encoder weight prep (split-3) ----
    wprep3<<<432, 256, 0, stream>>>(er0_c1w, e0c1h, e0c1m, e0c1l, 64, 64, 110592);
    wprep3<<<432, 256, 0, stream>>>(er0_c2w, e0c2h, e0c2m, e0c2l, 64, 64, 110592);
    wprep3<<<2048, 256, 0, stream>>>(ec1_w, ec1h, ec1m, ec1l, 64, 128, 524288);
    wprep3<<<1728, 256, 0, stream>>>(er1_c1w, e1c1h, e1c1m, e1c1l, 128, 128, 442368);
    wprep3<<<1728, 256, 0, stream>>>(er1_c2w, e1c2h, e1c2m, e1c2l, 128, 128, 442368);
    wprep3<<<864, 256, 0, stream>>>(eo_w, eoh, eom, eol, 128, 64, 221184);

    // ---- encoder (fp32-class) ----
    conv_ec0f<<<131072, dim3(64, 4), 0, stream>>>(x, ec0_w, ec0_b, Af);

    conv3e<64, 64, 64, 1, 1><<<8192, 128, 0, stream>>>(
        Af, e0c1h, e0c1m, e0c1l, er0_c1b, fn, fn, fn, fn, fn, fn, Hf);
    conv3e<64, 64, 64, 1, 3><<<8192, 128, 0, stream>>>(
        Hf, e0c2h, e0c2m, e0c2l, er0_c2b, er0_g, er0_be, er0_m, er0_v, er0_a, Af, Af);

    convs2e<<<2048, 128, 0, stream>>>(Af, ec1h, ec1m, ec1l, ec1_b, E1f);

    conv3e<128, 128, 32, 2, 1><<<2048, 128, 0, stream>>>(
        E1f, e1c1h, e1c1m, e1c1l, er1_c1b, fn, fn, fn, fn, fn, fn, R1f);
    conv3e<128, 128, 32, 2, 3><<<2048, 128, 0, stream>>>(
        R1f, e1c2h, e1c2m, e1c2l, er1_c2b, er1_g, er1_be, er1_m, er1_v, er1_a, E1f, E1f);

    conv3e<128, 64, 32, 1, 2><<<2048, 64, 0, stream>>>(
        E1f, eoh, eom, eol, eo_b, fn, fn, fn, fn, eo_a, fn, Zf);

    // ---- VQ (exact fp32) ----
    vq_cnorm<<<8, 64, 0, stream>>>(cb, CN);
    zero512<<<1, 512, 0, stream>>>(HS);
    vq_assign<<<256, 256, 0, stream>>>(Zf, cb, CN, IDX, HS, 65536);
    perplexity_k<<<1, 512, 0, stream>>>(HS, out + 4194304, 1.0f / 65536.0f);
    vq_gather_split<<<4096, 256, 0, stream>>>(cb, IDX, ZQh, ZQl);

    // ---- decoder weight prep (split-2, overwrites encoder arena) ----
    wprep_split<<<864, 256, 0, stream>>>(dc0_w, dc0h, dc0l, 64, 128, 221184);
    wprep_split<<<1728, 256, 0, stream>>>(dr0_c1w, d0c1h, d0c1l, 128, 128, 442368);
    wprep_split<<<1728, 256, 0, stream>>>(dr0_c2w, d0c2h, d0c2l, 128, 128, 442368);
    wprep_split<<<2048, 256, 0, stream>>>(du0_w, du0h, du0l, 128, 64, 524288);
    wprep_split<<<432, 256, 0, stream>>>(dr1_c1w, d1c1h, d1c1l, 64, 64, 110592);
    wprep_split<<<432, 256, 0, stream>>>(dr1_c2w, d1c2h, d1c2l, 64, 64, 110592);

    // ---- decoder (split-2 bf16) ----
    conv3d<64, 128, 32, 2, 2><<<2048, 128, 0, stream>>>(
        ZQh, ZQl, dc0h, dc0l, dc0_b, fn, fn, fn, fn, dc0_a, bn_, bn_, D0h, D0l);
    conv3d<128, 128, 32, 2, 1><<<2048, 128, 0, stream>>>(
        D0h, D0l, d0c1h, d0c1l, dr0_c1b, fn, fn, fn, fn, fn, bn_, bn_, Gh, Gl);
    conv3d<128, 128, 32, 2, 3><<<2048, 128, 0, stream>>>(
        Gh, Gl, d0c2h, d0c2l, dr0_c2b, dr0_g, dr0_be, dr0_m, dr0_v, dr0_a,
        D0h, D0l, D0h, D0l);

    convTm<<<8192, 256, 0, stream>>>(D0h, D0l, du0h, du0l, du0_b, U0h, U0l);

    conv3d<64, 64, 64, 1, 1><<<8192, 128, 0, stream>>>(
        U0h, U0l, d1c1h, d1c1l, dr1_c1b, fn, fn, fn, fn, fn, bn_, bn_, G1h, G1l);
    conv3d<64, 64, 64, 1, 3><<<8192, 128, 0, stream>>>(
        G1h, G1l, d1c2h, d1c2l, dr1_c2b, dr1_g, dr1_be, dr1_m, dr1_v, dr1_a,
        U0h, U0l, U0h, U0l);

    convT_du1b<<<16384, 256, 0, stream>>>(U0h, U0l, du1_w, du1_b, out);
}

// Round 8
// 10920.599 us; speedup vs baseline: 5.7100x; 1.0212x over previous
//
#include <hip/hip_runtime.h>
#include <cstdint>

// ---------------------------------------------------------------------------
// VQVAE forward — MFMA implicit-GEMM convolutions, channels-last.
//
// Encoder: fp32 activations in memory; EXACT 3-way bf16 split (v = h+m+l)
//   done at LDS-stage time; 6-MFMA products => fp32-class => VQ argmin safe.
// Decoder: split-2 bf16 (hi/lo) storage, 3-pass MFMA.
//
// Round-8:
//  - T14 async-STAGE: single LDS buffer; next-row global loads issued into
//    registers BEFORE the MFMA phase, written to LDS between two barriers.
//    Halves LDS (24KB enc / 16KB dec) => 2x occupancy.
//  - T1 XCD-chunked swizzle: bid = (orig&7)*(nwg/8) + orig>>3 (grids %8==0)
//    so each XCD sweeps contiguous (b,d,h); 3-plane working set fits its L2.
//  - LDS XOR swizzle byte ^= (vox&7)<<4 retained (G4).
//
// C layout: col = lane&31, row = (reg&3) + 8*(reg>>2) + 4*(lane>>5)
// ws layout and weight arenas identical to rounds 5-7 (proven).
// ---------------------------------------------------------------------------

typedef unsigned short bf16_t;
typedef __attribute__((ext_vector_type(8)))  short s8b;     // 8 x bf16 frag
typedef __attribute__((ext_vector_type(16))) float f32x16;  // 32x32 acc

__device__ __forceinline__ float b2f(bf16_t u) { return __uint_as_float((unsigned)u << 16); }
__device__ __forceinline__ bf16_t f2b(float f) {
    unsigned x = __float_as_uint(f);
    return (bf16_t)((x + 0x7FFFu + ((x >> 16) & 1u)) >> 16);
}

__device__ __forceinline__ void split3s(float v, unsigned short& h,
                                        unsigned short& m, unsigned short& l)
{
    const unsigned uv = __float_as_uint(v);
    const float fh = __uint_as_float(uv & 0xFFFF0000u);
    const float r1 = v - fh;
    const unsigned u1 = __float_as_uint(r1);
    const float fm = __uint_as_float(u1 & 0xFFFF0000u);
    const float r2 = r1 - fm;
    h = (unsigned short)(uv >> 16);
    m = (unsigned short)(u1 >> 16);
    l = (unsigned short)(__float_as_uint(r2) >> 16);
}

// ------------------------- weight prep ------------------------------------
__global__ __launch_bounds__(256)
void wprep3(const float* __restrict__ w, bf16_t* __restrict__ h,
            bf16_t* __restrict__ m, bf16_t* __restrict__ l,
            int ci, int co, int n)
{
    const int i = blockIdx.x * 256 + threadIdx.x;
    if (i >= n) return;
    const int co_ = i % co;
    const int ci_ = (i / co) % ci;
    const int tap = i / (co * ci);
    const int dst = (tap * co + co_) * ci + ci_;
    unsigned short hh, mm, ll2;
    split3s(w[i], hh, mm, ll2);
    h[dst] = hh; m[dst] = mm; l[dst] = ll2;
}

__global__ __launch_bounds__(256)
void wprep_split(const float* __restrict__ w, bf16_t* __restrict__ hi,
                 bf16_t* __restrict__ lo, int ci, int co, int n)
{
    const int i = blockIdx.x * 256 + threadIdx.x;
    if (i >= n) return;
    const int co_ = i % co;
    const int ci_ = (i / co) % ci;
    const int tap = i / (co * ci);
    const float v = w[i];
    const int dst = (tap * co + co_) * ci + ci_;
    const bf16_t h = f2b(v);
    hi[dst] = h;
    lo[dst] = f2b(v - b2f(h));
}

// ---------------- encoder 3x3x3 conv: fp32 in, T14-staged split-3 -----------
// EPI: 0=ReLU 1=swish 2=PReLU 3=BN+PReLU+skip+ReLU
template<int CIN, int COUT, int SD, int NW, int EPI>
__global__ __launch_bounds__((SD / 32) * NW * 64)
void conv3e(const float* __restrict__ xf,
            const bf16_t* __restrict__ wh, const bf16_t* __restrict__ wm,
            const bf16_t* __restrict__ wl,
            const float* __restrict__ bias,
            const float* __restrict__ g, const float* __restrict__ be,
            const float* __restrict__ mn, const float* __restrict__ vr,
            const float* __restrict__ al,
            const float* skf, float* __restrict__ of)
{
    constexpr int NT = (SD / 32) * NW * 64;
    constexpr int LP = (SD * CIN) / (4 * NT);
    __shared__ bf16_t lh[SD * CIN], lm[SD * CIN], ll[SD * CIN];

    const int tid  = threadIdx.x;
    const int lane = tid & 63;
    const int wid  = tid >> 6;
    const int wn   = wid % NW, wm2 = wid / NW;
    const int half = lane >> 5, ln = lane & 31;
    const int w    = wm2 * 32 + ln;
    const int nwg  = gridDim.x;
    const int bid  = (blockIdx.x & 7) * (nwg >> 3) + (blockIdx.x >> 3);
    const int h    = bid % SD;
    const int d    = (bid / SD) % SD;
    const int b    = bid / (SD * SD);
    const size_t boff = (size_t)(wn * 64 + ln) * CIN + half * 8;

    int pz[9], py[9], pt[9], np = 0;
    for (int kd = 0; kd < 3; ++kd) {
        const int iz = d + kd - 1;
        if ((unsigned)iz >= (unsigned)SD) continue;
        for (int kh = 0; kh < 3; ++kh) {
            const int iy = h + kh - 1;
            if ((unsigned)iy >= (unsigned)SD) continue;
            pz[np] = iz; py[np] = iy; pt[np] = (kd * 3 + kh) * 3; ++np;
        }
    }

    f32x16 accA[2], accB[2];
#pragma unroll
    for (int i = 0; i < 16; ++i) {
        accA[0][i] = 0.f; accA[1][i] = 0.f;
        accB[0][i] = 0.f; accB[1][i] = 0.f;
    }

    float4 rg[LP];
    auto loadrow = [&](int iz, int iy) {
        const float* src = xf + ((size_t)((b * SD + iz) * SD + iy)) * SD * CIN;
#pragma unroll
        for (int j = 0; j < LP; ++j)
            rg[j] = *reinterpret_cast<const float4*>(src + (size_t)(tid + j * NT) * 4);
    };
    auto writerow = [&]() {
#pragma unroll
        for (int j = 0; j < LP; ++j) {
            const int idx = (tid + j * NT) * 4;
            const int vox = idx / CIN, ch = idx % CIN;
            ushort4 h4, m4, l4;
            split3s(rg[j].x, h4.x, m4.x, l4.x);
            split3s(rg[j].y, h4.y, m4.y, l4.y);
            split3s(rg[j].z, h4.z, m4.z, l4.z);
            split3s(rg[j].w, h4.w, m4.w, l4.w);
            const int bo = ((vox * CIN + ch) * 2) ^ ((vox & 7) << 4);
            *reinterpret_cast<ushort4*>((char*)&lh[0] + bo) = h4;
            *reinterpret_cast<ushort4*>((char*)&lm[0] + bo) = m4;
            *reinterpret_cast<ushort4*>((char*)&ll[0] + bo) = l4;
        }
    };

    loadrow(pz[0], py[0]);
    writerow();
    __syncthreads();
#pragma unroll 1
    for (int i = 0; i < np; ++i) {
        if (i + 1 < np) loadrow(pz[i + 1], py[i + 1]);   // issue early (T14)
        const size_t tapb = (size_t)pt[i] * CIN * COUT;
#pragma unroll
        for (int kw = 0; kw < 3; ++kw) {
            const int iw = w + kw - 1;
            const bool edge = (unsigned)iw >= (unsigned)SD;
            const int wcl = edge ? w : iw;
            const size_t wbase = tapb + (size_t)kw * CIN * COUT + boff;
            const s8b zz = {};
#pragma unroll
            for (int ks = 0; ks < CIN / 16; ++ks) {
                const int bo = ((wcl * CIN + half * 8 + ks * 16) * 2) ^ ((wcl & 7) << 4);
                s8b ah  = *reinterpret_cast<const s8b*>((const char*)&lh[0] + bo);
                s8b am  = *reinterpret_cast<const s8b*>((const char*)&lm[0] + bo);
                s8b al3 = *reinterpret_cast<const s8b*>((const char*)&ll[0] + bo);
                if (edge) { ah = zz; am = zz; al3 = zz; }
#pragma unroll
                for (int n2 = 0; n2 < 2; ++n2) {
                    const size_t wb = wbase + (size_t)n2 * 32 * CIN + ks * 16;
                    const s8b bh = *reinterpret_cast<const s8b*>(wh + wb);
                    const s8b bm = *reinterpret_cast<const s8b*>(wm + wb);
                    const s8b bl = *reinterpret_cast<const s8b*>(wl + wb);
                    accA[n2] = __builtin_amdgcn_mfma_f32_32x32x16_bf16(ah, bh, accA[n2], 0, 0, 0);
                    accB[n2] = __builtin_amdgcn_mfma_f32_32x32x16_bf16(ah, bm, accB[n2], 0, 0, 0);
                    accA[n2] = __builtin_amdgcn_mfma_f32_32x32x16_bf16(am, bh, accA[n2], 0, 0, 0);
                    accB[n2] = __builtin_amdgcn_mfma_f32_32x32x16_bf16(am, bm, accB[n2], 0, 0, 0);
                    accA[n2] = __builtin_amdgcn_mfma_f32_32x32x16_bf16(al3, bh, accA[n2], 0, 0, 0);
                    accB[n2] = __builtin_amdgcn_mfma_f32_32x32x16_bf16(ah, bl, accB[n2], 0, 0, 0);
                }
            }
        }
        if (i + 1 < np) {
            __syncthreads();          // all waves done reading LDS
            writerow();               // implicit vmcnt wait on rg here
            __syncthreads();          // LDS ready
        }
    }

    const size_t outrow = ((size_t)((b * SD + d) * SD + h)) * SD;
#pragma unroll
    for (int n2 = 0; n2 < 2; ++n2) {
        const int cout = wn * 64 + n2 * 32 + ln;
        const float bv = bias[cout];
        float sc = 0.f, mm = 0.f, bb2 = 0.f, aa = 0.f;
        if constexpr (EPI == 3) {
            sc = g[cout] * (1.0f / sqrtf(vr[cout] + 1e-3f));
            mm = mn[cout]; bb2 = be[cout]; aa = al[cout];
        }
        if constexpr (EPI == 2) aa = al[cout];
#pragma unroll
        for (int r = 0; r < 16; ++r) {
            const int rl = (r & 3) + 8 * (r >> 2) + 4 * half;
            const size_t oe = (outrow + wm2 * 32 + rl) * COUT + cout;
            float y = accA[n2][r] + accB[n2][r] + bv;
            if constexpr (EPI == 0) y = fmaxf(y, 0.f);
            else if constexpr (EPI == 1) y = y / (1.f + expf(-y));
            else if constexpr (EPI == 2) y = y > 0.f ? y : aa * y;
            else {
                float t2 = (y - mm) * sc + bb2;
                t2 = t2 > 0.f ? t2 : aa * t2;
                y = fmaxf(skf[oe] + t2, 0.f);
            }
            of[oe] = y;
        }
    }
}

// ---------------- ec1: stride-2 k=4, fp32 in, T14-staged split-3 ------------
__global__ __launch_bounds__(128)
void convs2e(const float* __restrict__ xf,
             const bf16_t* __restrict__ wh, const bf16_t* __restrict__ wm,
             const bf16_t* __restrict__ wl,
             const float* __restrict__ bias, float* __restrict__ of)
{
    constexpr int NT = 128, LP = (64 * 64) / (4 * NT);
    __shared__ bf16_t lh[64 * 64], lm[64 * 64], ll[64 * 64];

    const int tid  = threadIdx.x;
    const int lane = tid & 63;
    const int wn   = tid >> 6;
    const int half = lane >> 5, ln = lane & 31;
    const int nwg  = gridDim.x;
    const int bid  = (blockIdx.x & 7) * (nwg >> 3) + (blockIdx.x >> 3);
    const int h    = bid % 32;
    const int d    = (bid / 32) % 32;
    const int b    = bid / 1024;
    const size_t boff = (size_t)(wn * 64 + ln) * 64 + half * 8;

    int pz[16], py[16], pt[16], np = 0;
    for (int kd = 0; kd < 4; ++kd) {
        const int iz = 2 * d + kd - 1;
        if ((unsigned)iz >= 64u) continue;
        for (int kh = 0; kh < 4; ++kh) {
            const int iy = 2 * h + kh - 1;
            if ((unsigned)iy >= 64u) continue;
            pz[np] = iz; py[np] = iy; pt[np] = (kd * 4 + kh) * 4; ++np;
        }
    }

    f32x16 accA[2], accB[2];
#pragma unroll
    for (int i = 0; i < 16; ++i) {
        accA[0][i] = 0.f; accA[1][i] = 0.f;
        accB[0][i] = 0.f; accB[1][i] = 0.f;
    }

    float4 rg[LP];
    auto loadrow = [&](int iz, int iy) {
        const float* src = xf + ((size_t)((b * 64 + iz) * 64 + iy)) * 64 * 64;
#pragma unroll
        for (int j = 0; j < LP; ++j)
            rg[j] = *reinterpret_cast<const float4*>(src + (size_t)(tid + j * NT) * 4);
    };
    auto writerow = [&]() {
#pragma unroll
        for (int j = 0; j < LP; ++j) {
            const int idx = (tid + j * NT) * 4;
            const int vox = idx / 64, ch = idx % 64;
            ushort4 h4, m4, l4;
            split3s(rg[j].x, h4.x, m4.x, l4.x);
            split3s(rg[j].y, h4.y, m4.y, l4.y);
            split3s(rg[j].z, h4.z, m4.z, l4.z);
            split3s(rg[j].w, h4.w, m4.w, l4.w);
            const int bo = ((vox * 64 + ch) * 2) ^ ((vox & 7) << 4);
            *reinterpret_cast<ushort4*>((char*)&lh[0] + bo) = h4;
            *reinterpret_cast<ushort4*>((char*)&lm[0] + bo) = m4;
            *reinterpret_cast<ushort4*>((char*)&ll[0] + bo) = l4;
        }
    };

    loadrow(pz[0], py[0]);
    writerow();
    __syncthreads();
#pragma unroll 1
    for (int i = 0; i < np; ++i) {
        if (i + 1 < np) loadrow(pz[i + 1], py[i + 1]);
        const size_t tapb = (size_t)pt[i] * 64 * 128;
#pragma unroll
        for (int kw = 0; kw < 4; ++kw) {
            const int iw = 2 * ln + kw - 1;
            const bool edge = (unsigned)iw >= 64u;
            const int wcl = edge ? 2 * ln : iw;
            const size_t wbase = tapb + (size_t)kw * 64 * 128 + boff;
            const s8b zz = {};
#pragma unroll
            for (int ks = 0; ks < 4; ++ks) {
                const int bo = ((wcl * 64 + half * 8 + ks * 16) * 2) ^ ((wcl & 7) << 4);
                s8b ah  = *reinterpret_cast<const s8b*>((const char*)&lh[0] + bo);
                s8b am  = *reinterpret_cast<const s8b*>((const char*)&lm[0] + bo);
                s8b al3 = *reinterpret_cast<const s8b*>((const char*)&ll[0] + bo);
                if (edge) { ah = zz; am = zz; al3 = zz; }
#pragma unroll
                for (int n2 = 0; n2 < 2; ++n2) {
                    const size_t wb = wbase + (size_t)n2 * 32 * 64 + ks * 16;
                    const s8b bh = *reinterpret_cast<const s8b*>(wh + wb);
                    const s8b bm = *reinterpret_cast<const s8b*>(wm + wb);
                    const s8b bl = *reinterpret_cast<const s8b*>(wl + wb);
                    accA[n2] = __builtin_amdgcn_mfma_f32_32x32x16_bf16(ah, bh, accA[n2], 0, 0, 0);
                    accB[n2] = __builtin_amdgcn_mfma_f32_32x32x16_bf16(ah, bm, accB[n2], 0, 0, 0);
                    accA[n2] = __builtin_amdgcn_mfma_f32_32x32x16_bf16(am, bh, accA[n2], 0, 0, 0);
                    accB[n2] = __builtin_amdgcn_mfma_f32_32x32x16_bf16(am, bm, accB[n2], 0, 0, 0);
                    accA[n2] = __builtin_amdgcn_mfma_f32_32x32x16_bf16(al3, bh, accA[n2], 0, 0, 0);
                    accB[n2] = __builtin_amdgcn_mfma_f32_32x32x16_bf16(ah, bl, accB[n2], 0, 0, 0);
                }
            }
        }
        if (i + 1 < np) {
            __syncthreads();
            writerow();
            __syncthreads();
        }
    }

    const size_t outrow = ((size_t)((b * 32 + d) * 32 + h)) * 32;
#pragma unroll
    for (int n2 = 0; n2 < 2; ++n2) {
        const int cout = wn * 64 + n2 * 32 + ln;
        const float bv = bias[cout];
#pragma unroll
        for (int r = 0; r < 16; ++r) {
            const int rl = (r & 3) + 8 * (r >> 2) + 4 * half;
            const size_t oe = (outrow + rl) * 128 + cout;
            of[oe] = fmaxf(accA[n2][r] + accB[n2][r] + bv, 0.f);
        }
    }
}

// ---------------- decoder 3x3x3 conv: split-2 bf16, T14-staged --------------
template<int CIN, int COUT, int SD, int NW, int EPI>
__global__ __launch_bounds__((SD / 32) * NW * 64)
void conv3d(const bf16_t* __restrict__ xh, const bf16_t* __restrict__ xl,
            const bf16_t* __restrict__ wh, const bf16_t* __restrict__ wl,
            const float* __restrict__ bias,
            const float* __restrict__ g, const float* __restrict__ be,
            const float* __restrict__ mn, const float* __restrict__ vr,
            const float* __restrict__ al,
            const bf16_t* skh, const bf16_t* skl,
            bf16_t* oh, bf16_t* ol)
{
    constexpr int NT = (SD / 32) * NW * 64;
    constexpr int LP = (SD * CIN) / (4 * NT);
    __shared__ bf16_t lh[SD * CIN], ll[SD * CIN];

    const int tid  = threadIdx.x;
    const int lane = tid & 63;
    const int wid  = tid >> 6;
    const int wn   = wid % NW, wm2 = wid / NW;
    const int half = lane >> 5, ln = lane & 31;
    const int w    = wm2 * 32 + ln;
    const int nwg  = gridDim.x;
    const int bid  = (blockIdx.x & 7) * (nwg >> 3) + (blockIdx.x >> 3);
    const int h    = bid % SD;
    const int d    = (bid / SD) % SD;
    const int b    = bid / (SD * SD);
    const size_t boff = (size_t)(wn * 64 + ln) * CIN + half * 8;

    int pz[9], py[9], pt[9], np = 0;
    for (int kd = 0; kd < 3; ++kd) {
        const int iz = d + kd - 1;
        if ((unsigned)iz >= (unsigned)SD) continue;
        for (int kh = 0; kh < 3; ++kh) {
            const int iy = h + kh - 1;
            if ((unsigned)iy >= (unsigned)SD) continue;
            pz[np] = iz; py[np] = iy; pt[np] = (kd * 3 + kh) * 3; ++np;
        }
    }

    f32x16 accA[2], accB[2];
#pragma unroll
    for (int i = 0; i < 16; ++i) {
        accA[0][i] = 0.f; accA[1][i] = 0.f;
        accB[0][i] = 0.f; accB[1][i] = 0.f;
    }

    ushort4 rh[LP], rl2[LP];
    auto loadrow = [&](int iz, int iy) {
        const size_t rb = ((size_t)((b * SD + iz) * SD + iy)) * SD * CIN;
#pragma unroll
        for (int j = 0; j < LP; ++j) {
            const int idx = (tid + j * NT) * 4;
            rh[j]  = *reinterpret_cast<const ushort4*>(xh + rb + idx);
            rl2[j] = *reinterpret_cast<const ushort4*>(xl + rb + idx);
        }
    };
    auto writerow = [&]() {
#pragma unroll
        for (int j = 0; j < LP; ++j) {
            const int idx = (tid + j * NT) * 4;
            const int vox = idx / CIN, ch = idx % CIN;
            const int bo = ((vox * CIN + ch) * 2) ^ ((vox & 7) << 4);
            *reinterpret_cast<ushort4*>((char*)&lh[0] + bo) = rh[j];
            *reinterpret_cast<ushort4*>((char*)&ll[0] + bo) = rl2[j];
        }
    };

    loadrow(pz[0], py[0]);
    writerow();
    __syncthreads();
#pragma unroll 1
    for (int i = 0; i < np; ++i) {
        if (i + 1 < np) loadrow(pz[i + 1], py[i + 1]);
        const size_t tapb = (size_t)pt[i] * CIN * COUT;
#pragma unroll
        for (int kw = 0; kw < 3; ++kw) {
            const int iw = w + kw - 1;
            const bool edge = (unsigned)iw >= (unsigned)SD;
            const int wcl = edge ? w : iw;
            const size_t wbase = tapb + (size_t)kw * CIN * COUT + boff;
            const s8b zz = {};
#pragma unroll
            for (int ks = 0; ks < CIN / 16; ++ks) {
                const int bo = ((wcl * CIN + half * 8 + ks * 16) * 2) ^ ((wcl & 7) << 4);
                s8b ah  = *reinterpret_cast<const s8b*>((const char*)&lh[0] + bo);
                s8b al2 = *reinterpret_cast<const s8b*>((const char*)&ll[0] + bo);
                if (edge) { ah = zz; al2 = zz; }
#pragma unroll
                for (int n2 = 0; n2 < 2; ++n2) {
                    const size_t wb = wbase + (size_t)n2 * 32 * CIN + ks * 16;
                    const s8b bh = *reinterpret_cast<const s8b*>(wh + wb);
                    const s8b bl = *reinterpret_cast<const s8b*>(wl + wb);
                    accA[n2] = __builtin_amdgcn_mfma_f32_32x32x16_bf16(ah, bh, accA[n2], 0, 0, 0);
                    accB[n2] = __builtin_amdgcn_mfma_f32_32x32x16_bf16(al2, bh, accB[n2], 0, 0, 0);
                    accB[n2] = __builtin_amdgcn_mfma_f32_32x32x16_bf16(ah, bl, accB[n2], 0, 0, 0);
                }
            }
        }
        if (i + 1 < np) {
            __syncthreads();
            writerow();
            __syncthreads();
        }
    }

    const size_t outrow = ((size_t)((b * SD + d) * SD + h)) * SD;
#pragma unroll
    for (int n2 = 0; n2 < 2; ++n2) {
        const int cout = wn * 64 + n2 * 32 + ln;
        const float bv = bias[cout];
        float sc = 0.f, mm = 0.f, bb2 = 0.f, aa = 0.f;
        if constexpr (EPI == 3) {
            sc = g[cout] * (1.0f / sqrtf(vr[cout] + 1e-3f));
            mm = mn[cout]; bb2 = be[cout]; aa = al[cout];
        }
        if constexpr (EPI == 2) aa = al[cout];
#pragma unroll
        for (int r = 0; r < 16; ++r) {
            const int rl = (r & 3) + 8 * (r >> 2) + 4 * half;
            const size_t oe = (outrow + wm2 * 32 + rl) * COUT + cout;
            float y = accA[n2][r] + accB[n2][r] + bv;
            if constexpr (EPI == 0) y = fmaxf(y, 0.f);
            else if constexpr (EPI == 1) y = y / (1.f + expf(-y));
            else if constexpr (EPI == 2) y = y > 0.f ? y : aa * y;
            else {
                float t2 = (y - mm) * sc + bb2;
                t2 = t2 > 0.f ? t2 : aa * t2;
                float sv = b2f(skh[oe]) + b2f(skl[oe]);
                y = fmaxf(sv + t2, 0.f);
            }
            const bf16_t hh = f2b(y);
            oh[oe] = hh;
            ol[oe] = f2b(y - b2f(hh));
        }
    }
}

// ---------------- convT stride-2 k=4 (du0, split-2, T14-staged) -------------
__global__ __launch_bounds__(256)
void convTm(const bf16_t* __restrict__ xh, const bf16_t* __restrict__ xl,
            const bf16_t* __restrict__ wh, const bf16_t* __restrict__ wl,
            const float* __restrict__ bias,
            bf16_t* __restrict__ oh, bf16_t* __restrict__ ol)
{
    constexpr int NT = 256, LP = (32 * 128) / (4 * NT);
    __shared__ bf16_t lh[32 * 128], ll[32 * 128];

    const int tid  = threadIdx.x;
    const int lane = tid & 63;
    const int wid  = tid >> 6;
    const int wn   = wid & 1, p = wid >> 1;
    const int half = lane >> 5, ln = lane & 31;
    const int nwg  = gridDim.x;
    const int bid  = (blockIdx.x & 7) * (nwg >> 3) + (blockIdx.x >> 3);
    const int ohh  = bid % 64;
    const int od   = (bid / 64) % 64;
    const int b    = bid / 4096;
    const int pd = od & 1, dz = od >> 1;
    const int ph = ohh & 1, hy = ohh >> 1;
    const int cout = wn * 32 + ln;
    const int boff = cout * 128 + half * 8;

    int pz[4], py[4], pt[4], np = 0;
    for (int jd = 0; jd < 2; ++jd) {
        const int kd = pd + 2 * jd;
        const int iz = dz + pd - 1 + jd;
        if ((unsigned)iz >= 32u) continue;
        for (int jh = 0; jh < 2; ++jh) {
            const int kh = ph + 2 * jh;
            const int iy = hy + ph - 1 + jh;
            if ((unsigned)iy >= 32u) continue;
            pz[np] = iz; py[np] = iy; pt[np] = (kd * 4 + kh) * 4; ++np;
        }
    }

    f32x16 accA, accB;
#pragma unroll
    for (int i = 0; i < 16; ++i) { accA[i] = 0.0f; accB[i] = 0.0f; }

    ushort4 rh[LP], rl2[LP];
    auto loadrow = [&](int iz, int iy) {
        const size_t rb = ((size_t)((b * 32 + iz) * 32 + iy)) * 32 * 128;
#pragma unroll
        for (int j = 0; j < LP; ++j) {
            const int idx = (tid + j * NT) * 4;
            rh[j]  = *reinterpret_cast<const ushort4*>(xh + rb + idx);
            rl2[j] = *reinterpret_cast<const ushort4*>(xl + rb + idx);
        }
    };
    auto writerow = [&]() {
#pragma unroll
        for (int j = 0; j < LP; ++j) {
            const int idx = (tid + j * NT) * 4;
            const int vox = idx / 128, ch = idx % 128;
            const int bo = ((vox * 128 + ch) * 2) ^ ((vox & 7) << 4);
            *reinterpret_cast<ushort4*>((char*)&lh[0] + bo) = rh[j];
            *reinterpret_cast<ushort4*>((char*)&ll[0] + bo) = rl2[j];
        }
    };

    loadrow(pz[0], py[0]);
    writerow();
    __syncthreads();
#pragma unroll 1
    for (int i = 0; i < np; ++i) {
        if (i + 1 < np) loadrow(pz[i + 1], py[i + 1]);
#pragma unroll
        for (int jw = 0; jw < 2; ++jw) {
            const int kw = p + 2 * jw;
            const int ix = ln + p - 1 + jw;
            const bool edge = (unsigned)ix >= 32u;
            const int xcl = edge ? ln : ix;
            const size_t wbase = (size_t)(pt[i] + kw) * 128 * 64 + boff;
            const s8b zz = {};
#pragma unroll
            for (int ks = 0; ks < 8; ++ks) {
                const int bo = ((xcl * 128 + half * 8 + ks * 16) * 2) ^ ((xcl & 7) << 4);
                s8b a  = *reinterpret_cast<const s8b*>((const char*)&lh[0] + bo);
                s8b a2 = *reinterpret_cast<const s8b*>((const char*)&ll[0] + bo);
                if (edge) { a = zz; a2 = zz; }
                const s8b bb = *reinterpret_cast<const s8b*>(wh + wbase + ks * 16);
                const s8b b2 = *reinterpret_cast<const s8b*>(wl + wbase + ks * 16);
                accA = __builtin_amdgcn_mfma_f32_32x32x16_bf16(a, bb, accA, 0, 0, 0);
                accB = __builtin_amdgcn_mfma_f32_32x32x16_bf16(a2, bb, accB, 0, 0, 0);
                accB = __builtin_amdgcn_mfma_f32_32x32x16_bf16(a, b2, accB, 0, 0, 0);
            }
        }
        if (i + 1 < np) {
            __syncthreads();
            writerow();
            __syncthreads();
        }
    }

    const float bv = bias[cout];
#pragma unroll
    for (int r = 0; r < 16; ++r) {
        const int rl = (r & 3) + 8 * (r >> 2) + 4 * half;
        const int ow = 2 * rl + p;
        const size_t oe = (((size_t)((b * 64 + od) * 64 + ohh)) * 64 + ow) * 64 + cout;
        const float y = fmaxf(accA[r] + accB[r] + bv, 0.f);
        const bf16_t hh = f2b(y);
        oh[oe] = hh;
        ol[oe] = f2b(y - b2f(hh));
    }
}

// ---------------- ec0: s2 k=4, CIN=1, fp32 direct, fp32 out -----------------
__global__ __launch_bounds__(256)
void conv_ec0f(const float* __restrict__ in, const float* __restrict__ wt,
               const float* __restrict__ bias, float* __restrict__ out)
{
    const int co  = threadIdx.x;
    const int vox = blockIdx.x * 4 + threadIdx.y;
    const int w = vox % 64; int rem = vox / 64;
    const int h = rem % 64; rem /= 64;
    const int d = rem % 64; rem /= 64;
    const int b = rem;
    float acc = bias[co];
#pragma unroll 1
    for (int kd = 0; kd < 4; ++kd) {
        const int iz = 2 * d + kd - 1;
        if ((unsigned)iz >= 128u) continue;
#pragma unroll 1
        for (int kh = 0; kh < 4; ++kh) {
            const int iy = 2 * h + kh - 1;
            if ((unsigned)iy >= 128u) continue;
#pragma unroll
            for (int kw = 0; kw < 4; ++kw) {
                const int ix = 2 * w + kw - 1;
                if ((unsigned)ix >= 128u) continue;
                const float xv = in[(size_t)((b * 128 + iz) * 128 + iy) * 128 + ix];
                acc = fmaf(xv, wt[((kd * 4 + kh) * 4 + kw) * 64 + co], acc);
            }
        }
    }
    out[(size_t)vox * 64 + co] = fmaxf(acc, 0.f);
}

// ---------------- du1: convT s2 k=4, CIN=64, COUT=1, split-2 in -------------
__global__ __launch_bounds__(256)
void convT_du1b(const bf16_t* __restrict__ inh, const bf16_t* __restrict__ inl,
                const float* __restrict__ wt, const float* __restrict__ bias,
                float* __restrict__ out)
{
    const int vox = blockIdx.x * 256 + threadIdx.x;
    const int ow = vox % 128; int rem = vox / 128;
    const int ohh = rem % 128; rem /= 128;
    const int od = rem % 128; rem /= 128;
    const int b  = rem;
    const int pd = od & 1, dz = od >> 1;
    const int ph = ohh & 1, hy = ohh >> 1;
    const int pw = ow & 1, wx = ow >> 1;
    float acc = bias[0];
#pragma unroll 1
    for (int jd = 0; jd < 2; ++jd) {
        const int kd = pd + 2 * jd, iz = dz + pd - 1 + jd;
        if ((unsigned)iz >= 64u) continue;
#pragma unroll 1
        for (int jh = 0; jh < 2; ++jh) {
            const int kh = ph + 2 * jh, iy = hy + ph - 1 + jh;
            if ((unsigned)iy >= 64u) continue;
#pragma unroll 1
            for (int jw = 0; jw < 2; ++jw) {
                const int kw = pw + 2 * jw, ix = wx + pw - 1 + jw;
                if ((unsigned)ix >= 64u) continue;
                const size_t base = (size_t)(((b * 64 + iz) * 64 + iy) * 64 + ix) * 64;
                const float* wp = wt + (size_t)((kd * 4 + kh) * 4 + kw) * 64;
#pragma unroll
                for (int c8 = 0; c8 < 8; ++c8) {
                    const s8b vh = *reinterpret_cast<const s8b*>(inh + base + c8 * 8);
                    const s8b vl = *reinterpret_cast<const s8b*>(inl + base + c8 * 8);
#pragma unroll
                    for (int j = 0; j < 8; ++j)
                        acc = fmaf(b2f((bf16_t)vh[j]) + b2f((bf16_t)vl[j]), wp[c8 * 8 + j], acc);
                }
            }
        }
    }
    out[vox] = acc;
}

// --------------------------------- VQ ---------------------------------------
__global__ void zero512(float* __restrict__ p) { p[threadIdx.x] = 0.0f; }

__global__ void vq_cnorm(const float* __restrict__ cb, float* __restrict__ cnorm)
{
    const int k = blockIdx.x * 64 + threadIdx.x;
    float s = 0.0f;
    for (int ci = 0; ci < 64; ++ci) { const float c = cb[k * 64 + ci]; s = fmaf(c, c, s); }
    cnorm[k] = s;
}

__global__ __launch_bounds__(256)
void vq_assign(const float* __restrict__ z, const float* __restrict__ cb,
               const float* __restrict__ cnorm, int* __restrict__ idx,
               float* __restrict__ hist, int N)
{
    const int n = blockIdx.x * 256 + threadIdx.x;
    const float4* zp = reinterpret_cast<const float4*>(z + (size_t)n * 64);
    float4 zv[16];
    float z2 = 0.0f;
#pragma unroll
    for (int i = 0; i < 16; ++i) {
        zv[i] = zp[i];
        z2 += zv[i].x * zv[i].x + zv[i].y * zv[i].y + zv[i].z * zv[i].z + zv[i].w * zv[i].w;
    }
    float best = 3.4e38f;
    int bi = 0;
#pragma unroll 1
    for (int k = 0; k < 512; ++k) {
        const float4* cp = reinterpret_cast<const float4*>(cb + (size_t)k * 64);
        float dot = 0.0f;
#pragma unroll
        for (int i = 0; i < 16; ++i) {
            const float4 c = cp[i];
            dot += zv[i].x * c.x + zv[i].y * c.y + zv[i].z * c.z + zv[i].w * c.w;
        }
        const float dist = z2 + cnorm[k] - 2.0f * dot;
        if (dist < best) { best = dist; bi = k; }
    }
    idx[n] = bi;
    atomicAdd(&hist[bi], 1.0f);
}

__global__ __launch_bounds__(256)
void vq_gather_split(const float* __restrict__ cb, const int* __restrict__ idx,
                     bf16_t* __restrict__ zh, bf16_t* __restrict__ zl)
{
    const int gid = blockIdx.x * 256 + threadIdx.x;
    const int n = gid >> 4, c4 = gid & 15;
    const int k = idx[n];
    const float4 c = reinterpret_cast<const float4*>(cb)[k * 16 + c4];
    ushort4 h, l;
    h.x = f2b(c.x); l.x = f2b(c.x - b2f(h.x));
    h.y = f2b(c.y); l.y = f2b(c.y - b2f(h.y));
    h.z = f2b(c.z); l.z = f2b(c.z - b2f(h.z));
    h.w = f2b(c.w); l.w = f2b(c.w - b2f(h.w));
    reinterpret_cast<ushort4*>(zh)[gid] = h;
    reinterpret_cast<ushort4*>(zl)[gid] = l;
}

__global__ __launch_bounds__(512)
void perplexity_k(const float* __restrict__ hist, float* __restrict__ out, float invN)
{
    __shared__ float red[512];
    const int t = threadIdx.x;
    const float p = hist[t] * invN;
    red[t] = p * logf(p + 1e-12f);
    __syncthreads();
    for (int s = 256; s > 0; s >>= 1) {
        if (t < s) red[t] += red[t + s];
        __syncthreads();
    }
    if (t == 0) out[0] = expf(-red[0]);
}

// ---------------------------------------------------------------------------
extern "C" void kernel_launch(void* const* d_in, const int* in_sizes, int n_in,
                              void* d_out, int out_size, void* d_ws, size_t ws_size,
                              hipStream_t stream)
{
    const float* x       = (const float*)d_in[0];
    const float* ec0_w   = (const float*)d_in[1];
    const float* ec0_b   = (const float*)d_in[2];
    const float* er0_c1w = (const float*)d_in[3];
    const float* er0_c1b = (const float*)d_in[4];
    const float* er0_c2w = (const float*)d_in[5];
    const float* er0_c2b = (const float*)d_in[6];
    const float* er0_g   = (const float*)d_in[7];
    const float* er0_be  = (const float*)d_in[8];
    const float* er0_m   = (const float*)d_in[9];
    const float* er0_v   = (const float*)d_in[10];
    const float* er0_a   = (const float*)d_in[11];
    const float* ec1_w   = (const float*)d_in[12];
    const float* ec1_b   = (const float*)d_in[13];
    const float* er1_c1w = (const float*)d_in[14];
    const float* er1_c1b = (const float*)d_in[15];
    const float* er1_c2w = (const float*)d_in[16];
    const float* er1_c2b = (const float*)d_in[17];
    const float* er1_g   = (const float*)d_in[18];
    const float* er1_be  = (const float*)d_in[19];
    const float* er1_m   = (const float*)d_in[20];
    const float* er1_v   = (const float*)d_in[21];
    const float* er1_a   = (const float*)d_in[22];
    const float* eo_w    = (const float*)d_in[23];
    const float* eo_b    = (const float*)d_in[24];
    const float* eo_a    = (const float*)d_in[25];
    const float* cb      = (const float*)d_in[26];
    const float* dc0_w   = (const float*)d_in[27];
    const float* dc0_b   = (const float*)d_in[28];
    const float* dc0_a   = (const float*)d_in[29];
    const float* dr0_c1w = (const float*)d_in[30];
    const float* dr0_c1b = (const float*)d_in[31];
    const float* dr0_c2w = (const float*)d_in[32];
    const float* dr0_c2b = (const float*)d_in[33];
    const float* dr0_g   = (const float*)d_in[34];
    const float* dr0_be  = (const float*)d_in[35];
    const float* dr0_m   = (const float*)d_in[36];
    const float* dr0_v   = (const float*)d_in[37];
    const float* dr0_a   = (const float*)d_in[38];
    const float* du0_w   = (const float*)d_in[39];
    const float* du0_b   = (const float*)d_in[40];
    const float* dr1_c1w = (const float*)d_in[41];
    const float* dr1_c1b = (const float*)d_in[42];
    const float* dr1_c2w = (const float*)d_in[43];
    const float* dr1_c2b = (const float*)d_in[44];
    const float* dr1_g   = (const float*)d_in[45];
    const float* dr1_be  = (const float*)d_in[46];
    const float* dr1_m   = (const float*)d_in[47];
    const float* dr1_v   = (const float*)d_in[48];
    const float* dr1_a   = (const float*)d_in[49];
    const float* du1_w   = (const float*)d_in[50];
    const float* du1_b   = (const float*)d_in[51];

    float* out = (float*)d_out;

    // ---- ws: A=[0,134MB) , H=[134MB,268MB) ----
    char* W = (char*)d_ws;
    float*  Af  = (float*)(W);
    float*  Hf  = (float*)(W + 134217728);
    float*  E1f = (float*)(W + 134217728);
    float*  R1f = (float*)(W + 134217728 + 33554432);
    float*  Zf  = (float*)(W);
    int*    IDX = (int*)  (W + 16777216);
    float*  CN  = (float*)(W + 17039360);
    float*  HS  = (float*)(W + 17041408);
    bf16_t* ZQh = (bf16_t*)(W + 33554432);
    bf16_t* ZQl = (bf16_t*)(W + 41943040);
    bf16_t* D0h = (bf16_t*)(W + 50331648);
    bf16_t* D0l = (bf16_t*)(W + 67108864);
    bf16_t* Gh  = (bf16_t*)(W + 83886080);
    bf16_t* Gl  = (bf16_t*)(W + 100663296);
    bf16_t* U0h = (bf16_t*)(W + 134217728);
    bf16_t* U0l = (bf16_t*)(W + 201326592);
    bf16_t* G1h = (bf16_t*)(W);
    bf16_t* G1l = (bf16_t*)(W + 67108864);

    // ---- weight arenas in d_out ----
    char* WB = (char*)d_out;
    bf16_t* e0c1h = (bf16_t*)(WB + 0);
    bf16_t* e0c1m = (bf16_t*)(WB + 221184);
    bf16_t* e0c1l = (bf16_t*)(WB + 442368);
    bf16_t* e0c2h = (bf16_t*)(WB + 663552);
    bf16_t* e0c2m = (bf16_t*)(WB + 884736);
    bf16_t* e0c2l = (bf16_t*)(WB + 1105920);
    bf16_t* ec1h  = (bf16_t*)(WB + 1327104);
    bf16_t* ec1m  = (bf16_t*)(WB + 2375680);
    bf16_t* ec1l  = (bf16_t*)(WB + 3424256);
    bf16_t* e1c1h = (bf16_t*)(WB + 4472832);
    bf16_t* e1c1m = (bf16_t*)(WB + 5357568);
    bf16_t* e1c1l = (bf16_t*)(WB + 6242304);
    bf16_t* e1c2h = (bf16_t*)(WB + 7127040);
    bf16_t* e1c2m = (bf16_t*)(WB + 8011776);
    bf16_t* e1c2l = (bf16_t*)(WB + 8896512);
    bf16_t* eoh   = (bf16_t*)(WB + 9781248);
    bf16_t* eom   = (bf16_t*)(WB + 10223616);
    bf16_t* eol   = (bf16_t*)(WB + 10665984);
    bf16_t* dc0h  = (bf16_t*)(WB + 0);
    bf16_t* dc0l  = (bf16_t*)(WB + 442368);
    bf16_t* d0c1h = (bf16_t*)(WB + 884736);
    bf16_t* d0c1l = (bf16_t*)(WB + 1769472);
    bf16_t* d0c2h = (bf16_t*)(WB + 2654208);
    bf16_t* d0c2l = (bf16_t*)(WB + 3538944);
    bf16_t* du0h  = (bf16_t*)(WB + 4423680);
    bf16_t* du0l  = (bf16_t*)(WB + 5472256);
    bf16_t* d1c1h = (bf16_t*)(WB + 6520832);
    bf16_t* d1c1l = (bf16_t*)(WB + 6742016);
    bf16_t* d1c2h = (bf16_t*)(WB + 6963200);
    bf16_t* d1c2l = (bf16_t*)(WB + 7184384);

    const float* fn = nullptr;
    const bf16_t* bn_ = nullptr;

    // ---- encoder weight prep (split-3) ----
    wprep3<<<432, 256, 0, stream>>>(er0_c1w, e0c1h, e0c1m, e0c1l, 64, 64, 110592);
    wprep3<<<432, 256, 0, stream>>>(er0_c2w, e0c2h, e0c2m, e0c2l, 64, 64, 110592);
    wprep3<<<2048, 256, 0, stream>>>(ec1_w, ec1h, ec1m, ec1l, 64, 128, 524288);
    wprep3<<<1728, 256, 0, stream>>>(er1_c1w, e1c1h, e1c1m, e1c1l, 128, 128, 442368);
    wprep3<<<1728, 256, 0, stream>>>(er1_c2w, e1c2h, e1c2m, e1c2l, 128, 128, 442368);
    wprep3<<<864, 256, 0, stream>>>(eo_w, eoh, eom, eol, 128, 64, 221184);

    // ---- encoder (fp32-class) ----
    conv_ec0f<<<131072, dim3(64, 4), 0, stream>>>(x, ec0_w, ec0_b, Af);

    conv3e<64, 64, 64, 1, 1><<<8192, 128, 0, stream>>>(
        Af, e0c1h, e0c1m, e0c1l, er0_c1b, fn, fn, fn, fn, fn, fn, Hf);
    conv3e<64, 64, 64, 1, 3><<<8192, 128, 0, stream>>>(
        Hf, e0c2h, e0c2m, e0c2l, er0_c2b, er0_g, er0_be, er0_m, er0_v, er0_a, Af, Af);

    convs2e<<<2048, 128, 0, stream>>>(Af, ec1h, ec1m, ec1l, ec1_b, E1f);

    conv3e<128, 128, 32, 2, 1><<<2048, 128, 0, stream>>>(
        E1f, e1c1h, e1c1m, e1c1l, er1_c1b, fn, fn, fn, fn, fn, fn, R1f);
    conv3e<128, 128, 32, 2, 3><<<2048, 128, 0, stream>>>(
        R1f, e1c2h, e1c2m, e1c2l, er1_c2b, er1_g, er1_be, er1_m, er1_v, er1_a, E1f, E1f);

    conv3e<128, 64, 32, 1, 2><<<2048, 64, 0, stream>>>(
        E1f, eoh, eom, eol, eo_b, fn, fn, fn, fn, eo_a, fn, Zf);

    // ---- VQ (exact fp32) ----
    vq_cnorm<<<8, 64, 0, stream>>>(cb, CN);
    zero512<<<1, 512, 0, stream>>>(HS);
    vq_assign<<<256, 256, 0, stream>>>(Zf, cb, CN, IDX, HS, 65536);
    perplexity_k<<<1, 512, 0, stream>>>(HS, out + 4194304, 1.0f / 65536.0f);
    vq_gather_split<<<4096, 256, 0, stream>>>(cb, IDX, ZQh, ZQl);

    // ---- decoder weight prep (split-2, overwrites encoder arena) ----
    wprep_split<<<864, 256, 0, stream>>>(dc0_w, dc0h, dc0l, 64, 128, 221184);
    wprep_split<<<1728, 256, 0, stream>>>(dr0_c1w, d0c1h, d0c1l, 128, 128, 442368);
    wprep_split<<<1728, 256, 0, stream>>>(dr0_c2w, d0c2h, d0c2l, 128, 128, 442368);
    wprep_split<<<2048, 256, 0, stream>>>(du0_w, du0h, du0l, 128, 64, 524288);
    wprep_split<<<432, 256, 0, stream>>>(dr1_c1w, d1c1h, d1c1l, 64, 64, 110592);
    wprep_split<<<432, 256, 0, stream>>>(dr1_c2w, d1c2h, d1c2l, 64, 64, 110592);

    // ---- decoder (split-2 bf16) ----
    conv3d<64, 128, 32, 2, 2><<<2048, 128, 0, stream>>>(
        ZQh, ZQl, dc0h, dc0l, dc0_b, fn, fn, fn, fn, dc0_a, bn_, bn_, D0h, D0l);
    conv3d<128, 128, 32, 2, 1><<<2048, 128, 0, stream>>>(
        D0h, D0l, d0c1h, d0c1l, dr0_c1b, fn, fn, fn, fn, fn, bn_, bn_, Gh, Gl);
    conv3d<128, 128, 32, 2, 3><<<2048, 128, 0, stream>>>(
        Gh, Gl, d0c2h, d0c2l, dr0_c2b, dr0_g, dr0_be, dr0_m, dr0_v, dr0_a,
        D0h, D0l, D0h, D0l);

    convTm<<<8192, 256, 0, stream>>>(D0h, D0l, du0h, du0l, du0_b, U0h, U0l);

    conv3d<64, 64, 64, 1, 1><<<8192, 128, 0, stream>>>(
        U0h, U0l, d1c1h, d1c1l, dr1_c1b, fn, fn, fn, fn, fn, bn_, bn_, G1h, G1l);
    conv3d<64, 64, 64, 1, 3><<<8192, 128, 0, stream>>>(
        G1h, G1l, d1c2h, d1c2l, dr1_c2b, dr1_g, dr1_be, dr1_m, dr1_v, dr1_a,
        U0h, U0l, U0h, U0l);

    convT_du1b<<<16384, 256, 0, stream>>>(U0h, U0l, du1_w, du1_b, out);
}

// Round 9
// 7087.019 us; speedup vs baseline: 8.7987x; 1.5409x over previous
//
#include <hip/hip_runtime.h>
#include <cstdint>

// ---------------------------------------------------------------------------
// VQVAE forward — MFMA implicit-GEMM convolutions, channels-last.
//
// Encoder: fp32 activations in memory; EXACT 3-way bf16 split (v = h+m+l)
//   at LDS-stage time; 6-MFMA products => fp32-class => VQ argmin safe.
// Decoder: split-2 bf16 (hi/lo) storage, 3-pass MFMA.
//
// Round-9: FRAGMENT-MAJOR WEIGHT LAYOUT  w[tap][ks][half][cout][8k].
//   B-fragment loads are now lane-contiguous (2 x 512B blocks per wave
//   instead of 64 scattered 64B sectors) — removes the L1-transaction
//   bottleneck identified in round 8 (2.6M L1 req/CU ~= measured 1.35ms).
// Retained: T14 async-STAGE single-LDS-buffer, T1 XCD-chunked swizzle,
//   LDS XOR swizzle byte ^= (vox&7)<<4.
//
// C layout: col = lane&31, row = (reg&3) + 8*(reg>>2) + 4*(lane>>5)
// ---------------------------------------------------------------------------

typedef unsigned short bf16_t;
typedef __attribute__((ext_vector_type(8)))  short s8b;     // 8 x bf16 frag
typedef __attribute__((ext_vector_type(16))) float f32x16;  // 32x32 acc

__device__ __forceinline__ float b2f(bf16_t u) { return __uint_as_float((unsigned)u << 16); }
__device__ __forceinline__ bf16_t f2b(float f) {
    unsigned x = __float_as_uint(f);
    return (bf16_t)((x + 0x7FFFu + ((x >> 16) & 1u)) >> 16);
}

__device__ __forceinline__ void split3s(float v, unsigned short& h,
                                        unsigned short& m, unsigned short& l)
{
    const unsigned uv = __float_as_uint(v);
    const float fh = __uint_as_float(uv & 0xFFFF0000u);
    const float r1 = v - fh;
    const unsigned u1 = __float_as_uint(r1);
    const float fm = __uint_as_float(u1 & 0xFFFF0000u);
    const float r2 = r1 - fm;
    h = (unsigned short)(uv >> 16);
    m = (unsigned short)(u1 >> 16);
    l = (unsigned short)(__float_as_uint(r2) >> 16);
}

// ------------------------- weight prep ------------------------------------
// src [tap][ci][co] fp32 -> dst fragment-major [tap][ks][half][co][8k]
__device__ __forceinline__ int wdst(int tap, int ci_, int co_, int ci, int co)
{
    const int ks = ci_ >> 4, half = (ci_ >> 3) & 1, j = ci_ & 7;
    return (((tap * (ci >> 4) + ks) * 2 + half) * co + co_) * 8 + j;
}

__global__ __launch_bounds__(256)
void wprep3(const float* __restrict__ w, bf16_t* __restrict__ h,
            bf16_t* __restrict__ m, bf16_t* __restrict__ l,
            int ci, int co, int n)
{
    const int i = blockIdx.x * 256 + threadIdx.x;
    if (i >= n) return;
    const int co_ = i % co;
    const int ci_ = (i / co) % ci;
    const int tap = i / (co * ci);
    const int dst = wdst(tap, ci_, co_, ci, co);
    unsigned short hh, mm, ll2;
    split3s(w[i], hh, mm, ll2);
    h[dst] = hh; m[dst] = mm; l[dst] = ll2;
}

__global__ __launch_bounds__(256)
void wprep_split(const float* __restrict__ w, bf16_t* __restrict__ hi,
                 bf16_t* __restrict__ lo, int ci, int co, int n)
{
    const int i = blockIdx.x * 256 + threadIdx.x;
    if (i >= n) return;
    const int co_ = i % co;
    const int ci_ = (i / co) % ci;
    const int tap = i / (co * ci);
    const float v = w[i];
    const int dst = wdst(tap, ci_, co_, ci, co);
    const bf16_t h = f2b(v);
    hi[dst] = h;
    lo[dst] = f2b(v - b2f(h));
}

// ---------------- encoder 3x3x3 conv: fp32 in, T14-staged split-3 -----------
// EPI: 0=ReLU 1=swish 2=PReLU 3=BN+PReLU+skip+ReLU
template<int CIN, int COUT, int SD, int NW, int EPI>
__global__ __launch_bounds__((SD / 32) * NW * 64)
void conv3e(const float* __restrict__ xf,
            const bf16_t* __restrict__ wh, const bf16_t* __restrict__ wm,
            const bf16_t* __restrict__ wl,
            const float* __restrict__ bias,
            const float* __restrict__ g, const float* __restrict__ be,
            const float* __restrict__ mn, const float* __restrict__ vr,
            const float* __restrict__ al,
            const float* skf, float* __restrict__ of)
{
    constexpr int NT = (SD / 32) * NW * 64;
    constexpr int LP = (SD * CIN) / (4 * NT);
    constexpr int KS = CIN / 16;
    __shared__ bf16_t lh[SD * CIN], lm[SD * CIN], ll[SD * CIN];

    const int tid  = threadIdx.x;
    const int lane = tid & 63;
    const int wid  = tid >> 6;
    const int wn   = wid % NW, wm2 = wid / NW;
    const int half = lane >> 5, ln = lane & 31;
    const int w    = wm2 * 32 + ln;
    const int nwg  = gridDim.x;
    const int bid  = (blockIdx.x & 7) * (nwg >> 3) + (blockIdx.x >> 3);
    const int h    = bid % SD;
    const int d    = (bid / SD) % SD;
    const int b    = bid / (SD * SD);
    const int cout0 = wn * 64 + ln;

    int pz[9], py[9], pt[9], np = 0;
    for (int kd = 0; kd < 3; ++kd) {
        const int iz = d + kd - 1;
        if ((unsigned)iz >= (unsigned)SD) continue;
        for (int kh = 0; kh < 3; ++kh) {
            const int iy = h + kh - 1;
            if ((unsigned)iy >= (unsigned)SD) continue;
            pz[np] = iz; py[np] = iy; pt[np] = (kd * 3 + kh) * 3; ++np;
        }
    }

    f32x16 accA[2], accB[2];
#pragma unroll
    for (int i = 0; i < 16; ++i) {
        accA[0][i] = 0.f; accA[1][i] = 0.f;
        accB[0][i] = 0.f; accB[1][i] = 0.f;
    }

    float4 rg[LP];
    auto loadrow = [&](int iz, int iy) {
        const float* src = xf + ((size_t)((b * SD + iz) * SD + iy)) * SD * CIN;
#pragma unroll
        for (int j = 0; j < LP; ++j)
            rg[j] = *reinterpret_cast<const float4*>(src + (size_t)(tid + j * NT) * 4);
    };
    auto writerow = [&]() {
#pragma unroll
        for (int j = 0; j < LP; ++j) {
            const int idx = (tid + j * NT) * 4;
            const int vox = idx / CIN, ch = idx % CIN;
            ushort4 h4, m4, l4;
            split3s(rg[j].x, h4.x, m4.x, l4.x);
            split3s(rg[j].y, h4.y, m4.y, l4.y);
            split3s(rg[j].z, h4.z, m4.z, l4.z);
            split3s(rg[j].w, h4.w, m4.w, l4.w);
            const int bo = ((vox * CIN + ch) * 2) ^ ((vox & 7) << 4);
            *reinterpret_cast<ushort4*>((char*)&lh[0] + bo) = h4;
            *reinterpret_cast<ushort4*>((char*)&lm[0] + bo) = m4;
            *reinterpret_cast<ushort4*>((char*)&ll[0] + bo) = l4;
        }
    };

    loadrow(pz[0], py[0]);
    writerow();
    __syncthreads();
#pragma unroll 1
    for (int i = 0; i < np; ++i) {
        if (i + 1 < np) loadrow(pz[i + 1], py[i + 1]);   // issue early (T14)
#pragma unroll
        for (int kw = 0; kw < 3; ++kw) {
            const int tap = pt[i] + kw;
            const int iw = w + kw - 1;
            const bool edge = (unsigned)iw >= (unsigned)SD;
            const int wcl = edge ? w : iw;
            const s8b zz = {};
#pragma unroll
            for (int ks = 0; ks < KS; ++ks) {
                const int bo = ((wcl * CIN + half * 8 + ks * 16) * 2) ^ ((wcl & 7) << 4);
                s8b ah  = *reinterpret_cast<const s8b*>((const char*)&lh[0] + bo);
                s8b am  = *reinterpret_cast<const s8b*>((const char*)&lm[0] + bo);
                s8b al3 = *reinterpret_cast<const s8b*>((const char*)&ll[0] + bo);
                if (edge) { ah = zz; am = zz; al3 = zz; }
                const size_t wb0 = ((size_t)((tap * KS + ks) * 2 + half) * COUT + cout0) * 8;
#pragma unroll
                for (int n2 = 0; n2 < 2; ++n2) {
                    const size_t wb = wb0 + n2 * 256;   // cout += 32
                    const s8b bh = *reinterpret_cast<const s8b*>(wh + wb);
                    const s8b bm = *reinterpret_cast<const s8b*>(wm + wb);
                    const s8b bl = *reinterpret_cast<const s8b*>(wl + wb);
                    accA[n2] = __builtin_amdgcn_mfma_f32_32x32x16_bf16(ah, bh, accA[n2], 0, 0, 0);
                    accB[n2] = __builtin_amdgcn_mfma_f32_32x32x16_bf16(ah, bm, accB[n2], 0, 0, 0);
                    accA[n2] = __builtin_amdgcn_mfma_f32_32x32x16_bf16(am, bh, accA[n2], 0, 0, 0);
                    accB[n2] = __builtin_amdgcn_mfma_f32_32x32x16_bf16(am, bm, accB[n2], 0, 0, 0);
                    accA[n2] = __builtin_amdgcn_mfma_f32_32x32x16_bf16(al3, bh, accA[n2], 0, 0, 0);
                    accB[n2] = __builtin_amdgcn_mfma_f32_32x32x16_bf16(ah, bl, accB[n2], 0, 0, 0);
                }
            }
        }
        if (i + 1 < np) {
            __syncthreads();          // all waves done reading LDS
            writerow();               // implicit vmcnt wait on rg here
            __syncthreads();          // LDS ready
        }
    }

    const size_t outrow = ((size_t)((b * SD + d) * SD + h)) * SD;
#pragma unroll
    for (int n2 = 0; n2 < 2; ++n2) {
        const int cout = wn * 64 + n2 * 32 + ln;
        const float bv = bias[cout];
        float sc = 0.f, mm = 0.f, bb2 = 0.f, aa = 0.f;
        if constexpr (EPI == 3) {
            sc = g[cout] * (1.0f / sqrtf(vr[cout] + 1e-3f));
            mm = mn[cout]; bb2 = be[cout]; aa = al[cout];
        }
        if constexpr (EPI == 2) aa = al[cout];
#pragma unroll
        for (int r = 0; r < 16; ++r) {
            const int rl = (r & 3) + 8 * (r >> 2) + 4 * half;
            const size_t oe = (outrow + wm2 * 32 + rl) * COUT + cout;
            float y = accA[n2][r] + accB[n2][r] + bv;
            if constexpr (EPI == 0) y = fmaxf(y, 0.f);
            else if constexpr (EPI == 1) y = y / (1.f + expf(-y));
            else if constexpr (EPI == 2) y = y > 0.f ? y : aa * y;
            else {
                float t2 = (y - mm) * sc + bb2;
                t2 = t2 > 0.f ? t2 : aa * t2;
                y = fmaxf(skf[oe] + t2, 0.f);
            }
            of[oe] = y;
        }
    }
}

// ---------------- ec1: stride-2 k=4, fp32 in, T14-staged split-3 ------------
__global__ __launch_bounds__(128)
void convs2e(const float* __restrict__ xf,
             const bf16_t* __restrict__ wh, const bf16_t* __restrict__ wm,
             const bf16_t* __restrict__ wl,
             const float* __restrict__ bias, float* __restrict__ of)
{
    constexpr int NT = 128, LP = (64 * 64) / (4 * NT);
    __shared__ bf16_t lh[64 * 64], lm[64 * 64], ll[64 * 64];

    const int tid  = threadIdx.x;
    const int lane = tid & 63;
    const int wn   = tid >> 6;
    const int half = lane >> 5, ln = lane & 31;
    const int nwg  = gridDim.x;
    const int bid  = (blockIdx.x & 7) * (nwg >> 3) + (blockIdx.x >> 3);
    const int h    = bid % 32;
    const int d    = (bid / 32) % 32;
    const int b    = bid / 1024;
    const int cout0 = wn * 64 + ln;

    int pz[16], py[16], pt[16], np = 0;
    for (int kd = 0; kd < 4; ++kd) {
        const int iz = 2 * d + kd - 1;
        if ((unsigned)iz >= 64u) continue;
        for (int kh = 0; kh < 4; ++kh) {
            const int iy = 2 * h + kh - 1;
            if ((unsigned)iy >= 64u) continue;
            pz[np] = iz; py[np] = iy; pt[np] = (kd * 4 + kh) * 4; ++np;
        }
    }

    f32x16 accA[2], accB[2];
#pragma unroll
    for (int i = 0; i < 16; ++i) {
        accA[0][i] = 0.f; accA[1][i] = 0.f;
        accB[0][i] = 0.f; accB[1][i] = 0.f;
    }

    float4 rg[LP];
    auto loadrow = [&](int iz, int iy) {
        const float* src = xf + ((size_t)((b * 64 + iz) * 64 + iy)) * 64 * 64;
#pragma unroll
        for (int j = 0; j < LP; ++j)
            rg[j] = *reinterpret_cast<const float4*>(src + (size_t)(tid + j * NT) * 4);
    };
    auto writerow = [&]() {
#pragma unroll
        for (int j = 0; j < LP; ++j) {
            const int idx = (tid + j * NT) * 4;
            const int vox = idx / 64, ch = idx % 64;
            ushort4 h4, m4, l4;
            split3s(rg[j].x, h4.x, m4.x, l4.x);
            split3s(rg[j].y, h4.y, m4.y, l4.y);
            split3s(rg[j].z, h4.z, m4.z, l4.z);
            split3s(rg[j].w, h4.w, m4.w, l4.w);
            const int bo = ((vox * 64 + ch) * 2) ^ ((vox & 7) << 4);
            *reinterpret_cast<ushort4*>((char*)&lh[0] + bo) = h4;
            *reinterpret_cast<ushort4*>((char*)&lm[0] + bo) = m4;
            *reinterpret_cast<ushort4*>((char*)&ll[0] + bo) = l4;
        }
    };

    loadrow(pz[0], py[0]);
    writerow();
    __syncthreads();
#pragma unroll 1
    for (int i = 0; i < np; ++i) {
        if (i + 1 < np) loadrow(pz[i + 1], py[i + 1]);
#pragma unroll
        for (int kw = 0; kw < 4; ++kw) {
            const int tap = pt[i] + kw;
            const int iw = 2 * ln + kw - 1;
            const bool edge = (unsigned)iw >= 64u;
            const int wcl = edge ? 2 * ln : iw;
            const s8b zz = {};
#pragma unroll
            for (int ks = 0; ks < 4; ++ks) {
                const int bo = ((wcl * 64 + half * 8 + ks * 16) * 2) ^ ((wcl & 7) << 4);
                s8b ah  = *reinterpret_cast<const s8b*>((const char*)&lh[0] + bo);
                s8b am  = *reinterpret_cast<const s8b*>((const char*)&lm[0] + bo);
                s8b al3 = *reinterpret_cast<const s8b*>((const char*)&ll[0] + bo);
                if (edge) { ah = zz; am = zz; al3 = zz; }
                const size_t wb0 = ((size_t)((tap * 4 + ks) * 2 + half) * 128 + cout0) * 8;
#pragma unroll
                for (int n2 = 0; n2 < 2; ++n2) {
                    const size_t wb = wb0 + n2 * 256;
                    const s8b bh = *reinterpret_cast<const s8b*>(wh + wb);
                    const s8b bm = *reinterpret_cast<const s8b*>(wm + wb);
                    const s8b bl = *reinterpret_cast<const s8b*>(wl + wb);
                    accA[n2] = __builtin_amdgcn_mfma_f32_32x32x16_bf16(ah, bh, accA[n2], 0, 0, 0);
                    accB[n2] = __builtin_amdgcn_mfma_f32_32x32x16_bf16(ah, bm, accB[n2], 0, 0, 0);
                    accA[n2] = __builtin_amdgcn_mfma_f32_32x32x16_bf16(am, bh, accA[n2], 0, 0, 0);
                    accB[n2] = __builtin_amdgcn_mfma_f32_32x32x16_bf16(am, bm, accB[n2], 0, 0, 0);
                    accA[n2] = __builtin_amdgcn_mfma_f32_32x32x16_bf16(al3, bh, accA[n2], 0, 0, 0);
                    accB[n2] = __builtin_amdgcn_mfma_f32_32x32x16_bf16(ah, bl, accB[n2], 0, 0, 0);
                }
            }
        }
        if (i + 1 < np) {
            __syncthreads();
            writerow();
            __syncthreads();
        }
    }

    const size_t outrow = ((size_t)((b * 32 + d) * 32 + h)) * 32;
#pragma unroll
    for (int n2 = 0; n2 < 2; ++n2) {
        const int cout = wn * 64 + n2 * 32 + ln;
        const float bv = bias[cout];
#pragma unroll
        for (int r = 0; r < 16; ++r) {
            const int rl = (r & 3) + 8 * (r >> 2) + 4 * half;
            const size_t oe = (outrow + rl) * 128 + cout;
            of[oe] = fmaxf(accA[n2][r] + accB[n2][r] + bv, 0.f);
        }
    }
}

// ---------------- decoder 3x3x3 conv: split-2 bf16, T14-staged --------------
template<int CIN, int COUT, int SD, int NW, int EPI>
__global__ __launch_bounds__((SD / 32) * NW * 64)
void conv3d(const bf16_t* __restrict__ xh, const bf16_t* __restrict__ xl,
            const bf16_t* __restrict__ wh, const bf16_t* __restrict__ wl,
            const float* __restrict__ bias,
            const float* __restrict__ g, const float* __restrict__ be,
            const float* __restrict__ mn, const float* __restrict__ vr,
            const float* __restrict__ al,
            const bf16_t* skh, const bf16_t* skl,
            bf16_t* oh, bf16_t* ol)
{
    constexpr int NT = (SD / 32) * NW * 64;
    constexpr int LP = (SD * CIN) / (4 * NT);
    constexpr int KS = CIN / 16;
    __shared__ bf16_t lh[SD * CIN], ll[SD * CIN];

    const int tid  = threadIdx.x;
    const int lane = tid & 63;
    const int wid  = tid >> 6;
    const int wn   = wid % NW, wm2 = wid / NW;
    const int half = lane >> 5, ln = lane & 31;
    const int w    = wm2 * 32 + ln;
    const int nwg  = gridDim.x;
    const int bid  = (blockIdx.x & 7) * (nwg >> 3) + (blockIdx.x >> 3);
    const int h    = bid % SD;
    const int d    = (bid / SD) % SD;
    const int b    = bid / (SD * SD);
    const int cout0 = wn * 64 + ln;

    int pz[9], py[9], pt[9], np = 0;
    for (int kd = 0; kd < 3; ++kd) {
        const int iz = d + kd - 1;
        if ((unsigned)iz >= (unsigned)SD) continue;
        for (int kh = 0; kh < 3; ++kh) {
            const int iy = h + kh - 1;
            if ((unsigned)iy >= (unsigned)SD) continue;
            pz[np] = iz; py[np] = iy; pt[np] = (kd * 3 + kh) * 3; ++np;
        }
    }

    f32x16 accA[2], accB[2];
#pragma unroll
    for (int i = 0; i < 16; ++i) {
        accA[0][i] = 0.f; accA[1][i] = 0.f;
        accB[0][i] = 0.f; accB[1][i] = 0.f;
    }

    ushort4 rh[LP], rl2[LP];
    auto loadrow = [&](int iz, int iy) {
        const size_t rb = ((size_t)((b * SD + iz) * SD + iy)) * SD * CIN;
#pragma unroll
        for (int j = 0; j < LP; ++j) {
            const int idx = (tid + j * NT) * 4;
            rh[j]  = *reinterpret_cast<const ushort4*>(xh + rb + idx);
            rl2[j] = *reinterpret_cast<const ushort4*>(xl + rb + idx);
        }
    };
    auto writerow = [&]() {
#pragma unroll
        for (int j = 0; j < LP; ++j) {
            const int idx = (tid + j * NT) * 4;
            const int vox = idx / CIN, ch = idx % CIN;
            const int bo = ((vox * CIN + ch) * 2) ^ ((vox & 7) << 4);
            *reinterpret_cast<ushort4*>((char*)&lh[0] + bo) = rh[j];
            *reinterpret_cast<ushort4*>((char*)&ll[0] + bo) = rl2[j];
        }
    };

    loadrow(pz[0], py[0]);
    writerow();
    __syncthreads();
#pragma unroll 1
    for (int i = 0; i < np; ++i) {
        if (i + 1 < np) loadrow(pz[i + 1], py[i + 1]);
#pragma unroll
        for (int kw = 0; kw < 3; ++kw) {
            const int tap = pt[i] + kw;
            const int iw = w + kw - 1;
            const bool edge = (unsigned)iw >= (unsigned)SD;
            const int wcl = edge ? w : iw;
            const s8b zz = {};
#pragma unroll
            for (int ks = 0; ks < KS; ++ks) {
                const int bo = ((wcl * CIN + half * 8 + ks * 16) * 2) ^ ((wcl & 7) << 4);
                s8b ah  = *reinterpret_cast<const s8b*>((const char*)&lh[0] + bo);
                s8b al2 = *reinterpret_cast<const s8b*>((const char*)&ll[0] + bo);
                if (edge) { ah = zz; al2 = zz; }
                const size_t wb0 = ((size_t)((tap * KS + ks) * 2 + half) * COUT + cout0) * 8;
#pragma unroll
                for (int n2 = 0; n2 < 2; ++n2) {
                    const size_t wb = wb0 + n2 * 256;
                    const s8b bh = *reinterpret_cast<const s8b*>(wh + wb);
                    const s8b bl = *reinterpret_cast<const s8b*>(wl + wb);
                    accA[n2] = __builtin_amdgcn_mfma_f32_32x32x16_bf16(ah, bh, accA[n2], 0, 0, 0);
                    accB[n2] = __builtin_amdgcn_mfma_f32_32x32x16_bf16(al2, bh, accB[n2], 0, 0, 0);
                    accB[n2] = __builtin_amdgcn_mfma_f32_32x32x16_bf16(ah, bl, accB[n2], 0, 0, 0);
                }
            }
        }
        if (i + 1 < np) {
            __syncthreads();
            writerow();
            __syncthreads();
        }
    }

    const size_t outrow = ((size_t)((b * SD + d) * SD + h)) * SD;
#pragma unroll
    for (int n2 = 0; n2 < 2; ++n2) {
        const int cout = wn * 64 + n2 * 32 + ln;
        const float bv = bias[cout];
        float sc = 0.f, mm = 0.f, bb2 = 0.f, aa = 0.f;
        if constexpr (EPI == 3) {
            sc = g[cout] * (1.0f / sqrtf(vr[cout] + 1e-3f));
            mm = mn[cout]; bb2 = be[cout]; aa = al[cout];
        }
        if constexpr (EPI == 2) aa = al[cout];
#pragma unroll
        for (int r = 0; r < 16; ++r) {
            const int rl = (r & 3) + 8 * (r >> 2) + 4 * half;
            const size_t oe = (outrow + wm2 * 32 + rl) * COUT + cout;
            float y = accA[n2][r] + accB[n2][r] + bv;
            if constexpr (EPI == 0) y = fmaxf(y, 0.f);
            else if constexpr (EPI == 1) y = y / (1.f + expf(-y));
            else if constexpr (EPI == 2) y = y > 0.f ? y : aa * y;
            else {
                float t2 = (y - mm) * sc + bb2;
                t2 = t2 > 0.f ? t2 : aa * t2;
                float sv = b2f(skh[oe]) + b2f(skl[oe]);
                y = fmaxf(sv + t2, 0.f);
            }
            const bf16_t hh = f2b(y);
            oh[oe] = hh;
            ol[oe] = f2b(y - b2f(hh));
        }
    }
}

// ---------------- convT stride-2 k=4 (du0, split-2, T14-staged) -------------
__global__ __launch_bounds__(256)
void convTm(const bf16_t* __restrict__ xh, const bf16_t* __restrict__ xl,
            const bf16_t* __restrict__ wh, const bf16_t* __restrict__ wl,
            const float* __restrict__ bias,
            bf16_t* __restrict__ oh, bf16_t* __restrict__ ol)
{
    constexpr int NT = 256, LP = (32 * 128) / (4 * NT);
    __shared__ bf16_t lh[32 * 128], ll[32 * 128];

    const int tid  = threadIdx.x;
    const int lane = tid & 63;
    const int wid  = tid >> 6;
    const int wn   = wid & 1, p = wid >> 1;
    const int half = lane >> 5, ln = lane & 31;
    const int nwg  = gridDim.x;
    const int bid  = (blockIdx.x & 7) * (nwg >> 3) + (blockIdx.x >> 3);
    const int ohh  = bid % 64;
    const int od   = (bid / 64) % 64;
    const int b    = bid / 4096;
    const int pd = od & 1, dz = od >> 1;
    const int ph = ohh & 1, hy = ohh >> 1;
    const int cout = wn * 32 + ln;

    int pz[4], py[4], pt[4], np = 0;
    for (int jd = 0; jd < 2; ++jd) {
        const int kd = pd + 2 * jd;
        const int iz = dz + pd - 1 + jd;
        if ((unsigned)iz >= 32u) continue;
        for (int jh = 0; jh < 2; ++jh) {
            const int kh = ph + 2 * jh;
            const int iy = hy + ph - 1 + jh;
            if ((unsigned)iy >= 32u) continue;
            pz[np] = iz; py[np] = iy; pt[np] = (kd * 4 + kh) * 4; ++np;
        }
    }

    f32x16 accA, accB;
#pragma unroll
    for (int i = 0; i < 16; ++i) { accA[i] = 0.0f; accB[i] = 0.0f; }

    ushort4 rh[LP], rl2[LP];
    auto loadrow = [&](int iz, int iy) {
        const size_t rb = ((size_t)((b * 32 + iz) * 32 + iy)) * 32 * 128;
#pragma unroll
        for (int j = 0; j < LP; ++j) {
            const int idx = (tid + j * NT) * 4;
            rh[j]  = *reinterpret_cast<const ushort4*>(xh + rb + idx);
            rl2[j] = *reinterpret_cast<const ushort4*>(xl + rb + idx);
        }
    };
    auto writerow = [&]() {
#pragma unroll
        for (int j = 0; j < LP; ++j) {
            const int idx = (tid + j * NT) * 4;
            const int vox = idx / 128, ch = idx % 128;
            const int bo = ((vox * 128 + ch) * 2) ^ ((vox & 7) << 4);
            *reinterpret_cast<ushort4*>((char*)&lh[0] + bo) = rh[j];
            *reinterpret_cast<ushort4*>((char*)&ll[0] + bo) = rl2[j];
        }
    };

    loadrow(pz[0], py[0]);
    writerow();
    __syncthreads();
#pragma unroll 1
    for (int i = 0; i < np; ++i) {
        if (i + 1 < np) loadrow(pz[i + 1], py[i + 1]);
#pragma unroll
        for (int jw = 0; jw < 2; ++jw) {
            const int kw = p + 2 * jw;
            const int tap = pt[i] + kw;
            const int ix = ln + p - 1 + jw;
            const bool edge = (unsigned)ix >= 32u;
            const int xcl = edge ? ln : ix;
            const s8b zz = {};
#pragma unroll
            for (int ks = 0; ks < 8; ++ks) {
                const int bo = ((xcl * 128 + half * 8 + ks * 16) * 2) ^ ((xcl & 7) << 4);
                s8b a  = *reinterpret_cast<const s8b*>((const char*)&lh[0] + bo);
                s8b a2 = *reinterpret_cast<const s8b*>((const char*)&ll[0] + bo);
                if (edge) { a = zz; a2 = zz; }
                const size_t wb = ((size_t)((tap * 8 + ks) * 2 + half) * 64 + cout) * 8;
                const s8b bb = *reinterpret_cast<const s8b*>(wh + wb);
                const s8b b2 = *reinterpret_cast<const s8b*>(wl + wb);
                accA = __builtin_amdgcn_mfma_f32_32x32x16_bf16(a, bb, accA, 0, 0, 0);
                accB = __builtin_amdgcn_mfma_f32_32x32x16_bf16(a2, bb, accB, 0, 0, 0);
                accB = __builtin_amdgcn_mfma_f32_32x32x16_bf16(a, b2, accB, 0, 0, 0);
            }
        }
        if (i + 1 < np) {
            __syncthreads();
            writerow();
            __syncthreads();
        }
    }

    const float bv = bias[cout];
#pragma unroll
    for (int r = 0; r < 16; ++r) {
        const int rl = (r & 3) + 8 * (r >> 2) + 4 * half;
        const int ow = 2 * rl + p;
        const size_t oe = (((size_t)((b * 64 + od) * 64 + ohh)) * 64 + ow) * 64 + cout;
        const float y = fmaxf(accA[r] + accB[r] + bv, 0.f);
        const bf16_t hh = f2b(y);
        oh[oe] = hh;
        ol[oe] = f2b(y - b2f(hh));
    }
}

// ---------------- ec0: s2 k=4, CIN=1, fp32 direct, fp32 out -----------------
__global__ __launch_bounds__(256)
void conv_ec0f(const float* __restrict__ in, const float* __restrict__ wt,
               const float* __restrict__ bias, float* __restrict__ out)
{
    const int co  = threadIdx.x;
    const int vox = blockIdx.x * 4 + threadIdx.y;
    const int w = vox % 64; int rem = vox / 64;
    const int h = rem % 64; rem /= 64;
    const int d = rem % 64; rem /= 64;
    const int b = rem;
    float acc = bias[co];
#pragma unroll 1
    for (int kd = 0; kd < 4; ++kd) {
        const int iz = 2 * d + kd - 1;
        if ((unsigned)iz >= 128u) continue;
#pragma unroll 1
        for (int kh = 0; kh < 4; ++kh) {
            const int iy = 2 * h + kh - 1;
            if ((unsigned)iy >= 128u) continue;
#pragma unroll
            for (int kw = 0; kw < 4; ++kw) {
                const int ix = 2 * w + kw - 1;
                if ((unsigned)ix >= 128u) continue;
                const float xv = in[(size_t)((b * 128 + iz) * 128 + iy) * 128 + ix];
                acc = fmaf(xv, wt[((kd * 4 + kh) * 4 + kw) * 64 + co], acc);
            }
        }
    }
    out[(size_t)vox * 64 + co] = fmaxf(acc, 0.f);
}

// ---------------- du1: convT s2 k=4, CIN=64, COUT=1, split-2 in -------------
__global__ __launch_bounds__(256)
void convT_du1b(const bf16_t* __restrict__ inh, const bf16_t* __restrict__ inl,
                const float* __restrict__ wt, const float* __restrict__ bias,
                float* __restrict__ out)
{
    const int vox = blockIdx.x * 256 + threadIdx.x;
    const int ow = vox % 128; int rem = vox / 128;
    const int ohh = rem % 128; rem /= 128;
    const int od = rem % 128; rem /= 128;
    const int b  = rem;
    const int pd = od & 1, dz = od >> 1;
    const int ph = ohh & 1, hy = ohh >> 1;
    const int pw = ow & 1, wx = ow >> 1;
    float acc = bias[0];
#pragma unroll 1
    for (int jd = 0; jd < 2; ++jd) {
        const int kd = pd + 2 * jd, iz = dz + pd - 1 + jd;
        if ((unsigned)iz >= 64u) continue;
#pragma unroll 1
        for (int jh = 0; jh < 2; ++jh) {
            const int kh = ph + 2 * jh, iy = hy + ph - 1 + jh;
            if ((unsigned)iy >= 64u) continue;
#pragma unroll 1
            for (int jw = 0; jw < 2; ++jw) {
                const int kw = pw + 2 * jw, ix = wx + pw - 1 + jw;
                if ((unsigned)ix >= 64u) continue;
                const size_t base = (size_t)(((b * 64 + iz) * 64 + iy) * 64 + ix) * 64;
                const float* wp = wt + (size_t)((kd * 4 + kh) * 4 + kw) * 64;
#pragma unroll
                for (int c8 = 0; c8 < 8; ++c8) {
                    const s8b vh = *reinterpret_cast<const s8b*>(inh + base + c8 * 8);
                    const s8b vl = *reinterpret_cast<const s8b*>(inl + base + c8 * 8);
#pragma unroll
                    for (int j = 0; j < 8; ++j)
                        acc = fmaf(b2f((bf16_t)vh[j]) + b2f((bf16_t)vl[j]), wp[c8 * 8 + j], acc);
                }
            }
        }
    }
    out[vox] = acc;
}

// --------------------------------- VQ ---------------------------------------
__global__ void zero512(float* __restrict__ p) { p[threadIdx.x] = 0.0f; }

__global__ void vq_cnorm(const float* __restrict__ cb, float* __restrict__ cnorm)
{
    const int k = blockIdx.x * 64 + threadIdx.x;
    float s = 0.0f;
    for (int ci = 0; ci < 64; ++ci) { const float c = cb[k * 64 + ci]; s = fmaf(c, c, s); }
    cnorm[k] = s;
}

__global__ __launch_bounds__(256)
void vq_assign(const float* __restrict__ z, const float* __restrict__ cb,
               const float* __restrict__ cnorm, int* __restrict__ idx,
               float* __restrict__ hist, int N)
{
    const int n = blockIdx.x * 256 + threadIdx.x;
    const float4* zp = reinterpret_cast<const float4*>(z + (size_t)n * 64);
    float4 zv[16];
    float z2 = 0.0f;
#pragma unroll
    for (int i = 0; i < 16; ++i) {
        zv[i] = zp[i];
        z2 += zv[i].x * zv[i].x + zv[i].y * zv[i].y + zv[i].z * zv[i].z + zv[i].w * zv[i].w;
    }
    float best = 3.4e38f;
    int bi = 0;
#pragma unroll 1
    for (int k = 0; k < 512; ++k) {
        const float4* cp = reinterpret_cast<const float4*>(cb + (size_t)k * 64);
        float dot = 0.0f;
#pragma unroll
        for (int i = 0; i < 16; ++i) {
            const float4 c = cp[i];
            dot += zv[i].x * c.x + zv[i].y * c.y + zv[i].z * c.z + zv[i].w * c.w;
        }
        const float dist = z2 + cnorm[k] - 2.0f * dot;
        if (dist < best) { best = dist; bi = k; }
    }
    idx[n] = bi;
    atomicAdd(&hist[bi], 1.0f);
}

__global__ __launch_bounds__(256)
void vq_gather_split(const float* __restrict__ cb, const int* __restrict__ idx,
                     bf16_t* __restrict__ zh, bf16_t* __restrict__ zl)
{
    const int gid = blockIdx.x * 256 + threadIdx.x;
    const int n = gid >> 4, c4 = gid & 15;
    const int k = idx[n];
    const float4 c = reinterpret_cast<const float4*>(cb)[k * 16 + c4];
    ushort4 h, l;
    h.x = f2b(c.x); l.x = f2b(c.x - b2f(h.x));
    h.y = f2b(c.y); l.y = f2b(c.y - b2f(h.y));
    h.z = f2b(c.z); l.z = f2b(c.z - b2f(h.z));
    h.w = f2b(c.w); l.w = f2b(c.w - b2f(h.w));
    reinterpret_cast<ushort4*>(zh)[gid] = h;
    reinterpret_cast<ushort4*>(zl)[gid] = l;
}

__global__ __launch_bounds__(512)
void perplexity_k(const float* __restrict__ hist, float* __restrict__ out, float invN)
{
    __shared__ float red[512];
    const int t = threadIdx.x;
    const float p = hist[t] * invN;
    red[t] = p * logf(p + 1e-12f);
    __syncthreads();
    for (int s = 256; s > 0; s >>= 1) {
        if (t < s) red[t] += red[t + s];
        __syncthreads();
    }
    if (t == 0) out[0] = expf(-red[0]);
}

// ---------------------------------------------------------------------------
extern "C" void kernel_launch(void* const* d_in, const int* in_sizes, int n_in,
                              void* d_out, int out_size, void* d_ws, size_t ws_size,
                              hipStream_t stream)
{
    const float* x       = (const float*)d_in[0];
    const float* ec0_w   = (const float*)d_in[1];
    const float* ec0_b   = (const float*)d_in[2];
    const float* er0_c1w = (const float*)d_in[3];
    const float* er0_c1b = (const float*)d_in[4];
    const float* er0_c2w = (const float*)d_in[5];
    const float* er0_c2b = (const float*)d_in[6];
    const float* er0_g   = (const float*)d_in[7];
    const float* er0_be  = (const float*)d_in[8];
    const float* er0_m   = (const float*)d_in[9];
    const float* er0_v   = (const float*)d_in[10];
    const float* er0_a   = (const float*)d_in[11];
    const float* ec1_w   = (const float*)d_in[12];
    const float* ec1_b   = (const float*)d_in[13];
    const float* er1_c1w = (const float*)d_in[14];
    const float* er1_c1b = (const float*)d_in[15];
    const float* er1_c2w = (const float*)d_in[16];
    const float* er1_c2b = (const float*)d_in[17];
    const float* er1_g   = (const float*)d_in[18];
    const float* er1_be  = (const float*)d_in[19];
    const float* er1_m   = (const float*)d_in[20];
    const float* er1_v   = (const float*)d_in[21];
    const float* er1_a   = (const float*)d_in[22];
    const float* eo_w    = (const float*)d_in[23];
    const float* eo_b    = (const float*)d_in[24];
    const float* eo_a    = (const float*)d_in[25];
    const float* cb      = (const float*)d_in[26];
    const float* dc0_w   = (const float*)d_in[27];
    const float* dc0_b   = (const float*)d_in[28];
    const float* dc0_a   = (const float*)d_in[29];
    const float* dr0_c1w = (const float*)d_in[30];
    const float* dr0_c1b = (const float*)d_in[31];
    const float* dr0_c2w = (const float*)d_in[32];
    const float* dr0_c2b = (const float*)d_in[33];
    const float* dr0_g   = (const float*)d_in[34];
    const float* dr0_be  = (const float*)d_in[35];
    const float* dr0_m   = (const float*)d_in[36];
    const float* dr0_v   = (const float*)d_in[37];
    const float* dr0_a   = (const float*)d_in[38];
    const float* du0_w   = (const float*)d_in[39];
    const float* du0_b   = (const float*)d_in[40];
    const float* dr1_c1w = (const float*)d_in[41];
    const float* dr1_c1b = (const float*)d_in[42];
    const float* dr1_c2w = (const float*)d_in[43];
    const float* dr1_c2b = (const float*)d_in[44];
    const float* dr1_g   = (const float*)d_in[45];
    const float* dr1_be  = (const float*)d_in[46];
    const float* dr1_m   = (const float*)d_in[47];
    const float* dr1_v   = (const float*)d_in[48];
    const float* dr1_a   = (const float*)d_in[49];
    const float* du1_w   = (const float*)d_in[50];
    const float* du1_b   = (const float*)d_in[51];

    float* out = (float*)d_out;

    // ---- ws: A=[0,134MB) , H=[134MB,268MB) ----
    char* W = (char*)d_ws;
    float*  Af  = (float*)(W);
    float*  Hf  = (float*)(W + 134217728);
    float*  E1f = (float*)(W + 134217728);
    float*  R1f = (float*)(W + 134217728 + 33554432);
    float*  Zf  = (float*)(W);
    int*    IDX = (int*)  (W + 16777216);
    float*  CN  = (float*)(W + 17039360);
    float*  HS  = (float*)(W + 17041408);
    bf16_t* ZQh = (bf16_t*)(W + 33554432);
    bf16_t* ZQl = (bf16_t*)(W + 41943040);
    bf16_t* D0h = (bf16_t*)(W + 50331648);
    bf16_t* D0l = (bf16_t*)(W + 67108864);
    bf16_t* Gh  = (bf16_t*)(W + 83886080);
    bf16_t* Gl  = (bf16_t*)(W + 100663296);
    bf16_t* U0h = (bf16_t*)(W + 134217728);
    bf16_t* U0l = (bf16_t*)(W + 201326592);
    bf16_t* G1h = (bf16_t*)(W);
    bf16_t* G1l = (bf16_t*)(W + 67108864);

    // ---- weight arenas in d_out ----
    char* WB = (char*)d_out;
    bf16_t* e0c1h = (bf16_t*)(WB + 0);
    bf16_t* e0c1m = (bf16_t*)(WB + 221184);
    bf16_t* e0c1l = (bf16_t*)(WB + 442368);
    bf16_t* e0c2h = (bf16_t*)(WB + 663552);
    bf16_t* e0c2m = (bf16_t*)(WB + 884736);
    bf16_t* e0c2l = (bf16_t*)(WB + 1105920);
    bf16_t* ec1h  = (bf16_t*)(WB + 1327104);
    bf16_t* ec1m  = (bf16_t*)(WB + 2375680);
    bf16_t* ec1l  = (bf16_t*)(WB + 3424256);
    bf16_t* e1c1h = (bf16_t*)(WB + 4472832);
    bf16_t* e1c1m = (bf16_t*)(WB + 5357568);
    bf16_t* e1c1l = (bf16_t*)(WB + 6242304);
    bf16_t* e1c2h = (bf16_t*)(WB + 7127040);
    bf16_t* e1c2m = (bf16_t*)(WB + 8011776);
    bf16_t* e1c2l = (bf16_t*)(WB + 8896512);
    bf16_t* eoh   = (bf16_t*)(WB + 9781248);
    bf16_t* eom   = (bf16_t*)(WB + 10223616);
    bf16_t* eol   = (bf16_t*)(WB + 10665984);
    bf16_t* dc0h  = (bf16_t*)(WB + 0);
    bf16_t* dc0l  = (bf16_t*)(WB + 442368);
    bf16_t* d0c1h = (bf16_t*)(WB + 884736);
    bf16_t* d0c1l = (bf16_t*)(WB + 1769472);
    bf16_t* d0c2h = (bf16_t*)(WB + 2654208);
    bf16_t* d0c2l = (bf16_t*)(WB + 3538944);
    bf16_t* du0h  = (bf16_t*)(WB + 4423680);
    bf16_t* du0l  = (bf16_t*)(WB + 5472256);
    bf16_t* d1c1h = (bf16_t*)(WB + 6520832);
    bf16_t* d1c1l = (bf16_t*)(WB + 6742016);
    bf16_t* d1c2h = (bf16_t*)(WB + 6963200);
    bf16_t* d1c2l = (bf16_t*)(WB + 7184384);

    const float* fn = nullptr;
    const bf16_t* bn_ = nullptr;

    // ---- encoder weight prep (split-3, fragment-major) ----
    wprep3<<<432, 256, 0, stream>>>(er0_c1w, e0c1h, e0c1m, e0c1l, 64, 64, 110592);
    wprep3<<<432, 256, 0, stream>>>(er0_c2w, e0c2h, e0c2m, e0c2l, 64, 64, 110592);
    wprep3<<<2048, 256, 0, stream>>>(ec1_w, ec1h, ec1m, ec1l, 64, 128, 524288);
    wprep3<<<1728, 256, 0, stream>>>(er1_c1w, e1c1h, e1c1m, e1c1l, 128, 128, 442368);
    wprep3<<<1728, 256, 0, stream>>>(er1_c2w, e1c2h, e1c2m, e1c2l, 128, 128, 442368);
    wprep3<<<864, 256, 0, stream>>>(eo_w, eoh, eom, eol, 128, 64, 221184);

    // ---- encoder (fp32-class) ----
    conv_ec0f<<<131072, dim3(64, 4), 0, stream>>>(x, ec0_w, ec0_b, Af);

    conv3e<64, 64, 64, 1, 1><<<8192, 128, 0, stream>>>(
        Af, e0c1h, e0c1m, e0c1l, er0_c1b, fn, fn, fn, fn, fn, fn, Hf);
    conv3e<64, 64, 64, 1, 3><<<8192, 128, 0, stream>>>(
        Hf, e0c2h, e0c2m, e0c2l, er0_c2b, er0_g, er0_be, er0_m, er0_v, er0_a, Af, Af);

    convs2e<<<2048, 128, 0, stream>>>(Af, ec1h, ec1m, ec1l, ec1_b, E1f);

    conv3e<128, 128, 32, 2, 1><<<2048, 128, 0, stream>>>(
        E1f, e1c1h, e1c1m, e1c1l, er1_c1b, fn, fn, fn, fn, fn, fn, R1f);
    conv3e<128, 128, 32, 2, 3><<<2048, 128, 0, stream>>>(
        R1f, e1c2h, e1c2m, e1c2l, er1_c2b, er1_g, er1_be, er1_m, er1_v, er1_a, E1f, E1f);

    conv3e<128, 64, 32, 1, 2><<<2048, 64, 0, stream>>>(
        E1f, eoh, eom, eol, eo_b, fn, fn, fn, fn, eo_a, fn, Zf);

    // ---- VQ (exact fp32) ----
    vq_cnorm<<<8, 64, 0, stream>>>(cb, CN);
    zero512<<<1, 512, 0, stream>>>(HS);
    vq_assign<<<256, 256, 0, stream>>>(Zf, cb, CN, IDX, HS, 65536);
    perplexity_k<<<1, 512, 0, stream>>>(HS, out + 4194304, 1.0f / 65536.0f);
    vq_gather_split<<<4096, 256, 0, stream>>>(cb, IDX, ZQh, ZQl);

    // ---- decoder weight prep (split-2, fragment-major, overwrites arena) ----
    wprep_split<<<864, 256, 0, stream>>>(dc0_w, dc0h, dc0l, 64, 128, 221184);
    wprep_split<<<1728, 256, 0, stream>>>(dr0_c1w, d0c1h, d0c1l, 128, 128, 442368);
    wprep_split<<<1728, 256, 0, stream>>>(dr0_c2w, d0c2h, d0c2l, 128, 128, 442368);
    wprep_split<<<2048, 256, 0, stream>>>(du0_w, du0h, du0l, 128, 64, 524288);
    wprep_split<<<432, 256, 0, stream>>>(dr1_c1w, d1c1h, d1c1l, 64, 64, 110592);
    wprep_split<<<432, 256, 0, stream>>>(dr1_c2w, d1c2h, d1c2l, 64, 64, 110592);

    // ---- decoder (split-2 bf16) ----
    conv3d<64, 128, 32, 2, 2><<<2048, 128, 0, stream>>>(
        ZQh, ZQl, dc0h, dc0l, dc0_b, fn, fn, fn, fn, dc0_a, bn_, bn_, D0h, D0l);
    conv3d<128, 128, 32, 2, 1><<<2048, 128, 0, stream>>>(
        D0h, D0l, d0c1h, d0c1l, dr0_c1b, fn, fn, fn, fn, fn, bn_, bn_, Gh, Gl);
    conv3d<128, 128, 32, 2, 3><<<2048, 128, 0, stream>>>(
        Gh, Gl, d0c2h, d0c2l, dr0_c2b, dr0_g, dr0_be, dr0_m, dr0_v, dr0_a,
        D0h, D0l, D0h, D0l);

    convTm<<<8192, 256, 0, stream>>>(D0h, D0l, du0h, du0l, du0_b, U0h, U0l);

    conv3d<64, 64, 64, 1, 1><<<8192, 128, 0, stream>>>(
        U0h, U0l, d1c1h, d1c1l, dr1_c1b, fn, fn, fn, fn, fn, bn_, bn_, G1h, G1l);
    conv3d<64, 64, 64, 1, 3><<<8192, 128, 0, stream>>>(
        G1h, G1l, d1c2h, d1c2l, dr1_c2b, dr1_g, dr1_be, dr1_m, dr1_v, dr1_a,
        U0h, U0l, U0h, U0l);

    convT_du1b<<<16384, 256, 0, stream>>>(U0h, U0l, du1_w, du1_b, out);
}

// Round 10
// 6203.271 us; speedup vs baseline: 10.0522x; 1.1425x over previous
//
#include <hip/hip_runtime.h>
#include <cstdint>

// ---------------------------------------------------------------------------
// VQVAE forward — MFMA implicit-GEMM convolutions, channels-last.
//
// Encoder: fp32 activations in memory; EXACT 3-way bf16 split (v = h+m+l)
//   at LDS-stage time; 6-MFMA products => fp32-class => VQ argmin safe.
// Decoder: split-2 bf16 (hi/lo) storage, 3-pass MFMA.
//
// Round-10:
//  - convT_du1w: wave-level du1 (lane = input channel). 16 outputs/wave,
//    dedup'd 10-column coalesced input window per (jd,jh), 4 preloaded
//    weight lanes, 16 independent acc chains, 64-lane butterfly reduce.
//    Replaces the 1.2ms latency-bound scalar kernel (~40 ops/output vs 1700).
//  - ec0: 4-way accumulator ILP (static kw-indexed).
// Retained: fragment-major weights w[tap][ks][half][cout][8k], T14 async-
// STAGE single-LDS-buffer, T1 XCD-chunked swizzle, LDS XOR swizzle.
//
// C layout: col = lane&31, row = (reg&3) + 8*(reg>>2) + 4*(lane>>5)
// ---------------------------------------------------------------------------

typedef unsigned short bf16_t;
typedef __attribute__((ext_vector_type(8)))  short s8b;     // 8 x bf16 frag
typedef __attribute__((ext_vector_type(16))) float f32x16;  // 32x32 acc

__device__ __forceinline__ float b2f(bf16_t u) { return __uint_as_float((unsigned)u << 16); }
__device__ __forceinline__ bf16_t f2b(float f) {
    unsigned x = __float_as_uint(f);
    return (bf16_t)((x + 0x7FFFu + ((x >> 16) & 1u)) >> 16);
}

__device__ __forceinline__ void split3s(float v, unsigned short& h,
                                        unsigned short& m, unsigned short& l)
{
    const unsigned uv = __float_as_uint(v);
    const float fh = __uint_as_float(uv & 0xFFFF0000u);
    const float r1 = v - fh;
    const unsigned u1 = __float_as_uint(r1);
    const float fm = __uint_as_float(u1 & 0xFFFF0000u);
    const float r2 = r1 - fm;
    h = (unsigned short)(uv >> 16);
    m = (unsigned short)(u1 >> 16);
    l = (unsigned short)(__float_as_uint(r2) >> 16);
}

// ------------------------- weight prep ------------------------------------
// src [tap][ci][co] fp32 -> dst fragment-major [tap][ks][half][co][8k]
__device__ __forceinline__ int wdst(int tap, int ci_, int co_, int ci, int co)
{
    const int ks = ci_ >> 4, half = (ci_ >> 3) & 1, j = ci_ & 7;
    return (((tap * (ci >> 4) + ks) * 2 + half) * co + co_) * 8 + j;
}

__global__ __launch_bounds__(256)
void wprep3(const float* __restrict__ w, bf16_t* __restrict__ h,
            bf16_t* __restrict__ m, bf16_t* __restrict__ l,
            int ci, int co, int n)
{
    const int i = blockIdx.x * 256 + threadIdx.x;
    if (i >= n) return;
    const int co_ = i % co;
    const int ci_ = (i / co) % ci;
    const int tap = i / (co * ci);
    const int dst = wdst(tap, ci_, co_, ci, co);
    unsigned short hh, mm, ll2;
    split3s(w[i], hh, mm, ll2);
    h[dst] = hh; m[dst] = mm; l[dst] = ll2;
}

__global__ __launch_bounds__(256)
void wprep_split(const float* __restrict__ w, bf16_t* __restrict__ hi,
                 bf16_t* __restrict__ lo, int ci, int co, int n)
{
    const int i = blockIdx.x * 256 + threadIdx.x;
    if (i >= n) return;
    const int co_ = i % co;
    const int ci_ = (i / co) % ci;
    const int tap = i / (co * ci);
    const float v = w[i];
    const int dst = wdst(tap, ci_, co_, ci, co);
    const bf16_t h = f2b(v);
    hi[dst] = h;
    lo[dst] = f2b(v - b2f(h));
}

// ---------------- encoder 3x3x3 conv: fp32 in, T14-staged split-3 -----------
// EPI: 0=ReLU 1=swish 2=PReLU 3=BN+PReLU+skip+ReLU
template<int CIN, int COUT, int SD, int NW, int EPI>
__global__ __launch_bounds__((SD / 32) * NW * 64)
void conv3e(const float* __restrict__ xf,
            const bf16_t* __restrict__ wh, const bf16_t* __restrict__ wm,
            const bf16_t* __restrict__ wl,
            const float* __restrict__ bias,
            const float* __restrict__ g, const float* __restrict__ be,
            const float* __restrict__ mn, const float* __restrict__ vr,
            const float* __restrict__ al,
            const float* skf, float* __restrict__ of)
{
    constexpr int NT = (SD / 32) * NW * 64;
    constexpr int LP = (SD * CIN) / (4 * NT);
    constexpr int KS = CIN / 16;
    __shared__ bf16_t lh[SD * CIN], lm[SD * CIN], ll[SD * CIN];

    const int tid  = threadIdx.x;
    const int lane = tid & 63;
    const int wid  = tid >> 6;
    const int wn   = wid % NW, wm2 = wid / NW;
    const int half = lane >> 5, ln = lane & 31;
    const int w    = wm2 * 32 + ln;
    const int nwg  = gridDim.x;
    const int bid  = (blockIdx.x & 7) * (nwg >> 3) + (blockIdx.x >> 3);
    const int h    = bid % SD;
    const int d    = (bid / SD) % SD;
    const int b    = bid / (SD * SD);
    const int cout0 = wn * 64 + ln;

    int pz[9], py[9], pt[9], np = 0;
    for (int kd = 0; kd < 3; ++kd) {
        const int iz = d + kd - 1;
        if ((unsigned)iz >= (unsigned)SD) continue;
        for (int kh = 0; kh < 3; ++kh) {
            const int iy = h + kh - 1;
            if ((unsigned)iy >= (unsigned)SD) continue;
            pz[np] = iz; py[np] = iy; pt[np] = (kd * 3 + kh) * 3; ++np;
        }
    }

    f32x16 accA[2], accB[2];
#pragma unroll
    for (int i = 0; i < 16; ++i) {
        accA[0][i] = 0.f; accA[1][i] = 0.f;
        accB[0][i] = 0.f; accB[1][i] = 0.f;
    }

    float4 rg[LP];
    auto loadrow = [&](int iz, int iy) {
        const float* src = xf + ((size_t)((b * SD + iz) * SD + iy)) * SD * CIN;
#pragma unroll
        for (int j = 0; j < LP; ++j)
            rg[j] = *reinterpret_cast<const float4*>(src + (size_t)(tid + j * NT) * 4);
    };
    auto writerow = [&]() {
#pragma unroll
        for (int j = 0; j < LP; ++j) {
            const int idx = (tid + j * NT) * 4;
            const int vox = idx / CIN, ch = idx % CIN;
            ushort4 h4, m4, l4;
            split3s(rg[j].x, h4.x, m4.x, l4.x);
            split3s(rg[j].y, h4.y, m4.y, l4.y);
            split3s(rg[j].z, h4.z, m4.z, l4.z);
            split3s(rg[j].w, h4.w, m4.w, l4.w);
            const int bo = ((vox * CIN + ch) * 2) ^ ((vox & 7) << 4);
            *reinterpret_cast<ushort4*>((char*)&lh[0] + bo) = h4;
            *reinterpret_cast<ushort4*>((char*)&lm[0] + bo) = m4;
            *reinterpret_cast<ushort4*>((char*)&ll[0] + bo) = l4;
        }
    };

    loadrow(pz[0], py[0]);
    writerow();
    __syncthreads();
#pragma unroll 1
    for (int i = 0; i < np; ++i) {
        if (i + 1 < np) loadrow(pz[i + 1], py[i + 1]);   // issue early (T14)
#pragma unroll
        for (int kw = 0; kw < 3; ++kw) {
            const int tap = pt[i] + kw;
            const int iw = w + kw - 1;
            const bool edge = (unsigned)iw >= (unsigned)SD;
            const int wcl = edge ? w : iw;
            const s8b zz = {};
#pragma unroll
            for (int ks = 0; ks < KS; ++ks) {
                const int bo = ((wcl * CIN + half * 8 + ks * 16) * 2) ^ ((wcl & 7) << 4);
                s8b ah  = *reinterpret_cast<const s8b*>((const char*)&lh[0] + bo);
                s8b am  = *reinterpret_cast<const s8b*>((const char*)&lm[0] + bo);
                s8b al3 = *reinterpret_cast<const s8b*>((const char*)&ll[0] + bo);
                if (edge) { ah = zz; am = zz; al3 = zz; }
                const size_t wb0 = ((size_t)((tap * KS + ks) * 2 + half) * COUT + cout0) * 8;
#pragma unroll
                for (int n2 = 0; n2 < 2; ++n2) {
                    const size_t wb = wb0 + n2 * 256;   // cout += 32
                    const s8b bh = *reinterpret_cast<const s8b*>(wh + wb);
                    const s8b bm = *reinterpret_cast<const s8b*>(wm + wb);
                    const s8b bl = *reinterpret_cast<const s8b*>(wl + wb);
                    accA[n2] = __builtin_amdgcn_mfma_f32_32x32x16_bf16(ah, bh, accA[n2], 0, 0, 0);
                    accB[n2] = __builtin_amdgcn_mfma_f32_32x32x16_bf16(ah, bm, accB[n2], 0, 0, 0);
                    accA[n2] = __builtin_amdgcn_mfma_f32_32x32x16_bf16(am, bh, accA[n2], 0, 0, 0);
                    accB[n2] = __builtin_amdgcn_mfma_f32_32x32x16_bf16(am, bm, accB[n2], 0, 0, 0);
                    accA[n2] = __builtin_amdgcn_mfma_f32_32x32x16_bf16(al3, bh, accA[n2], 0, 0, 0);
                    accB[n2] = __builtin_amdgcn_mfma_f32_32x32x16_bf16(ah, bl, accB[n2], 0, 0, 0);
                }
            }
        }
        if (i + 1 < np) {
            __syncthreads();          // all waves done reading LDS
            writerow();               // implicit vmcnt wait on rg here
            __syncthreads();          // LDS ready
        }
    }

    const size_t outrow = ((size_t)((b * SD + d) * SD + h)) * SD;
#pragma unroll
    for (int n2 = 0; n2 < 2; ++n2) {
        const int cout = wn * 64 + n2 * 32 + ln;
        const float bv = bias[cout];
        float sc = 0.f, mm = 0.f, bb2 = 0.f, aa = 0.f;
        if constexpr (EPI == 3) {
            sc = g[cout] * (1.0f / sqrtf(vr[cout] + 1e-3f));
            mm = mn[cout]; bb2 = be[cout]; aa = al[cout];
        }
        if constexpr (EPI == 2) aa = al[cout];
#pragma unroll
        for (int r = 0; r < 16; ++r) {
            const int rl = (r & 3) + 8 * (r >> 2) + 4 * half;
            const size_t oe = (outrow + wm2 * 32 + rl) * COUT + cout;
            float y = accA[n2][r] + accB[n2][r] + bv;
            if constexpr (EPI == 0) y = fmaxf(y, 0.f);
            else if constexpr (EPI == 1) y = y / (1.f + expf(-y));
            else if constexpr (EPI == 2) y = y > 0.f ? y : aa * y;
            else {
                float t2 = (y - mm) * sc + bb2;
                t2 = t2 > 0.f ? t2 : aa * t2;
                y = fmaxf(skf[oe] + t2, 0.f);
            }
            of[oe] = y;
        }
    }
}

// ---------------- ec1: stride-2 k=4, fp32 in, T14-staged split-3 ------------
__global__ __launch_bounds__(128)
void convs2e(const float* __restrict__ xf,
             const bf16_t* __restrict__ wh, const bf16_t* __restrict__ wm,
             const bf16_t* __restrict__ wl,
             const float* __restrict__ bias, float* __restrict__ of)
{
    constexpr int NT = 128, LP = (64 * 64) / (4 * NT);
    __shared__ bf16_t lh[64 * 64], lm[64 * 64], ll[64 * 64];

    const int tid  = threadIdx.x;
    const int lane = tid & 63;
    const int wn   = tid >> 6;
    const int half = lane >> 5, ln = lane & 31;
    const int nwg  = gridDim.x;
    const int bid  = (blockIdx.x & 7) * (nwg >> 3) + (blockIdx.x >> 3);
    const int h    = bid % 32;
    const int d    = (bid / 32) % 32;
    const int b    = bid / 1024;
    const int cout0 = wn * 64 + ln;

    int pz[16], py[16], pt[16], np = 0;
    for (int kd = 0; kd < 4; ++kd) {
        const int iz = 2 * d + kd - 1;
        if ((unsigned)iz >= 64u) continue;
        for (int kh = 0; kh < 4; ++kh) {
            const int iy = 2 * h + kh - 1;
            if ((unsigned)iy >= 64u) continue;
            pz[np] = iz; py[np] = iy; pt[np] = (kd * 4 + kh) * 4; ++np;
        }
    }

    f32x16 accA[2], accB[2];
#pragma unroll
    for (int i = 0; i < 16; ++i) {
        accA[0][i] = 0.f; accA[1][i] = 0.f;
        accB[0][i] = 0.f; accB[1][i] = 0.f;
    }

    float4 rg[LP];
    auto loadrow = [&](int iz, int iy) {
        const float* src = xf + ((size_t)((b * 64 + iz) * 64 + iy)) * 64 * 64;
#pragma unroll
        for (int j = 0; j < LP; ++j)
            rg[j] = *reinterpret_cast<const float4*>(src + (size_t)(tid + j * NT) * 4);
    };
    auto writerow = [&]() {
#pragma unroll
        for (int j = 0; j < LP; ++j) {
            const int idx = (tid + j * NT) * 4;
            const int vox = idx / 64, ch = idx % 64;
            ushort4 h4, m4, l4;
            split3s(rg[j].x, h4.x, m4.x, l4.x);
            split3s(rg[j].y, h4.y, m4.y, l4.y);
            split3s(rg[j].z, h4.z, m4.z, l4.z);
            split3s(rg[j].w, h4.w, m4.w, l4.w);
            const int bo = ((vox * 64 + ch) * 2) ^ ((vox & 7) << 4);
            *reinterpret_cast<ushort4*>((char*)&lh[0] + bo) = h4;
            *reinterpret_cast<ushort4*>((char*)&lm[0] + bo) = m4;
            *reinterpret_cast<ushort4*>((char*)&ll[0] + bo) = l4;
        }
    };

    loadrow(pz[0], py[0]);
    writerow();
    __syncthreads();
#pragma unroll 1
    for (int i = 0; i < np; ++i) {
        if (i + 1 < np) loadrow(pz[i + 1], py[i + 1]);
#pragma unroll
        for (int kw = 0; kw < 4; ++kw) {
            const int tap = pt[i] + kw;
            const int iw = 2 * ln + kw - 1;
            const bool edge = (unsigned)iw >= 64u;
            const int wcl = edge ? 2 * ln : iw;
            const s8b zz = {};
#pragma unroll
            for (int ks = 0; ks < 4; ++ks) {
                const int bo = ((wcl * 64 + half * 8 + ks * 16) * 2) ^ ((wcl & 7) << 4);
                s8b ah  = *reinterpret_cast<const s8b*>((const char*)&lh[0] + bo);
                s8b am  = *reinterpret_cast<const s8b*>((const char*)&lm[0] + bo);
                s8b al3 = *reinterpret_cast<const s8b*>((const char*)&ll[0] + bo);
                if (edge) { ah = zz; am = zz; al3 = zz; }
                const size_t wb0 = ((size_t)((tap * 4 + ks) * 2 + half) * 128 + cout0) * 8;
#pragma unroll
                for (int n2 = 0; n2 < 2; ++n2) {
                    const size_t wb = wb0 + n2 * 256;
                    const s8b bh = *reinterpret_cast<const s8b*>(wh + wb);
                    const s8b bm = *reinterpret_cast<const s8b*>(wm + wb);
                    const s8b bl = *reinterpret_cast<const s8b*>(wl + wb);
                    accA[n2] = __builtin_amdgcn_mfma_f32_32x32x16_bf16(ah, bh, accA[n2], 0, 0, 0);
                    accB[n2] = __builtin_amdgcn_mfma_f32_32x32x16_bf16(ah, bm, accB[n2], 0, 0, 0);
                    accA[n2] = __builtin_amdgcn_mfma_f32_32x32x16_bf16(am, bh, accA[n2], 0, 0, 0);
                    accB[n2] = __builtin_amdgcn_mfma_f32_32x32x16_bf16(am, bm, accB[n2], 0, 0, 0);
                    accA[n2] = __builtin_amdgcn_mfma_f32_32x32x16_bf16(al3, bh, accA[n2], 0, 0, 0);
                    accB[n2] = __builtin_amdgcn_mfma_f32_32x32x16_bf16(ah, bl, accB[n2], 0, 0, 0);
                }
            }
        }
        if (i + 1 < np) {
            __syncthreads();
            writerow();
            __syncthreads();
        }
    }

    const size_t outrow = ((size_t)((b * 32 + d) * 32 + h)) * 32;
#pragma unroll
    for (int n2 = 0; n2 < 2; ++n2) {
        const int cout = wn * 64 + n2 * 32 + ln;
        const float bv = bias[cout];
#pragma unroll
        for (int r = 0; r < 16; ++r) {
            const int rl = (r & 3) + 8 * (r >> 2) + 4 * half;
            const size_t oe = (outrow + rl) * 128 + cout;
            of[oe] = fmaxf(accA[n2][r] + accB[n2][r] + bv, 0.f);
        }
    }
}

// ---------------- decoder 3x3x3 conv: split-2 bf16, T14-staged --------------
template<int CIN, int COUT, int SD, int NW, int EPI>
__global__ __launch_bounds__((SD / 32) * NW * 64)
void conv3d(const bf16_t* __restrict__ xh, const bf16_t* __restrict__ xl,
            const bf16_t* __restrict__ wh, const bf16_t* __restrict__ wl,
            const float* __restrict__ bias,
            const float* __restrict__ g, const float* __restrict__ be,
            const float* __restrict__ mn, const float* __restrict__ vr,
            const float* __restrict__ al,
            const bf16_t* skh, const bf16_t* skl,
            bf16_t* oh, bf16_t* ol)
{
    constexpr int NT = (SD / 32) * NW * 64;
    constexpr int LP = (SD * CIN) / (4 * NT);
    constexpr int KS = CIN / 16;
    __shared__ bf16_t lh[SD * CIN], ll[SD * CIN];

    const int tid  = threadIdx.x;
    const int lane = tid & 63;
    const int wid  = tid >> 6;
    const int wn   = wid % NW, wm2 = wid / NW;
    const int half = lane >> 5, ln = lane & 31;
    const int w    = wm2 * 32 + ln;
    const int nwg  = gridDim.x;
    const int bid  = (blockIdx.x & 7) * (nwg >> 3) + (blockIdx.x >> 3);
    const int h    = bid % SD;
    const int d    = (bid / SD) % SD;
    const int b    = bid / (SD * SD);
    const int cout0 = wn * 64 + ln;

    int pz[9], py[9], pt[9], np = 0;
    for (int kd = 0; kd < 3; ++kd) {
        const int iz = d + kd - 1;
        if ((unsigned)iz >= (unsigned)SD) continue;
        for (int kh = 0; kh < 3; ++kh) {
            const int iy = h + kh - 1;
            if ((unsigned)iy >= (unsigned)SD) continue;
            pz[np] = iz; py[np] = iy; pt[np] = (kd * 3 + kh) * 3; ++np;
        }
    }

    f32x16 accA[2], accB[2];
#pragma unroll
    for (int i = 0; i < 16; ++i) {
        accA[0][i] = 0.f; accA[1][i] = 0.f;
        accB[0][i] = 0.f; accB[1][i] = 0.f;
    }

    ushort4 rh[LP], rl2[LP];
    auto loadrow = [&](int iz, int iy) {
        const size_t rb = ((size_t)((b * SD + iz) * SD + iy)) * SD * CIN;
#pragma unroll
        for (int j = 0; j < LP; ++j) {
            const int idx = (tid + j * NT) * 4;
            rh[j]  = *reinterpret_cast<const ushort4*>(xh + rb + idx);
            rl2[j] = *reinterpret_cast<const ushort4*>(xl + rb + idx);
        }
    };
    auto writerow = [&]() {
#pragma unroll
        for (int j = 0; j < LP; ++j) {
            const int idx = (tid + j * NT) * 4;
            const int vox = idx / CIN, ch = idx % CIN;
            const int bo = ((vox * CIN + ch) * 2) ^ ((vox & 7) << 4);
            *reinterpret_cast<ushort4*>((char*)&lh[0] + bo) = rh[j];
            *reinterpret_cast<ushort4*>((char*)&ll[0] + bo) = rl2[j];
        }
    };

    loadrow(pz[0], py[0]);
    writerow();
    __syncthreads();
#pragma unroll 1
    for (int i = 0; i < np; ++i) {
        if (i + 1 < np) loadrow(pz[i + 1], py[i + 1]);
#pragma unroll
        for (int kw = 0; kw < 3; ++kw) {
            const int tap = pt[i] + kw;
            const int iw = w + kw - 1;
            const bool edge = (unsigned)iw >= (unsigned)SD;
            const int wcl = edge ? w : iw;
            const s8b zz = {};
#pragma unroll
            for (int ks = 0; ks < KS; ++ks) {
                const int bo = ((wcl * CIN + half * 8 + ks * 16) * 2) ^ ((wcl & 7) << 4);
                s8b ah  = *reinterpret_cast<const s8b*>((const char*)&lh[0] + bo);
                s8b al2 = *reinterpret_cast<const s8b*>((const char*)&ll[0] + bo);
                if (edge) { ah = zz; al2 = zz; }
                const size_t wb0 = ((size_t)((tap * KS + ks) * 2 + half) * COUT + cout0) * 8;
#pragma unroll
                for (int n2 = 0; n2 < 2; ++n2) {
                    const size_t wb = wb0 + n2 * 256;
                    const s8b bh = *reinterpret_cast<const s8b*>(wh + wb);
                    const s8b bl = *reinterpret_cast<const s8b*>(wl + wb);
                    accA[n2] = __builtin_amdgcn_mfma_f32_32x32x16_bf16(ah, bh, accA[n2], 0, 0, 0);
                    accB[n2] = __builtin_amdgcn_mfma_f32_32x32x16_bf16(al2, bh, accB[n2], 0, 0, 0);
                    accB[n2] = __builtin_amdgcn_mfma_f32_32x32x16_bf16(ah, bl, accB[n2], 0, 0, 0);
                }
            }
        }
        if (i + 1 < np) {
            __syncthreads();
            writerow();
            __syncthreads();
        }
    }

    const size_t outrow = ((size_t)((b * SD + d) * SD + h)) * SD;
#pragma unroll
    for (int n2 = 0; n2 < 2; ++n2) {
        const int cout = wn * 64 + n2 * 32 + ln;
        const float bv = bias[cout];
        float sc = 0.f, mm = 0.f, bb2 = 0.f, aa = 0.f;
        if constexpr (EPI == 3) {
            sc = g[cout] * (1.0f / sqrtf(vr[cout] + 1e-3f));
            mm = mn[cout]; bb2 = be[cout]; aa = al[cout];
        }
        if constexpr (EPI == 2) aa = al[cout];
#pragma unroll
        for (int r = 0; r < 16; ++r) {
            const int rl = (r & 3) + 8 * (r >> 2) + 4 * half;
            const size_t oe = (outrow + wm2 * 32 + rl) * COUT + cout;
            float y = accA[n2][r] + accB[n2][r] + bv;
            if constexpr (EPI == 0) y = fmaxf(y, 0.f);
            else if constexpr (EPI == 1) y = y / (1.f + expf(-y));
            else if constexpr (EPI == 2) y = y > 0.f ? y : aa * y;
            else {
                float t2 = (y - mm) * sc + bb2;
                t2 = t2 > 0.f ? t2 : aa * t2;
                float sv = b2f(skh[oe]) + b2f(skl[oe]);
                y = fmaxf(sv + t2, 0.f);
            }
            const bf16_t hh = f2b(y);
            oh[oe] = hh;
            ol[oe] = f2b(y - b2f(hh));
        }
    }
}

// ---------------- convT stride-2 k=4 (du0, split-2, T14-staged) -------------
__global__ __launch_bounds__(256)
void convTm(const bf16_t* __restrict__ xh, const bf16_t* __restrict__ xl,
            const bf16_t* __restrict__ wh, const bf16_t* __restrict__ wl,
            const float* __restrict__ bias,
            bf16_t* __restrict__ oh, bf16_t* __restrict__ ol)
{
    constexpr int NT = 256, LP = (32 * 128) / (4 * NT);
    __shared__ bf16_t lh[32 * 128], ll[32 * 128];

    const int tid  = threadIdx.x;
    const int lane = tid & 63;
    const int wid  = tid >> 6;
    const int wn   = wid & 1, p = wid >> 1;
    const int half = lane >> 5, ln = lane & 31;
    const int nwg  = gridDim.x;
    const int bid  = (blockIdx.x & 7) * (nwg >> 3) + (blockIdx.x >> 3);
    const int ohh  = bid % 64;
    const int od   = (bid / 64) % 64;
    const int b    = bid / 4096;
    const int pd = od & 1, dz = od >> 1;
    const int ph = ohh & 1, hy = ohh >> 1;
    const int cout = wn * 32 + ln;

    int pz[4], py[4], pt[4], np = 0;
    for (int jd = 0; jd < 2; ++jd) {
        const int kd = pd + 2 * jd;
        const int iz = dz + pd - 1 + jd;
        if ((unsigned)iz >= 32u) continue;
        for (int jh = 0; jh < 2; ++jh) {
            const int kh = ph + 2 * jh;
            const int iy = hy + ph - 1 + jh;
            if ((unsigned)iy >= 32u) continue;
            pz[np] = iz; py[np] = iy; pt[np] = (kd * 4 + kh) * 4; ++np;
        }
    }

    f32x16 accA, accB;
#pragma unroll
    for (int i = 0; i < 16; ++i) { accA[i] = 0.0f; accB[i] = 0.0f; }

    ushort4 rh[LP], rl2[LP];
    auto loadrow = [&](int iz, int iy) {
        const size_t rb = ((size_t)((b * 32 + iz) * 32 + iy)) * 32 * 128;
#pragma unroll
        for (int j = 0; j < LP; ++j) {
            const int idx = (tid + j * NT) * 4;
            rh[j]  = *reinterpret_cast<const ushort4*>(xh + rb + idx);
            rl2[j] = *reinterpret_cast<const ushort4*>(xl + rb + idx);
        }
    };
    auto writerow = [&]() {
#pragma unroll
        for (int j = 0; j < LP; ++j) {
            const int idx = (tid + j * NT) * 4;
            const int vox = idx / 128, ch = idx % 128;
            const int bo = ((vox * 128 + ch) * 2) ^ ((vox & 7) << 4);
            *reinterpret_cast<ushort4*>((char*)&lh[0] + bo) = rh[j];
            *reinterpret_cast<ushort4*>((char*)&ll[0] + bo) = rl2[j];
        }
    };

    loadrow(pz[0], py[0]);
    writerow();
    __syncthreads();
#pragma unroll 1
    for (int i = 0; i < np; ++i) {
        if (i + 1 < np) loadrow(pz[i + 1], py[i + 1]);
#pragma unroll
        for (int jw = 0; jw < 2; ++jw) {
            const int kw = p + 2 * jw;
            const int tap = pt[i] + kw;
            const int ix = ln + p - 1 + jw;
            const bool edge = (unsigned)ix >= 32u;
            const int xcl = edge ? ln : ix;
            const s8b zz = {};
#pragma unroll
            for (int ks = 0; ks < 8; ++ks) {
                const int bo = ((xcl * 128 + half * 8 + ks * 16) * 2) ^ ((xcl & 7) << 4);
                s8b a  = *reinterpret_cast<const s8b*>((const char*)&lh[0] + bo);
                s8b a2 = *reinterpret_cast<const s8b*>((const char*)&ll[0] + bo);
                if (edge) { a = zz; a2 = zz; }
                const size_t wb = ((size_t)((tap * 8 + ks) * 2 + half) * 64 + cout) * 8;
                const s8b bb = *reinterpret_cast<const s8b*>(wh + wb);
                const s8b b2 = *reinterpret_cast<const s8b*>(wl + wb);
                accA = __builtin_amdgcn_mfma_f32_32x32x16_bf16(a, bb, accA, 0, 0, 0);
                accB = __builtin_amdgcn_mfma_f32_32x32x16_bf16(a2, bb, accB, 0, 0, 0);
                accB = __builtin_amdgcn_mfma_f32_32x32x16_bf16(a, b2, accB, 0, 0, 0);
            }
        }
        if (i + 1 < np) {
            __syncthreads();
            writerow();
            __syncthreads();
        }
    }

    const float bv = bias[cout];
#pragma unroll
    for (int r = 0; r < 16; ++r) {
        const int rl = (r & 3) + 8 * (r >> 2) + 4 * half;
        const int ow = 2 * rl + p;
        const size_t oe = (((size_t)((b * 64 + od) * 64 + ohh)) * 64 + ow) * 64 + cout;
        const float y = fmaxf(accA[r] + accB[r] + bv, 0.f);
        const bf16_t hh = f2b(y);
        oh[oe] = hh;
        ol[oe] = f2b(y - b2f(hh));
    }
}

// ---------------- ec0: s2 k=4, CIN=1, fp32 direct, 4-acc ILP ----------------
__global__ __launch_bounds__(256)
void conv_ec0f(const float* __restrict__ in, const float* __restrict__ wt,
               const float* __restrict__ bias, float* __restrict__ out)
{
    const int co  = threadIdx.x;
    const int vox = blockIdx.x * 4 + threadIdx.y;
    const int w = vox % 64; int rem = vox / 64;
    const int h = rem % 64; rem /= 64;
    const int d = rem % 64; rem /= 64;
    const int b = rem;
    float acc[4] = {0.f, 0.f, 0.f, 0.f};
#pragma unroll 1
    for (int kd = 0; kd < 4; ++kd) {
        const int iz = 2 * d + kd - 1;
        if ((unsigned)iz >= 128u) continue;
#pragma unroll 1
        for (int kh = 0; kh < 4; ++kh) {
            const int iy = 2 * h + kh - 1;
            if ((unsigned)iy >= 128u) continue;
#pragma unroll
            for (int kw = 0; kw < 4; ++kw) {   // unrolled -> acc[kw] static
                const int ix = 2 * w + kw - 1;
                if ((unsigned)ix >= 128u) continue;
                const float xv = in[(size_t)((b * 128 + iz) * 128 + iy) * 128 + ix];
                acc[kw] = fmaf(xv, wt[((kd * 4 + kh) * 4 + kw) * 64 + co], acc[kw]);
            }
        }
    }
    const float s = (acc[0] + acc[1]) + (acc[2] + acc[3]) + bias[co];
    out[(size_t)vox * 64 + co] = fmaxf(s, 0.f);
}

// ---------------- du1: convT s2 k=4, CIN=64, COUT=1 — wave-level ------------
// lane = input channel; wave computes 16 consecutive-ow outputs (same row,
// fixed pd/ph). Per (jd,jh): dedup'd 10-column coalesced window + 4 weight
// lanes; 16 independent acc chains; 64-lane butterfly reduce at the end.
__global__ __launch_bounds__(256)
void convT_du1w(const bf16_t* __restrict__ inh, const bf16_t* __restrict__ inl,
                const float* __restrict__ wt, const float* __restrict__ bias,
                float* __restrict__ out)
{
    const int lane = threadIdx.x & 63;
    const int wv   = blockIdx.x * 4 + (threadIdx.x >> 6);
    const size_t obase = (size_t)wv * 16;
    const int ow0 = (int)(obase % 128);
    size_t rem = obase / 128;
    const int ohh = (int)(rem % 128); rem /= 128;
    const int od  = (int)(rem % 128); rem /= 128;
    const int b   = (int)rem;
    const int pd = od & 1, dz = od >> 1;
    const int ph = ohh & 1, hy = ohh >> 1;
    const int wx0 = ow0 >> 1;

    float acc[16];
#pragma unroll
    for (int o = 0; o < 16; ++o) acc[o] = 0.f;

#pragma unroll
    for (int jd = 0; jd < 2; ++jd) {
        const int kd = pd + 2 * jd;
        const int iz = dz + pd - 1 + jd;
        if ((unsigned)iz >= 64u) continue;
#pragma unroll
        for (int jh = 0; jh < 2; ++jh) {
            const int kh = ph + 2 * jh;
            const int iy = hy + ph - 1 + jh;
            if ((unsigned)iy >= 64u) continue;
            const size_t rbase = ((size_t)((b * 64 + iz) * 64 + iy)) * 64;
            // weights for the 4 kw taps (per-lane channel)
            float wv4[4];
#pragma unroll
            for (int kw = 0; kw < 4; ++kw)
                wv4[kw] = wt[(size_t)((kd * 4 + kh) * 4 + kw) * 64 + lane];
            // dedup'd input window: ix = wx0-1 .. wx0+8
            float v[10];
#pragma unroll
            for (int t = 0; t < 10; ++t) {
                const int ix = wx0 - 1 + t;
                if ((unsigned)ix < 64u) {
                    const size_t a = (rbase + ix) * 64 + lane;
                    v[t] = b2f(inh[a]) + b2f(inl[a]);
                } else {
                    v[t] = 0.f;
                }
            }
            // 16 outputs x 2 jw taps, all compile-time indices
#pragma unroll
            for (int o = 0; o < 16; ++o) {
                const int pw = o & 1;
                const int t0 = (o >> 1) + pw;           // jw = 0
                acc[o] = fmaf(v[t0],     wv4[pw],     acc[o]);
                acc[o] = fmaf(v[t0 + 1], wv4[pw + 2], acc[o]);  // jw = 1
            }
        }
    }

    const float b0 = bias[0];
#pragma unroll
    for (int o = 0; o < 16; ++o) {
        float s = acc[o];
        s += __shfl_xor(s, 1);
        s += __shfl_xor(s, 2);
        s += __shfl_xor(s, 4);
        s += __shfl_xor(s, 8);
        s += __shfl_xor(s, 16);
        s += __shfl_xor(s, 32);
        if (lane == 0) out[obase + o] = s + b0;
    }
}

// --------------------------------- VQ ---------------------------------------
__global__ void zero512(float* __restrict__ p) { p[threadIdx.x] = 0.0f; }

__global__ void vq_cnorm(const float* __restrict__ cb, float* __restrict__ cnorm)
{
    const int k = blockIdx.x * 64 + threadIdx.x;
    float s = 0.0f;
    for (int ci = 0; ci < 64; ++ci) { const float c = cb[k * 64 + ci]; s = fmaf(c, c, s); }
    cnorm[k] = s;
}

__global__ __launch_bounds__(256)
void vq_assign(const float* __restrict__ z, const float* __restrict__ cb,
               const float* __restrict__ cnorm, int* __restrict__ idx,
               float* __restrict__ hist, int N)
{
    const int n = blockIdx.x * 256 + threadIdx.x;
    const float4* zp = reinterpret_cast<const float4*>(z + (size_t)n * 64);
    float4 zv[16];
    float z2 = 0.0f;
#pragma unroll
    for (int i = 0; i < 16; ++i) {
        zv[i] = zp[i];
        z2 += zv[i].x * zv[i].x + zv[i].y * zv[i].y + zv[i].z * zv[i].z + zv[i].w * zv[i].w;
    }
    float best = 3.4e38f;
    int bi = 0;
#pragma unroll 1
    for (int k = 0; k < 512; ++k) {
        const float4* cp = reinterpret_cast<const float4*>(cb + (size_t)k * 64);
        float dot = 0.0f;
#pragma unroll
        for (int i = 0; i < 16; ++i) {
            const float4 c = cp[i];
            dot += zv[i].x * c.x + zv[i].y * c.y + zv[i].z * c.z + zv[i].w * c.w;
        }
        const float dist = z2 + cnorm[k] - 2.0f * dot;
        if (dist < best) { best = dist; bi = k; }
    }
    idx[n] = bi;
    atomicAdd(&hist[bi], 1.0f);
}

__global__ __launch_bounds__(256)
void vq_gather_split(const float* __restrict__ cb, const int* __restrict__ idx,
                     bf16_t* __restrict__ zh, bf16_t* __restrict__ zl)
{
    const int gid = blockIdx.x * 256 + threadIdx.x;
    const int n = gid >> 4, c4 = gid & 15;
    const int k = idx[n];
    const float4 c = reinterpret_cast<const float4*>(cb)[k * 16 + c4];
    ushort4 h, l;
    h.x = f2b(c.x); l.x = f2b(c.x - b2f(h.x));
    h.y = f2b(c.y); l.y = f2b(c.y - b2f(h.y));
    h.z = f2b(c.z); l.z = f2b(c.z - b2f(h.z));
    h.w = f2b(c.w); l.w = f2b(c.w - b2f(h.w));
    reinterpret_cast<ushort4*>(zh)[gid] = h;
    reinterpret_cast<ushort4*>(zl)[gid] = l;
}

__global__ __launch_bounds__(512)
void perplexity_k(const float* __restrict__ hist, float* __restrict__ out, float invN)
{
    __shared__ float red[512];
    const int t = threadIdx.x;
    const float p = hist[t] * invN;
    red[t] = p * logf(p + 1e-12f);
    __syncthreads();
    for (int s = 256; s > 0; s >>= 1) {
        if (t < s) red[t] += red[t + s];
        __syncthreads();
    }
    if (t == 0) out[0] = expf(-red[0]);
}

// ---------------------------------------------------------------------------
extern "C" void kernel_launch(void* const* d_in, const int* in_sizes, int n_in,
                              void* d_out, int out_size, void* d_ws, size_t ws_size,
                              hipStream_t stream)
{
    const float* x       = (const float*)d_in[0];
    const float* ec0_w   = (const float*)d_in[1];
    const float* ec0_b   = (const float*)d_in[2];
    const float* er0_c1w = (const float*)d_in[3];
    const float* er0_c1b = (const float*)d_in[4];
    const float* er0_c2w = (const float*)d_in[5];
    const float* er0_c2b = (const float*)d_in[6];
    const float* er0_g   = (const float*)d_in[7];
    const float* er0_be  = (const float*)d_in[8];
    const float* er0_m   = (const float*)d_in[9];
    const float* er0_v   = (const float*)d_in[10];
    const float* er0_a   = (const float*)d_in[11];
    const float* ec1_w   = (const float*)d_in[12];
    const float* ec1_b   = (const float*)d_in[13];
    const float* er1_c1w = (const float*)d_in[14];
    const float* er1_c1b = (const float*)d_in[15];
    const float* er1_c2w = (const float*)d_in[16];
    const float* er1_c2b = (const float*)d_in[17];
    const float* er1_g   = (const float*)d_in[18];
    const float* er1_be  = (const float*)d_in[19];
    const float* er1_m   = (const float*)d_in[20];
    const float* er1_v   = (const float*)d_in[21];
    const float* er1_a   = (const float*)d_in[22];
    const float* eo_w    = (const float*)d_in[23];
    const float* eo_b    = (const float*)d_in[24];
    const float* eo_a    = (const float*)d_in[25];
    const float* cb      = (const float*)d_in[26];
    const float* dc0_w   = (const float*)d_in[27];
    const float* dc0_b   = (const float*)d_in[28];
    const float* dc0_a   = (const float*)d_in[29];
    const float* dr0_c1w = (const float*)d_in[30];
    const float* dr0_c1b = (const float*)d_in[31];
    const float* dr0_c2w = (const float*)d_in[32];
    const float* dr0_c2b = (const float*)d_in[33];
    const float* dr0_g   = (const float*)d_in[34];
    const float* dr0_be  = (const float*)d_in[35];
    const float* dr0_m   = (const float*)d_in[36];
    const float* dr0_v   = (const float*)d_in[37];
    const float* dr0_a   = (const float*)d_in[38];
    const float* du0_w   = (const float*)d_in[39];
    const float* du0_b   = (const float*)d_in[40];
    const float* dr1_c1w = (const float*)d_in[41];
    const float* dr1_c1b = (const float*)d_in[42];
    const float* dr1_c2w = (const float*)d_in[43];
    const float* dr1_c2b = (const float*)d_in[44];
    const float* dr1_g   = (const float*)d_in[45];
    const float* dr1_be  = (const float*)d_in[46];
    const float* dr1_m   = (const float*)d_in[47];
    const float* dr1_v   = (const float*)d_in[48];
    const float* dr1_a   = (const float*)d_in[49];
    const float* du1_w   = (const float*)d_in[50];
    const float* du1_b   = (const float*)d_in[51];

    float* out = (float*)d_out;

    // ---- ws: A=[0,134MB) , H=[134MB,268MB) ----
    char* W = (char*)d_ws;
    float*  Af  = (float*)(W);
    float*  Hf  = (float*)(W + 134217728);
    float*  E1f = (float*)(W + 134217728);
    float*  R1f = (float*)(W + 134217728 + 33554432);
    float*  Zf  = (float*)(W);
    int*    IDX = (int*)  (W + 16777216);
    float*  CN  = (float*)(W + 17039360);
    float*  HS  = (float*)(W + 17041408);
    bf16_t* ZQh = (bf16_t*)(W + 33554432);
    bf16_t* ZQl = (bf16_t*)(W + 41943040);
    bf16_t* D0h = (bf16_t*)(W + 50331648);
    bf16_t* D0l = (bf16_t*)(W + 67108864);
    bf16_t* Gh  = (bf16_t*)(W + 83886080);
    bf16_t* Gl  = (bf16_t*)(W + 100663296);
    bf16_t* U0h = (bf16_t*)(W + 134217728);
    bf16_t* U0l = (bf16_t*)(W + 201326592);
    bf16_t* G1h = (bf16_t*)(W);
    bf16_t* G1l = (bf16_t*)(W + 67108864);

    // ---- weight arenas in d_out ----
    char* WB = (char*)d_out;
    bf16_t* e0c1h = (bf16_t*)(WB + 0);
    bf16_t* e0c1m = (bf16_t*)(WB + 221184);
    bf16_t* e0c1l = (bf16_t*)(WB + 442368);
    bf16_t* e0c2h = (bf16_t*)(WB + 663552);
    bf16_t* e0c2m = (bf16_t*)(WB + 884736);
    bf16_t* e0c2l = (bf16_t*)(WB + 1105920);
    bf16_t* ec1h  = (bf16_t*)(WB + 1327104);
    bf16_t* ec1m  = (bf16_t*)(WB + 2375680);
    bf16_t* ec1l  = (bf16_t*)(WB + 3424256);
    bf16_t* e1c1h = (bf16_t*)(WB + 4472832);
    bf16_t* e1c1m = (bf16_t*)(WB + 5357568);
    bf16_t* e1c1l = (bf16_t*)(WB + 6242304);
    bf16_t* e1c2h = (bf16_t*)(WB + 7127040);
    bf16_t* e1c2m = (bf16_t*)(WB + 8011776);
    bf16_t* e1c2l = (bf16_t*)(WB + 8896512);
    bf16_t* eoh   = (bf16_t*)(WB + 9781248);
    bf16_t* eom   = (bf16_t*)(WB + 10223616);
    bf16_t* eol   = (bf16_t*)(WB + 10665984);
    bf16_t* dc0h  = (bf16_t*)(WB + 0);
    bf16_t* dc0l  = (bf16_t*)(WB + 442368);
    bf16_t* d0c1h = (bf16_t*)(WB + 884736);
    bf16_t* d0c1l = (bf16_t*)(WB + 1769472);
    bf16_t* d0c2h = (bf16_t*)(WB + 2654208);
    bf16_t* d0c2l = (bf16_t*)(WB + 3538944);
    bf16_t* du0h  = (bf16_t*)(WB + 4423680);
    bf16_t* du0l  = (bf16_t*)(WB + 5472256);
    bf16_t* d1c1h = (bf16_t*)(WB + 6520832);
    bf16_t* d1c1l = (bf16_t*)(WB + 6742016);
    bf16_t* d1c2h = (bf16_t*)(WB + 6963200);
    bf16_t* d1c2l = (bf16_t*)(WB + 7184384);

    const float* fn = nullptr;
    const bf16_t* bn_ = nullptr;

    // ---- encoder weight prep (split-3, fragment-major) ----
    wprep3<<<432, 256, 0, stream>>>(er0_c1w, e0c1h, e0c1m, e0c1l, 64, 64, 110592);
    wprep3<<<432, 256, 0, stream>>>(er0_c2w, e0c2h, e0c2m, e0c2l, 64, 64, 110592);
    wprep3<<<2048, 256, 0, stream>>>(ec1_w, ec1h, ec1m, ec1l, 64, 128, 524288);
    wprep3<<<1728, 256, 0, stream>>>(er1_c1w, e1c1h, e1c1m, e1c1l, 128, 128, 442368);
    wprep3<<<1728, 256, 0, stream>>>(er1_c2w, e1c2h, e1c2m, e1c2l, 128, 128, 442368);
    wprep3<<<864, 256, 0, stream>>>(eo_w, eoh, eom, eol, 128, 64, 221184);

    // ---- encoder (fp32-class) ----
    conv_ec0f<<<131072, dim3(64, 4), 0, stream>>>(x, ec0_w, ec0_b, Af);

    conv3e<64, 64, 64, 1, 1><<<8192, 128, 0, stream>>>(
        Af, e0c1h, e0c1m, e0c1l, er0_c1b, fn, fn, fn, fn, fn, fn, Hf);
    conv3e<64, 64, 64, 1, 3><<<8192, 128, 0, stream>>>(
        Hf, e0c2h, e0c2m, e0c2l, er0_c2b, er0_g, er0_be, er0_m, er0_v, er0_a, Af, Af);

    convs2e<<<2048, 128, 0, stream>>>(Af, ec1h, ec1m, ec1l, ec1_b, E1f);

    conv3e<128, 128, 32, 2, 1><<<2048, 128, 0, stream>>>(
        E1f, e1c1h, e1c1m, e1c1l, er1_c1b, fn, fn, fn, fn, fn, fn, R1f);
    conv3e<128, 128, 32, 2, 3><<<2048, 128, 0, stream>>>(
        R1f, e1c2h, e1c2m, e1c2l, er1_c2b, er1_g, er1_be, er1_m, er1_v, er1_a, E1f, E1f);

    conv3e<128, 64, 32, 1, 2><<<2048, 64, 0, stream>>>(
        E1f, eoh, eom, eol, eo_b, fn, fn, fn, fn, eo_a, fn, Zf);

    // ---- VQ (exact fp32) ----
    vq_cnorm<<<8, 64, 0, stream>>>(cb, CN);
    zero512<<<1, 512, 0, stream>>>(HS);
    vq_assign<<<256, 256, 0, stream>>>(Zf, cb, CN, IDX, HS, 65536);
    perplexity_k<<<1, 512, 0, stream>>>(HS, out + 4194304, 1.0f / 65536.0f);
    vq_gather_split<<<4096, 256, 0, stream>>>(cb, IDX, ZQh, ZQl);

    // ---- decoder weight prep (split-2, fragment-major, overwrites arena) ----
    wprep_split<<<864, 256, 0, stream>>>(dc0_w, dc0h, dc0l, 64, 128, 221184);
    wprep_split<<<1728, 256, 0, stream>>>(dr0_c1w, d0c1h, d0c1l, 128, 128, 442368);
    wprep_split<<<1728, 256, 0, stream>>>(dr0_c2w, d0c2h, d0c2l, 128, 128, 442368);
    wprep_split<<<2048, 256, 0, stream>>>(du0_w, du0h, du0l, 128, 64, 524288);
    wprep_split<<<432, 256, 0, stream>>>(dr1_c1w, d1c1h, d1c1l, 64, 64, 110592);
    wprep_split<<<432, 256, 0, stream>>>(dr1_c2w, d1c2h, d1c2l, 64, 64, 110592);

    // ---- decoder (split-2 bf16) ----
    conv3d<64, 128, 32, 2, 2><<<2048, 128, 0, stream>>>(
        ZQh, ZQl, dc0h, dc0l, dc0_b, fn, fn, fn, fn, dc0_a, bn_, bn_, D0h, D0l);
    conv3d<128, 128, 32, 2, 1><<<2048, 128, 0, stream>>>(
        D0h, D0l, d0c1h, d0c1l, dr0_c1b, fn, fn, fn, fn, fn, bn_, bn_, Gh, Gl);
    conv3d<128, 128, 32, 2, 3><<<2048, 128, 0, stream>>>(
        Gh, Gl, d0c2h, d0c2l, dr0_c2b, dr0_g, dr0_be, dr0_m, dr0_v, dr0_a,
        D0h, D0l, D0h, D0l);

    convTm<<<8192, 256, 0, stream>>>(D0h, D0l, du0h, du0l, du0_b, U0h, U0l);

    conv3d<64, 64, 64, 1, 1><<<8192, 128, 0, stream>>>(
        U0h, U0l, d1c1h, d1c1l, dr1_c1b, fn, fn, fn, fn, fn, bn_, bn_, G1h, G1l);
    conv3d<64, 64, 64, 1, 3><<<8192, 128, 0, stream>>>(
        G1h, G1l, d1c2h, d1c2l, dr1_c2b, dr1_g, dr1_be, dr1_m, dr1_v, dr1_a,
        U0h, U0l, U0h, U0l);

    convT_du1w<<<65536, 256, 0, stream>>>(U0h, U0l, du1_w, du1_b, out);
}

// Round 11
// 5506.393 us; speedup vs baseline: 11.3244x; 1.1266x over previous
//
#include <hip/hip_runtime.h>
#include <cstdint>

// ---------------------------------------------------------------------------
// VQVAE forward — MFMA implicit-GEMM convolutions, channels-last.
//
// Encoder: fp32 activations in memory; EXACT 3-way bf16 split (v = h+m+l)
//   at LDS-stage time; 6-MFMA products => fp32-class => VQ argmin safe.
// Decoder: split-2 bf16 (hi/lo) storage, 3-pass MFMA.
//
// Round-11: conv_ec0m — ec0 (stride-2 k=4 CIN=1) as MFMA im2col GEMM.
//   K = 64 taps = 4 k-chunks; 16 padded input rows staged split-3 in LDS
//   (12.7KB); A-frags via 4 conflict-free uint LDS reads; weights reuse
//   wprep3 (ci=64 => [ks][half][cout][8] frag-major). Replaces the 828us
//   latency-bound scalar kernel (ideal ~30-50us).
// Retained: fragment-major weights, T14 async-STAGE, T1 XCD swizzle,
//   LDS XOR swizzle, wave-level du1.
//
// C layout: col = lane&31, row = (reg&3) + 8*(reg>>2) + 4*(lane>>5)
// ---------------------------------------------------------------------------

typedef unsigned short bf16_t;
typedef __attribute__((ext_vector_type(8)))  short s8b;     // 8 x bf16 frag
typedef __attribute__((ext_vector_type(16))) float f32x16;  // 32x32 acc

__device__ __forceinline__ float b2f(bf16_t u) { return __uint_as_float((unsigned)u << 16); }
__device__ __forceinline__ bf16_t f2b(float f) {
    unsigned x = __float_as_uint(f);
    return (bf16_t)((x + 0x7FFFu + ((x >> 16) & 1u)) >> 16);
}

__device__ __forceinline__ void split3s(float v, unsigned short& h,
                                        unsigned short& m, unsigned short& l)
{
    const unsigned uv = __float_as_uint(v);
    const float fh = __uint_as_float(uv & 0xFFFF0000u);
    const float r1 = v - fh;
    const unsigned u1 = __float_as_uint(r1);
    const float fm = __uint_as_float(u1 & 0xFFFF0000u);
    const float r2 = r1 - fm;
    h = (unsigned short)(uv >> 16);
    m = (unsigned short)(u1 >> 16);
    l = (unsigned short)(__float_as_uint(r2) >> 16);
}

// ------------------------- weight prep ------------------------------------
// src [tap][ci][co] fp32 -> dst fragment-major [tap][ks][half][co][8k]
__device__ __forceinline__ int wdst(int tap, int ci_, int co_, int ci, int co)
{
    const int ks = ci_ >> 4, half = (ci_ >> 3) & 1, j = ci_ & 7;
    return (((tap * (ci >> 4) + ks) * 2 + half) * co + co_) * 8 + j;
}

__global__ __launch_bounds__(256)
void wprep3(const float* __restrict__ w, bf16_t* __restrict__ h,
            bf16_t* __restrict__ m, bf16_t* __restrict__ l,
            int ci, int co, int n)
{
    const int i = blockIdx.x * 256 + threadIdx.x;
    if (i >= n) return;
    const int co_ = i % co;
    const int ci_ = (i / co) % ci;
    const int tap = i / (co * ci);
    const int dst = wdst(tap, ci_, co_, ci, co);
    unsigned short hh, mm, ll2;
    split3s(w[i], hh, mm, ll2);
    h[dst] = hh; m[dst] = mm; l[dst] = ll2;
}

__global__ __launch_bounds__(256)
void wprep_split(const float* __restrict__ w, bf16_t* __restrict__ hi,
                 bf16_t* __restrict__ lo, int ci, int co, int n)
{
    const int i = blockIdx.x * 256 + threadIdx.x;
    if (i >= n) return;
    const int co_ = i % co;
    const int ci_ = (i / co) % ci;
    const int tap = i / (co * ci);
    const float v = w[i];
    const int dst = wdst(tap, ci_, co_, ci, co);
    const bf16_t h = f2b(v);
    hi[dst] = h;
    lo[dst] = f2b(v - b2f(h));
}

// ---------------- encoder 3x3x3 conv: fp32 in, T14-staged split-3 -----------
// EPI: 0=ReLU 1=swish 2=PReLU 3=BN+PReLU+skip+ReLU
template<int CIN, int COUT, int SD, int NW, int EPI>
__global__ __launch_bounds__((SD / 32) * NW * 64)
void conv3e(const float* __restrict__ xf,
            const bf16_t* __restrict__ wh, const bf16_t* __restrict__ wm,
            const bf16_t* __restrict__ wl,
            const float* __restrict__ bias,
            const float* __restrict__ g, const float* __restrict__ be,
            const float* __restrict__ mn, const float* __restrict__ vr,
            const float* __restrict__ al,
            const float* skf, float* __restrict__ of)
{
    constexpr int NT = (SD / 32) * NW * 64;
    constexpr int LP = (SD * CIN) / (4 * NT);
    constexpr int KS = CIN / 16;
    __shared__ bf16_t lh[SD * CIN], lm[SD * CIN], ll[SD * CIN];

    const int tid  = threadIdx.x;
    const int lane = tid & 63;
    const int wid  = tid >> 6;
    const int wn   = wid % NW, wm2 = wid / NW;
    const int half = lane >> 5, ln = lane & 31;
    const int w    = wm2 * 32 + ln;
    const int nwg  = gridDim.x;
    const int bid  = (blockIdx.x & 7) * (nwg >> 3) + (blockIdx.x >> 3);
    const int h    = bid % SD;
    const int d    = (bid / SD) % SD;
    const int b    = bid / (SD * SD);
    const int cout0 = wn * 64 + ln;

    int pz[9], py[9], pt[9], np = 0;
    for (int kd = 0; kd < 3; ++kd) {
        const int iz = d + kd - 1;
        if ((unsigned)iz >= (unsigned)SD) continue;
        for (int kh = 0; kh < 3; ++kh) {
            const int iy = h + kh - 1;
            if ((unsigned)iy >= (unsigned)SD) continue;
            pz[np] = iz; py[np] = iy; pt[np] = (kd * 3 + kh) * 3; ++np;
        }
    }

    f32x16 accA[2], accB[2];
#pragma unroll
    for (int i = 0; i < 16; ++i) {
        accA[0][i] = 0.f; accA[1][i] = 0.f;
        accB[0][i] = 0.f; accB[1][i] = 0.f;
    }

    float4 rg[LP];
    auto loadrow = [&](int iz, int iy) {
        const float* src = xf + ((size_t)((b * SD + iz) * SD + iy)) * SD * CIN;
#pragma unroll
        for (int j = 0; j < LP; ++j)
            rg[j] = *reinterpret_cast<const float4*>(src + (size_t)(tid + j * NT) * 4);
    };
    auto writerow = [&]() {
#pragma unroll
        for (int j = 0; j < LP; ++j) {
            const int idx = (tid + j * NT) * 4;
            const int vox = idx / CIN, ch = idx % CIN;
            ushort4 h4, m4, l4;
            split3s(rg[j].x, h4.x, m4.x, l4.x);
            split3s(rg[j].y, h4.y, m4.y, l4.y);
            split3s(rg[j].z, h4.z, m4.z, l4.z);
            split3s(rg[j].w, h4.w, m4.w, l4.w);
            const int bo = ((vox * CIN + ch) * 2) ^ ((vox & 7) << 4);
            *reinterpret_cast<ushort4*>((char*)&lh[0] + bo) = h4;
            *reinterpret_cast<ushort4*>((char*)&lm[0] + bo) = m4;
            *reinterpret_cast<ushort4*>((char*)&ll[0] + bo) = l4;
        }
    };

    loadrow(pz[0], py[0]);
    writerow();
    __syncthreads();
#pragma unroll 1
    for (int i = 0; i < np; ++i) {
        if (i + 1 < np) loadrow(pz[i + 1], py[i + 1]);   // issue early (T14)
#pragma unroll
        for (int kw = 0; kw < 3; ++kw) {
            const int tap = pt[i] + kw;
            const int iw = w + kw - 1;
            const bool edge = (unsigned)iw >= (unsigned)SD;
            const int wcl = edge ? w : iw;
            const s8b zz = {};
#pragma unroll
            for (int ks = 0; ks < KS; ++ks) {
                const int bo = ((wcl * CIN + half * 8 + ks * 16) * 2) ^ ((wcl & 7) << 4);
                s8b ah  = *reinterpret_cast<const s8b*>((const char*)&lh[0] + bo);
                s8b am  = *reinterpret_cast<const s8b*>((const char*)&lm[0] + bo);
                s8b al3 = *reinterpret_cast<const s8b*>((const char*)&ll[0] + bo);
                if (edge) { ah = zz; am = zz; al3 = zz; }
                const size_t wb0 = ((size_t)((tap * KS + ks) * 2 + half) * COUT + cout0) * 8;
#pragma unroll
                for (int n2 = 0; n2 < 2; ++n2) {
                    const size_t wb = wb0 + n2 * 256;   // cout += 32
                    const s8b bh = *reinterpret_cast<const s8b*>(wh + wb);
                    const s8b bm = *reinterpret_cast<const s8b*>(wm + wb);
                    const s8b bl = *reinterpret_cast<const s8b*>(wl + wb);
                    accA[n2] = __builtin_amdgcn_mfma_f32_32x32x16_bf16(ah, bh, accA[n2], 0, 0, 0);
                    accB[n2] = __builtin_amdgcn_mfma_f32_32x32x16_bf16(ah, bm, accB[n2], 0, 0, 0);
                    accA[n2] = __builtin_amdgcn_mfma_f32_32x32x16_bf16(am, bh, accA[n2], 0, 0, 0);
                    accB[n2] = __builtin_amdgcn_mfma_f32_32x32x16_bf16(am, bm, accB[n2], 0, 0, 0);
                    accA[n2] = __builtin_amdgcn_mfma_f32_32x32x16_bf16(al3, bh, accA[n2], 0, 0, 0);
                    accB[n2] = __builtin_amdgcn_mfma_f32_32x32x16_bf16(ah, bl, accB[n2], 0, 0, 0);
                }
            }
        }
        if (i + 1 < np) {
            __syncthreads();          // all waves done reading LDS
            writerow();               // implicit vmcnt wait on rg here
            __syncthreads();          // LDS ready
        }
    }

    const size_t outrow = ((size_t)((b * SD + d) * SD + h)) * SD;
#pragma unroll
    for (int n2 = 0; n2 < 2; ++n2) {
        const int cout = wn * 64 + n2 * 32 + ln;
        const float bv = bias[cout];
        float sc = 0.f, mm = 0.f, bb2 = 0.f, aa = 0.f;
        if constexpr (EPI == 3) {
            sc = g[cout] * (1.0f / sqrtf(vr[cout] + 1e-3f));
            mm = mn[cout]; bb2 = be[cout]; aa = al[cout];
        }
        if constexpr (EPI == 2) aa = al[cout];
#pragma unroll
        for (int r = 0; r < 16; ++r) {
            const int rl = (r & 3) + 8 * (r >> 2) + 4 * half;
            const size_t oe = (outrow + wm2 * 32 + rl) * COUT + cout;
            float y = accA[n2][r] + accB[n2][r] + bv;
            if constexpr (EPI == 0) y = fmaxf(y, 0.f);
            else if constexpr (EPI == 1) y = y / (1.f + expf(-y));
            else if constexpr (EPI == 2) y = y > 0.f ? y : aa * y;
            else {
                float t2 = (y - mm) * sc + bb2;
                t2 = t2 > 0.f ? t2 : aa * t2;
                y = fmaxf(skf[oe] + t2, 0.f);
            }
            of[oe] = y;
        }
    }
}

// ---------------- ec1: stride-2 k=4, fp32 in, T14-staged split-3 ------------
__global__ __launch_bounds__(128)
void convs2e(const float* __restrict__ xf,
             const bf16_t* __restrict__ wh, const bf16_t* __restrict__ wm,
             const bf16_t* __restrict__ wl,
             const float* __restrict__ bias, float* __restrict__ of)
{
    constexpr int NT = 128, LP = (64 * 64) / (4 * NT);
    __shared__ bf16_t lh[64 * 64], lm[64 * 64], ll[64 * 64];

    const int tid  = threadIdx.x;
    const int lane = tid & 63;
    const int wn   = tid >> 6;
    const int half = lane >> 5, ln = lane & 31;
    const int nwg  = gridDim.x;
    const int bid  = (blockIdx.x & 7) * (nwg >> 3) + (blockIdx.x >> 3);
    const int h    = bid % 32;
    const int d    = (bid / 32) % 32;
    const int b    = bid / 1024;
    const int cout0 = wn * 64 + ln;

    int pz[16], py[16], pt[16], np = 0;
    for (int kd = 0; kd < 4; ++kd) {
        const int iz = 2 * d + kd - 1;
        if ((unsigned)iz >= 64u) continue;
        for (int kh = 0; kh < 4; ++kh) {
            const int iy = 2 * h + kh - 1;
            if ((unsigned)iy >= 64u) continue;
            pz[np] = iz; py[np] = iy; pt[np] = (kd * 4 + kh) * 4; ++np;
        }
    }

    f32x16 accA[2], accB[2];
#pragma unroll
    for (int i = 0; i < 16; ++i) {
        accA[0][i] = 0.f; accA[1][i] = 0.f;
        accB[0][i] = 0.f; accB[1][i] = 0.f;
    }

    float4 rg[LP];
    auto loadrow = [&](int iz, int iy) {
        const float* src = xf + ((size_t)((b * 64 + iz) * 64 + iy)) * 64 * 64;
#pragma unroll
        for (int j = 0; j < LP; ++j)
            rg[j] = *reinterpret_cast<const float4*>(src + (size_t)(tid + j * NT) * 4);
    };
    auto writerow = [&]() {
#pragma unroll
        for (int j = 0; j < LP; ++j) {
            const int idx = (tid + j * NT) * 4;
            const int vox = idx / 64, ch = idx % 64;
            ushort4 h4, m4, l4;
            split3s(rg[j].x, h4.x, m4.x, l4.x);
            split3s(rg[j].y, h4.y, m4.y, l4.y);
            split3s(rg[j].z, h4.z, m4.z, l4.z);
            split3s(rg[j].w, h4.w, m4.w, l4.w);
            const int bo = ((vox * 64 + ch) * 2) ^ ((vox & 7) << 4);
            *reinterpret_cast<ushort4*>((char*)&lh[0] + bo) = h4;
            *reinterpret_cast<ushort4*>((char*)&lm[0] + bo) = m4;
            *reinterpret_cast<ushort4*>((char*)&ll[0] + bo) = l4;
        }
    };

    loadrow(pz[0], py[0]);
    writerow();
    __syncthreads();
#pragma unroll 1
    for (int i = 0; i < np; ++i) {
        if (i + 1 < np) loadrow(pz[i + 1], py[i + 1]);
#pragma unroll
        for (int kw = 0; kw < 4; ++kw) {
            const int tap = pt[i] + kw;
            const int iw = 2 * ln + kw - 1;
            const bool edge = (unsigned)iw >= 64u;
            const int wcl = edge ? 2 * ln : iw;
            const s8b zz = {};
#pragma unroll
            for (int ks = 0; ks < 4; ++ks) {
                const int bo = ((wcl * 64 + half * 8 + ks * 16) * 2) ^ ((wcl & 7) << 4);
                s8b ah  = *reinterpret_cast<const s8b*>((const char*)&lh[0] + bo);
                s8b am  = *reinterpret_cast<const s8b*>((const char*)&lm[0] + bo);
                s8b al3 = *reinterpret_cast<const s8b*>((const char*)&ll[0] + bo);
                if (edge) { ah = zz; am = zz; al3 = zz; }
                const size_t wb0 = ((size_t)((tap * 4 + ks) * 2 + half) * 128 + cout0) * 8;
#pragma unroll
                for (int n2 = 0; n2 < 2; ++n2) {
                    const size_t wb = wb0 + n2 * 256;
                    const s8b bh = *reinterpret_cast<const s8b*>(wh + wb);
                    const s8b bm = *reinterpret_cast<const s8b*>(wm + wb);
                    const s8b bl = *reinterpret_cast<const s8b*>(wl + wb);
                    accA[n2] = __builtin_amdgcn_mfma_f32_32x32x16_bf16(ah, bh, accA[n2], 0, 0, 0);
                    accB[n2] = __builtin_amdgcn_mfma_f32_32x32x16_bf16(ah, bm, accB[n2], 0, 0, 0);
                    accA[n2] = __builtin_amdgcn_mfma_f32_32x32x16_bf16(am, bh, accA[n2], 0, 0, 0);
                    accB[n2] = __builtin_amdgcn_mfma_f32_32x32x16_bf16(am, bm, accB[n2], 0, 0, 0);
                    accA[n2] = __builtin_amdgcn_mfma_f32_32x32x16_bf16(al3, bh, accA[n2], 0, 0, 0);
                    accB[n2] = __builtin_amdgcn_mfma_f32_32x32x16_bf16(ah, bl, accB[n2], 0, 0, 0);
                }
            }
        }
        if (i + 1 < np) {
            __syncthreads();
            writerow();
            __syncthreads();
        }
    }

    const size_t outrow = ((size_t)((b * 32 + d) * 32 + h)) * 32;
#pragma unroll
    for (int n2 = 0; n2 < 2; ++n2) {
        const int cout = wn * 64 + n2 * 32 + ln;
        const float bv = bias[cout];
#pragma unroll
        for (int r = 0; r < 16; ++r) {
            const int rl = (r & 3) + 8 * (r >> 2) + 4 * half;
            const size_t oe = (outrow + rl) * 128 + cout;
            of[oe] = fmaxf(accA[n2][r] + accB[n2][r] + bv, 0.f);
        }
    }
}

// ---------------- decoder 3x3x3 conv: split-2 bf16, T14-staged --------------
template<int CIN, int COUT, int SD, int NW, int EPI>
__global__ __launch_bounds__((SD / 32) * NW * 64)
void conv3d(const bf16_t* __restrict__ xh, const bf16_t* __restrict__ xl,
            const bf16_t* __restrict__ wh, const bf16_t* __restrict__ wl,
            const float* __restrict__ bias,
            const float* __restrict__ g, const float* __restrict__ be,
            const float* __restrict__ mn, const float* __restrict__ vr,
            const float* __restrict__ al,
            const bf16_t* skh, const bf16_t* skl,
            bf16_t* oh, bf16_t* ol)
{
    constexpr int NT = (SD / 32) * NW * 64;
    constexpr int LP = (SD * CIN) / (4 * NT);
    constexpr int KS = CIN / 16;
    __shared__ bf16_t lh[SD * CIN], ll[SD * CIN];

    const int tid  = threadIdx.x;
    const int lane = tid & 63;
    const int wid  = tid >> 6;
    const int wn   = wid % NW, wm2 = wid / NW;
    const int half = lane >> 5, ln = lane & 31;
    const int w    = wm2 * 32 + ln;
    const int nwg  = gridDim.x;
    const int bid  = (blockIdx.x & 7) * (nwg >> 3) + (blockIdx.x >> 3);
    const int h    = bid % SD;
    const int d    = (bid / SD) % SD;
    const int b    = bid / (SD * SD);
    const int cout0 = wn * 64 + ln;

    int pz[9], py[9], pt[9], np = 0;
    for (int kd = 0; kd < 3; ++kd) {
        const int iz = d + kd - 1;
        if ((unsigned)iz >= (unsigned)SD) continue;
        for (int kh = 0; kh < 3; ++kh) {
            const int iy = h + kh - 1;
            if ((unsigned)iy >= (unsigned)SD) continue;
            pz[np] = iz; py[np] = iy; pt[np] = (kd * 3 + kh) * 3; ++np;
        }
    }

    f32x16 accA[2], accB[2];
#pragma unroll
    for (int i = 0; i < 16; ++i) {
        accA[0][i] = 0.f; accA[1][i] = 0.f;
        accB[0][i] = 0.f; accB[1][i] = 0.f;
    }

    ushort4 rh[LP], rl2[LP];
    auto loadrow = [&](int iz, int iy) {
        const size_t rb = ((size_t)((b * SD + iz) * SD + iy)) * SD * CIN;
#pragma unroll
        for (int j = 0; j < LP; ++j) {
            const int idx = (tid + j * NT) * 4;
            rh[j]  = *reinterpret_cast<const ushort4*>(xh + rb + idx);
            rl2[j] = *reinterpret_cast<const ushort4*>(xl + rb + idx);
        }
    };
    auto writerow = [&]() {
#pragma unroll
        for (int j = 0; j < LP; ++j) {
            const int idx = (tid + j * NT) * 4;
            const int vox = idx / CIN, ch = idx % CIN;
            const int bo = ((vox * CIN + ch) * 2) ^ ((vox & 7) << 4);
            *reinterpret_cast<ushort4*>((char*)&lh[0] + bo) = rh[j];
            *reinterpret_cast<ushort4*>((char*)&ll[0] + bo) = rl2[j];
        }
    };

    loadrow(pz[0], py[0]);
    writerow();
    __syncthreads();
#pragma unroll 1
    for (int i = 0; i < np; ++i) {
        if (i + 1 < np) loadrow(pz[i + 1], py[i + 1]);
#pragma unroll
        for (int kw = 0; kw < 3; ++kw) {
            const int tap = pt[i] + kw;
            const int iw = w + kw - 1;
            const bool edge = (unsigned)iw >= (unsigned)SD;
            const int wcl = edge ? w : iw;
            const s8b zz = {};
#pragma unroll
            for (int ks = 0; ks < KS; ++ks) {
                const int bo = ((wcl * CIN + half * 8 + ks * 16) * 2) ^ ((wcl & 7) << 4);
                s8b ah  = *reinterpret_cast<const s8b*>((const char*)&lh[0] + bo);
                s8b al2 = *reinterpret_cast<const s8b*>((const char*)&ll[0] + bo);
                if (edge) { ah = zz; al2 = zz; }
                const size_t wb0 = ((size_t)((tap * KS + ks) * 2 + half) * COUT + cout0) * 8;
#pragma unroll
                for (int n2 = 0; n2 < 2; ++n2) {
                    const size_t wb = wb0 + n2 * 256;
                    const s8b bh = *reinterpret_cast<const s8b*>(wh + wb);
                    const s8b bl = *reinterpret_cast<const s8b*>(wl + wb);
                    accA[n2] = __builtin_amdgcn_mfma_f32_32x32x16_bf16(ah, bh, accA[n2], 0, 0, 0);
                    accB[n2] = __builtin_amdgcn_mfma_f32_32x32x16_bf16(al2, bh, accB[n2], 0, 0, 0);
                    accB[n2] = __builtin_amdgcn_mfma_f32_32x32x16_bf16(ah, bl, accB[n2], 0, 0, 0);
                }
            }
        }
        if (i + 1 < np) {
            __syncthreads();
            writerow();
            __syncthreads();
        }
    }

    const size_t outrow = ((size_t)((b * SD + d) * SD + h)) * SD;
#pragma unroll
    for (int n2 = 0; n2 < 2; ++n2) {
        const int cout = wn * 64 + n2 * 32 + ln;
        const float bv = bias[cout];
        float sc = 0.f, mm = 0.f, bb2 = 0.f, aa = 0.f;
        if constexpr (EPI == 3) {
            sc = g[cout] * (1.0f / sqrtf(vr[cout] + 1e-3f));
            mm = mn[cout]; bb2 = be[cout]; aa = al[cout];
        }
        if constexpr (EPI == 2) aa = al[cout];
#pragma unroll
        for (int r = 0; r < 16; ++r) {
            const int rl = (r & 3) + 8 * (r >> 2) + 4 * half;
            const size_t oe = (outrow + wm2 * 32 + rl) * COUT + cout;
            float y = accA[n2][r] + accB[n2][r] + bv;
            if constexpr (EPI == 0) y = fmaxf(y, 0.f);
            else if constexpr (EPI == 1) y = y / (1.f + expf(-y));
            else if constexpr (EPI == 2) y = y > 0.f ? y : aa * y;
            else {
                float t2 = (y - mm) * sc + bb2;
                t2 = t2 > 0.f ? t2 : aa * t2;
                float sv = b2f(skh[oe]) + b2f(skl[oe]);
                y = fmaxf(sv + t2, 0.f);
            }
            const bf16_t hh = f2b(y);
            oh[oe] = hh;
            ol[oe] = f2b(y - b2f(hh));
        }
    }
}

// ---------------- convT stride-2 k=4 (du0, split-2, T14-staged) -------------
__global__ __launch_bounds__(256)
void convTm(const bf16_t* __restrict__ xh, const bf16_t* __restrict__ xl,
            const bf16_t* __restrict__ wh, const bf16_t* __restrict__ wl,
            const float* __restrict__ bias,
            bf16_t* __restrict__ oh, bf16_t* __restrict__ ol)
{
    constexpr int NT = 256, LP = (32 * 128) / (4 * NT);
    __shared__ bf16_t lh[32 * 128], ll[32 * 128];

    const int tid  = threadIdx.x;
    const int lane = tid & 63;
    const int wid  = tid >> 6;
    const int wn   = wid & 1, p = wid >> 1;
    const int half = lane >> 5, ln = lane & 31;
    const int nwg  = gridDim.x;
    const int bid  = (blockIdx.x & 7) * (nwg >> 3) + (blockIdx.x >> 3);
    const int ohh  = bid % 64;
    const int od   = (bid / 64) % 64;
    const int b    = bid / 4096;
    const int pd = od & 1, dz = od >> 1;
    const int ph = ohh & 1, hy = ohh >> 1;
    const int cout = wn * 32 + ln;

    int pz[4], py[4], pt[4], np = 0;
    for (int jd = 0; jd < 2; ++jd) {
        const int kd = pd + 2 * jd;
        const int iz = dz + pd - 1 + jd;
        if ((unsigned)iz >= 32u) continue;
        for (int jh = 0; jh < 2; ++jh) {
            const int kh = ph + 2 * jh;
            const int iy = hy + ph - 1 + jh;
            if ((unsigned)iy >= 32u) continue;
            pz[np] = iz; py[np] = iy; pt[np] = (kd * 4 + kh) * 4; ++np;
        }
    }

    f32x16 accA, accB;
#pragma unroll
    for (int i = 0; i < 16; ++i) { accA[i] = 0.0f; accB[i] = 0.0f; }

    ushort4 rh[LP], rl2[LP];
    auto loadrow = [&](int iz, int iy) {
        const size_t rb = ((size_t)((b * 32 + iz) * 32 + iy)) * 32 * 128;
#pragma unroll
        for (int j = 0; j < LP; ++j) {
            const int idx = (tid + j * NT) * 4;
            rh[j]  = *reinterpret_cast<const ushort4*>(xh + rb + idx);
            rl2[j] = *reinterpret_cast<const ushort4*>(xl + rb + idx);
        }
    };
    auto writerow = [&]() {
#pragma unroll
        for (int j = 0; j < LP; ++j) {
            const int idx = (tid + j * NT) * 4;
            const int vox = idx / 128, ch = idx % 128;
            const int bo = ((vox * 128 + ch) * 2) ^ ((vox & 7) << 4);
            *reinterpret_cast<ushort4*>((char*)&lh[0] + bo) = rh[j];
            *reinterpret_cast<ushort4*>((char*)&ll[0] + bo) = rl2[j];
        }
    };

    loadrow(pz[0], py[0]);
    writerow();
    __syncthreads();
#pragma unroll 1
    for (int i = 0; i < np; ++i) {
        if (i + 1 < np) loadrow(pz[i + 1], py[i + 1]);
#pragma unroll
        for (int jw = 0; jw < 2; ++jw) {
            const int kw = p + 2 * jw;
            const int tap = pt[i] + kw;
            const int ix = ln + p - 1 + jw;
            const bool edge = (unsigned)ix >= 32u;
            const int xcl = edge ? ln : ix;
            const s8b zz = {};
#pragma unroll
            for (int ks = 0; ks < 8; ++ks) {
                const int bo = ((xcl * 128 + half * 8 + ks * 16) * 2) ^ ((xcl & 7) << 4);
                s8b a  = *reinterpret_cast<const s8b*>((const char*)&lh[0] + bo);
                s8b a2 = *reinterpret_cast<const s8b*>((const char*)&ll[0] + bo);
                if (edge) { a = zz; a2 = zz; }
                const size_t wb = ((size_t)((tap * 8 + ks) * 2 + half) * 64 + cout) * 8;
                const s8b bb = *reinterpret_cast<const s8b*>(wh + wb);
                const s8b b2 = *reinterpret_cast<const s8b*>(wl + wb);
                accA = __builtin_amdgcn_mfma_f32_32x32x16_bf16(a, bb, accA, 0, 0, 0);
                accB = __builtin_amdgcn_mfma_f32_32x32x16_bf16(a2, bb, accB, 0, 0, 0);
                accB = __builtin_amdgcn_mfma_f32_32x32x16_bf16(a, b2, accB, 0, 0, 0);
            }
        }
        if (i + 1 < np) {
            __syncthreads();
            writerow();
            __syncthreads();
        }
    }

    const float bv = bias[cout];
#pragma unroll
    for (int r = 0; r < 16; ++r) {
        const int rl = (r & 3) + 8 * (r >> 2) + 4 * half;
        const int ow = 2 * rl + p;
        const size_t oe = (((size_t)((b * 64 + od) * 64 + ohh)) * 64 + ow) * 64 + cout;
        const float y = fmaxf(accA[r] + accB[r] + bv, 0.f);
        const bf16_t hh = f2b(y);
        oh[oe] = hh;
        ol[oe] = f2b(y - b2f(hh));
    }
}

// ---------------- ec0 via MFMA: s2 k=4, CIN=1, K=64 taps --------------------
// Block = one output row (b,d,h): 64 voxels x 64 couts, 2 waves.
// LDS: 16 input rows (4kd x 4kh), ix=-1..128 zero-padded, split-3 bf16.
// A-frag: lane vox=w, k=tap=ks*16+half*8+j -> two 4-elem rows (kh,kh+1),
// assembled from 4 uint LDS reads (lane stride 4B: conflict-free).
__global__ __launch_bounds__(128)
void conv_ec0m(const float* __restrict__ x,
               const bf16_t* __restrict__ wh, const bf16_t* __restrict__ wm,
               const bf16_t* __restrict__ wl,
               const float* __restrict__ bias, float* __restrict__ of)
{
    __shared__ bf16_t lh[16 * 132], lm[16 * 132], ll[16 * 132];

    const int tid  = threadIdx.x;
    const int lane = tid & 63;
    const int wm2  = tid >> 6;                 // voxel half (w 0-31 / 32-63)
    const int half = lane >> 5, ln = lane & 31;
    const int w    = wm2 * 32 + ln;
    const int nwg  = gridDim.x;
    const int bid  = (blockIdx.x & 7) * (nwg >> 3) + (blockIdx.x >> 3);
    const int h    = bid % 64;
    const int d    = (bid / 64) % 64;
    const int b    = bid / 4096;

    // stage 16 padded rows, split-3
    for (int i = tid; i < 16 * 132; i += 128) {
        const int row = i / 132, col = i % 132;     // col = ix+1, valid 0..129
        const int kd = row >> 2, kh = row & 3;
        const int iz = 2 * d + kd - 1, iy = 2 * h + kh - 1;
        const int ix = col - 1;
        float v = 0.f;
        if ((unsigned)iz < 128u && (unsigned)iy < 128u &&
            (unsigned)ix < 128u && col < 130)
            v = x[(size_t)((b * 128 + iz) * 128 + iy) * 128 + ix];
        unsigned short hh, mm2, ll2;
        split3s(v, hh, mm2, ll2);
        lh[i] = hh; lm[i] = mm2; ll[i] = ll2;
    }
    __syncthreads();

    f32x16 accA[2], accB[2];
#pragma unroll
    for (int i = 0; i < 16; ++i) {
        accA[0][i] = 0.f; accA[1][i] = 0.f;
        accB[0][i] = 0.f; accB[1][i] = 0.f;
    }

#pragma unroll
    for (int ks = 0; ks < 4; ++ks) {          // kd = ks
        const int row0 = ks * 4 + 2 * half;   // kh = 2*half (+1)
        const int i0 = row0 * 132 + 2 * w;    // ixo = 2w + kw
        const int i1 = i0 + 132;
        s8b ah, am, al3;
        {
            uint* ap = (uint*)&ah;
            ap[0] = *(const uint*)&lh[i0]; ap[1] = *(const uint*)&lh[i0 + 2];
            ap[2] = *(const uint*)&lh[i1]; ap[3] = *(const uint*)&lh[i1 + 2];
        }
        {
            uint* ap = (uint*)&am;
            ap[0] = *(const uint*)&lm[i0]; ap[1] = *(const uint*)&lm[i0 + 2];
            ap[2] = *(const uint*)&lm[i1]; ap[3] = *(const uint*)&lm[i1 + 2];
        }
        {
            uint* ap = (uint*)&al3;
            ap[0] = *(const uint*)&ll[i0]; ap[1] = *(const uint*)&ll[i0 + 2];
            ap[2] = *(const uint*)&ll[i1]; ap[3] = *(const uint*)&ll[i1 + 2];
        }
        const size_t wb0 = ((size_t)(ks * 2 + half) * 64 + ln) * 8;
#pragma unroll
        for (int n2 = 0; n2 < 2; ++n2) {
            const size_t wb = wb0 + n2 * 256;
            const s8b bh = *reinterpret_cast<const s8b*>(wh + wb);
            const s8b bm = *reinterpret_cast<const s8b*>(wm + wb);
            const s8b bl = *reinterpret_cast<const s8b*>(wl + wb);
            accA[n2] = __builtin_amdgcn_mfma_f32_32x32x16_bf16(ah, bh, accA[n2], 0, 0, 0);
            accB[n2] = __builtin_amdgcn_mfma_f32_32x32x16_bf16(ah, bm, accB[n2], 0, 0, 0);
            accA[n2] = __builtin_amdgcn_mfma_f32_32x32x16_bf16(am, bh, accA[n2], 0, 0, 0);
            accB[n2] = __builtin_amdgcn_mfma_f32_32x32x16_bf16(am, bm, accB[n2], 0, 0, 0);
            accA[n2] = __builtin_amdgcn_mfma_f32_32x32x16_bf16(al3, bh, accA[n2], 0, 0, 0);
            accB[n2] = __builtin_amdgcn_mfma_f32_32x32x16_bf16(ah, bl, accB[n2], 0, 0, 0);
        }
    }

    const size_t outrow = ((size_t)((b * 64 + d) * 64 + h)) * 64;
#pragma unroll
    for (int n2 = 0; n2 < 2; ++n2) {
        const int cout = n2 * 32 + ln;
        const float bv = bias[cout];
#pragma unroll
        for (int r = 0; r < 16; ++r) {
            const int rl = (r & 3) + 8 * (r >> 2) + 4 * half;
            const size_t oe = (outrow + wm2 * 32 + rl) * 64 + cout;
            of[oe] = fmaxf(accA[n2][r] + accB[n2][r] + bv, 0.f);
        }
    }
}

// ---------------- du1: convT s2 k=4, CIN=64, COUT=1 — wave-level ------------
__global__ __launch_bounds__(256)
void convT_du1w(const bf16_t* __restrict__ inh, const bf16_t* __restrict__ inl,
                const float* __restrict__ wt, const float* __restrict__ bias,
                float* __restrict__ out)
{
    const int lane = threadIdx.x & 63;
    const int wv   = blockIdx.x * 4 + (threadIdx.x >> 6);
    const size_t obase = (size_t)wv * 16;
    const int ow0 = (int)(obase % 128);
    size_t rem = obase / 128;
    const int ohh = (int)(rem % 128); rem /= 128;
    const int od  = (int)(rem % 128); rem /= 128;
    const int b   = (int)rem;
    const int pd = od & 1, dz = od >> 1;
    const int ph = ohh & 1, hy = ohh >> 1;
    const int wx0 = ow0 >> 1;

    float acc[16];
#pragma unroll
    for (int o = 0; o < 16; ++o) acc[o] = 0.f;

#pragma unroll
    for (int jd = 0; jd < 2; ++jd) {
        const int kd = pd + 2 * jd;
        const int iz = dz + pd - 1 + jd;
        if ((unsigned)iz >= 64u) continue;
#pragma unroll
        for (int jh = 0; jh < 2; ++jh) {
            const int kh = ph + 2 * jh;
            const int iy = hy + ph - 1 + jh;
            if ((unsigned)iy >= 64u) continue;
            const size_t rbase = ((size_t)((b * 64 + iz) * 64 + iy)) * 64;
            float wv4[4];
#pragma unroll
            for (int kw = 0; kw < 4; ++kw)
                wv4[kw] = wt[(size_t)((kd * 4 + kh) * 4 + kw) * 64 + lane];
            float v[10];
#pragma unroll
            for (int t = 0; t < 10; ++t) {
                const int ix = wx0 - 1 + t;
                if ((unsigned)ix < 64u) {
                    const size_t a = (rbase + ix) * 64 + lane;
                    v[t] = b2f(inh[a]) + b2f(inl[a]);
                } else {
                    v[t] = 0.f;
                }
            }
#pragma unroll
            for (int o = 0; o < 16; ++o) {
                const int pw = o & 1;
                const int t0 = (o >> 1) + pw;
                acc[o] = fmaf(v[t0],     wv4[pw],     acc[o]);
                acc[o] = fmaf(v[t0 + 1], wv4[pw + 2], acc[o]);
            }
        }
    }

    const float b0 = bias[0];
#pragma unroll
    for (int o = 0; o < 16; ++o) {
        float s = acc[o];
        s += __shfl_xor(s, 1);
        s += __shfl_xor(s, 2);
        s += __shfl_xor(s, 4);
        s += __shfl_xor(s, 8);
        s += __shfl_xor(s, 16);
        s += __shfl_xor(s, 32);
        if (lane == 0) out[obase + o] = s + b0;
    }
}

// --------------------------------- VQ ---------------------------------------
__global__ void zero512(float* __restrict__ p) { p[threadIdx.x] = 0.0f; }

__global__ void vq_cnorm(const float* __restrict__ cb, float* __restrict__ cnorm)
{
    const int k = blockIdx.x * 64 + threadIdx.x;
    float s = 0.0f;
    for (int ci = 0; ci < 64; ++ci) { const float c = cb[k * 64 + ci]; s = fmaf(c, c, s); }
    cnorm[k] = s;
}

__global__ __launch_bounds__(256)
void vq_assign(const float* __restrict__ z, const float* __restrict__ cb,
               const float* __restrict__ cnorm, int* __restrict__ idx,
               float* __restrict__ hist, int N)
{
    const int n = blockIdx.x * 256 + threadIdx.x;
    const float4* zp = reinterpret_cast<const float4*>(z + (size_t)n * 64);
    float4 zv[16];
    float z2 = 0.0f;
#pragma unroll
    for (int i = 0; i < 16; ++i) {
        zv[i] = zp[i];
        z2 += zv[i].x * zv[i].x + zv[i].y * zv[i].y + zv[i].z * zv[i].z + zv[i].w * zv[i].w;
    }
    float best = 3.4e38f;
    int bi = 0;
#pragma unroll 1
    for (int k = 0; k < 512; ++k) {
        const float4* cp = reinterpret_cast<const float4*>(cb + (size_t)k * 64);
        float dot = 0.0f;
#pragma unroll
        for (int i = 0; i < 16; ++i) {
            const float4 c = cp[i];
            dot += zv[i].x * c.x + zv[i].y * c.y + zv[i].z * c.z + zv[i].w * c.w;
        }
        const float dist = z2 + cnorm[k] - 2.0f * dot;
        if (dist < best) { best = dist; bi = k; }
    }
    idx[n] = bi;
    atomicAdd(&hist[bi], 1.0f);
}

__global__ __launch_bounds__(256)
void vq_gather_split(const float* __restrict__ cb, const int* __restrict__ idx,
                     bf16_t* __restrict__ zh, bf16_t* __restrict__ zl)
{
    const int gid = blockIdx.x * 256 + threadIdx.x;
    const int n = gid >> 4, c4 = gid & 15;
    const int k = idx[n];
    const float4 c = reinterpret_cast<const float4*>(cb)[k * 16 + c4];
    ushort4 h, l;
    h.x = f2b(c.x); l.x = f2b(c.x - b2f(h.x));
    h.y = f2b(c.y); l.y = f2b(c.y - b2f(h.y));
    h.z = f2b(c.z); l.z = f2b(c.z - b2f(h.z));
    h.w = f2b(c.w); l.w = f2b(c.w - b2f(h.w));
    reinterpret_cast<ushort4*>(zh)[gid] = h;
    reinterpret_cast<ushort4*>(zl)[gid] = l;
}

__global__ __launch_bounds__(512)
void perplexity_k(const float* __restrict__ hist, float* __restrict__ out, float invN)
{
    __shared__ float red[512];
    const int t = threadIdx.x;
    const float p = hist[t] * invN;
    red[t] = p * logf(p + 1e-12f);
    __syncthreads();
    for (int s = 256; s > 0; s >>= 1) {
        if (t < s) red[t] += red[t + s];
        __syncthreads();
    }
    if (t == 0) out[0] = expf(-red[0]);
}

// ---------------------------------------------------------------------------
extern "C" void kernel_launch(void* const* d_in, const int* in_sizes, int n_in,
                              void* d_out, int out_size, void* d_ws, size_t ws_size,
                              hipStream_t stream)
{
    const float* x       = (const float*)d_in[0];
    const float* ec0_w   = (const float*)d_in[1];
    const float* ec0_b   = (const float*)d_in[2];
    const float* er0_c1w = (const float*)d_in[3];
    const float* er0_c1b = (const float*)d_in[4];
    const float* er0_c2w = (const float*)d_in[5];
    const float* er0_c2b = (const float*)d_in[6];
    const float* er0_g   = (const float*)d_in[7];
    const float* er0_be  = (const float*)d_in[8];
    const float* er0_m   = (const float*)d_in[9];
    const float* er0_v   = (const float*)d_in[10];
    const float* er0_a   = (const float*)d_in[11];
    const float* ec1_w   = (const float*)d_in[12];
    const float* ec1_b   = (const float*)d_in[13];
    const float* er1_c1w = (const float*)d_in[14];
    const float* er1_c1b = (const float*)d_in[15];
    const float* er1_c2w = (const float*)d_in[16];
    const float* er1_c2b = (const float*)d_in[17];
    const float* er1_g   = (const float*)d_in[18];
    const float* er1_be  = (const float*)d_in[19];
    const float* er1_m   = (const float*)d_in[20];
    const float* er1_v   = (const float*)d_in[21];
    const float* er1_a   = (const float*)d_in[22];
    const float* eo_w    = (const float*)d_in[23];
    const float* eo_b    = (const float*)d_in[24];
    const float* eo_a    = (const float*)d_in[25];
    const float* cb      = (const float*)d_in[26];
    const float* dc0_w   = (const float*)d_in[27];
    const float* dc0_b   = (const float*)d_in[28];
    const float* dc0_a   = (const float*)d_in[29];
    const float* dr0_c1w = (const float*)d_in[30];
    const float* dr0_c1b = (const float*)d_in[31];
    const float* dr0_c2w = (const float*)d_in[32];
    const float* dr0_c2b = (const float*)d_in[33];
    const float* dr0_g   = (const float*)d_in[34];
    const float* dr0_be  = (const float*)d_in[35];
    const float* dr0_m   = (const float*)d_in[36];
    const float* dr0_v   = (const float*)d_in[37];
    const float* dr0_a   = (const float*)d_in[38];
    const float* du0_w   = (const float*)d_in[39];
    const float* du0_b   = (const float*)d_in[40];
    const float* dr1_c1w = (const float*)d_in[41];
    const float* dr1_c1b = (const float*)d_in[42];
    const float* dr1_c2w = (const float*)d_in[43];
    const float* dr1_c2b = (const float*)d_in[44];
    const float* dr1_g   = (const float*)d_in[45];
    const float* dr1_be  = (const float*)d_in[46];
    const float* dr1_m   = (const float*)d_in[47];
    const float* dr1_v   = (const float*)d_in[48];
    const float* dr1_a   = (const float*)d_in[49];
    const float* du1_w   = (const float*)d_in[50];
    const float* du1_b   = (const float*)d_in[51];

    float* out = (float*)d_out;

    // ---- ws: A=[0,134MB) , H=[134MB,268MB) ----
    char* W = (char*)d_ws;
    float*  Af  = (float*)(W);
    float*  Hf  = (float*)(W + 134217728);
    float*  E1f = (float*)(W + 134217728);
    float*  R1f = (float*)(W + 134217728 + 33554432);
    float*  Zf  = (float*)(W);
    int*    IDX = (int*)  (W + 16777216);
    float*  CN  = (float*)(W + 17039360);
    float*  HS  = (float*)(W + 17041408);
    bf16_t* ZQh = (bf16_t*)(W + 33554432);
    bf16_t* ZQl = (bf16_t*)(W + 41943040);
    bf16_t* D0h = (bf16_t*)(W + 50331648);
    bf16_t* D0l = (bf16_t*)(W + 67108864);
    bf16_t* Gh  = (bf16_t*)(W + 83886080);
    bf16_t* Gl  = (bf16_t*)(W + 100663296);
    bf16_t* U0h = (bf16_t*)(W + 134217728);
    bf16_t* U0l = (bf16_t*)(W + 201326592);
    bf16_t* G1h = (bf16_t*)(W);
    bf16_t* G1l = (bf16_t*)(W + 67108864);

    // ---- weight arenas in d_out ----
    char* WB = (char*)d_out;
    bf16_t* e0c1h = (bf16_t*)(WB + 0);
    bf16_t* e0c1m = (bf16_t*)(WB + 221184);
    bf16_t* e0c1l = (bf16_t*)(WB + 442368);
    bf16_t* e0c2h = (bf16_t*)(WB + 663552);
    bf16_t* e0c2m = (bf16_t*)(WB + 884736);
    bf16_t* e0c2l = (bf16_t*)(WB + 1105920);
    bf16_t* ec1h  = (bf16_t*)(WB + 1327104);
    bf16_t* ec1m  = (bf16_t*)(WB + 2375680);
    bf16_t* ec1l  = (bf16_t*)(WB + 3424256);
    bf16_t* e1c1h = (bf16_t*)(WB + 4472832);
    bf16_t* e1c1m = (bf16_t*)(WB + 5357568);
    bf16_t* e1c1l = (bf16_t*)(WB + 6242304);
    bf16_t* e1c2h = (bf16_t*)(WB + 7127040);
    bf16_t* e1c2m = (bf16_t*)(WB + 8011776);
    bf16_t* e1c2l = (bf16_t*)(WB + 8896512);
    bf16_t* eoh   = (bf16_t*)(WB + 9781248);
    bf16_t* eom   = (bf16_t*)(WB + 10223616);
    bf16_t* eol   = (bf16_t*)(WB + 10665984);
    bf16_t* wec0h = (bf16_t*)(WB + 11108352);   // ec0 MFMA weights (8KB x3)
    bf16_t* wec0m = (bf16_t*)(WB + 11116544);
    bf16_t* wec0l = (bf16_t*)(WB + 11124736);
    bf16_t* dc0h  = (bf16_t*)(WB + 0);
    bf16_t* dc0l  = (bf16_t*)(WB + 442368);
    bf16_t* d0c1h = (bf16_t*)(WB + 884736);
    bf16_t* d0c1l = (bf16_t*)(WB + 1769472);
    bf16_t* d0c2h = (bf16_t*)(WB + 2654208);
    bf16_t* d0c2l = (bf16_t*)(WB + 3538944);
    bf16_t* du0h  = (bf16_t*)(WB + 4423680);
    bf16_t* du0l  = (bf16_t*)(WB + 5472256);
    bf16_t* d1c1h = (bf16_t*)(WB + 6520832);
    bf16_t* d1c1l = (bf16_t*)(WB + 6742016);
    bf16_t* d1c2h = (bf16_t*)(WB + 6963200);
    bf16_t* d1c2l = (bf16_t*)(WB + 7184384);

    const float* fn = nullptr;
    const bf16_t* bn_ = nullptr;

    // ---- encoder weight prep (split-3, fragment-major) ----
    // ec0: src [tap=64][ci=1][co=64] == [K=64][co]; wprep3 with ci=64,co=64
    // (tap index folds into ci_) produces [ks][half][cout][8] exactly.
    wprep3<<<16, 256, 0, stream>>>(ec0_w, wec0h, wec0m, wec0l, 64, 64, 4096);
    wprep3<<<432, 256, 0, stream>>>(er0_c1w, e0c1h, e0c1m, e0c1l, 64, 64, 110592);
    wprep3<<<432, 256, 0, stream>>>(er0_c2w, e0c2h, e0c2m, e0c2l, 64, 64, 110592);
    wprep3<<<2048, 256, 0, stream>>>(ec1_w, ec1h, ec1m, ec1l, 64, 128, 524288);
    wprep3<<<1728, 256, 0, stream>>>(er1_c1w, e1c1h, e1c1m, e1c1l, 128, 128, 442368);
    wprep3<<<1728, 256, 0, stream>>>(er1_c2w, e1c2h, e1c2m, e1c2l, 128, 128, 442368);
    wprep3<<<864, 256, 0, stream>>>(eo_w, eoh, eom, eol, 128, 64, 221184);

    // ---- encoder (fp32-class) ----
    conv_ec0m<<<8192, 128, 0, stream>>>(x, wec0h, wec0m, wec0l, ec0_b, Af);

    conv3e<64, 64, 64, 1, 1><<<8192, 128, 0, stream>>>(
        Af, e0c1h, e0c1m, e0c1l, er0_c1b, fn, fn, fn, fn, fn, fn, Hf);
    conv3e<64, 64, 64, 1, 3><<<8192, 128, 0, stream>>>(
        Hf, e0c2h, e0c2m, e0c2l, er0_c2b, er0_g, er0_be, er0_m, er0_v, er0_a, Af, Af);

    convs2e<<<2048, 128, 0, stream>>>(Af, ec1h, ec1m, ec1l, ec1_b, E1f);

    conv3e<128, 128, 32, 2, 1><<<2048, 128, 0, stream>>>(
        E1f, e1c1h, e1c1m, e1c1l, er1_c1b, fn, fn, fn, fn, fn, fn, R1f);
    conv3e<128, 128, 32, 2, 3><<<2048, 128, 0, stream>>>(
        R1f, e1c2h, e1c2m, e1c2l, er1_c2b, er1_g, er1_be, er1_m, er1_v, er1_a, E1f, E1f);

    conv3e<128, 64, 32, 1, 2><<<2048, 64, 0, stream>>>(
        E1f, eoh, eom, eol, eo_b, fn, fn, fn, fn, eo_a, fn, Zf);

    // ---- VQ (exact fp32) ----
    vq_cnorm<<<8, 64, 0, stream>>>(cb, CN);
    zero512<<<1, 512, 0, stream>>>(HS);
    vq_assign<<<256, 256, 0, stream>>>(Zf, cb, CN, IDX, HS, 65536);
    perplexity_k<<<1, 512, 0, stream>>>(HS, out + 4194304, 1.0f / 65536.0f);
    vq_gather_split<<<4096, 256, 0, stream>>>(cb, IDX, ZQh, ZQl);

    // ---- decoder weight prep (split-2, fragment-major, overwrites arena) ----
    wprep_split<<<864, 256, 0, stream>>>(dc0_w, dc0h, dc0l, 64, 128, 221184);
    wprep_split<<<1728, 256, 0, stream>>>(dr0_c1w, d0c1h, d0c1l, 128, 128, 442368);
    wprep_split<<<1728, 256, 0, stream>>>(dr0_c2w, d0c2h, d0c2l, 128, 128, 442368);
    wprep_split<<<2048, 256, 0, stream>>>(du0_w, du0h, du0l, 128, 64, 524288);
    wprep_split<<<432, 256, 0, stream>>>(dr1_c1w, d1c1h, d1c1l, 64, 64, 110592);
    wprep_split<<<432, 256, 0, stream>>>(dr1_c2w, d1c2h, d1c2l, 64, 64, 110592);

    // ---- decoder (split-2 bf16) ----
    conv3d<64, 128, 32, 2, 2><<<2048, 128, 0, stream>>>(
        ZQh, ZQl, dc0h, dc0l, dc0_b, fn, fn, fn, fn, dc0_a, bn_, bn_, D0h, D0l);
    conv3d<128, 128, 32, 2, 1><<<2048, 128, 0, stream>>>(
        D0h, D0l, d0c1h, d0c1l, dr0_c1b, fn, fn, fn, fn, fn, bn_, bn_, Gh, Gl);
    conv3d<128, 128, 32, 2, 3><<<2048, 128, 0, stream>>>(
        Gh, Gl, d0c2h, d0c2l, dr0_c2b, dr0_g, dr0_be, dr0_m, dr0_v, dr0_a,
        D0h, D0l, D0h, D0l);

    convTm<<<8192, 256, 0, stream>>>(D0h, D0l, du0h, du0l, du0_b, U0h, U0l);

    conv3d<64, 64, 64, 1, 1><<<8192, 128, 0, stream>>>(
        U0h, U0l, d1c1h, d1c1l, dr1_c1b, fn, fn, fn, fn, fn, bn_, bn_, G1h, G1l);
    conv3d<64, 64, 64, 1, 3><<<8192, 128, 0, stream>>>(
        G1h, G1l, d1c2h, d1c2l, dr1_c2b, dr1_g, dr1_be, dr1_m, dr1_v, dr1_a,
        U0h, U0l, U0h, U0l);

    convT_du1w<<<65536, 256, 0, stream>>>(U0h, U0l, du1_w, du1_b, out);
}